// Round 2
// baseline (2111.698 us; speedup 1.0000x reference)
//
#include <hip/hip_runtime.h>
#include <hip/hip_bf16.h>

#define NN 50000
#define EE 800000
#define INDIM 128
#define HIDC 16
#define NHEAD 8

typedef __attribute__((ext_vector_type(8))) short bf16x8;
typedef __attribute__((ext_vector_type(4))) float f32x4;

__device__ __forceinline__ unsigned short f2bf(float f) {
    union { float f; unsigned int i; } v; v.f = f;
    unsigned int r = v.i + 0x7FFFu + ((v.i >> 16) & 1u);
    return (unsigned short)(r >> 16);
}

__device__ __forceinline__ bf16x8 load_bf16x8(const float* __restrict__ p) {
    bf16x8 r;
    #pragma unroll
    for (int i = 0; i < 8; i++) r[i] = (short)f2bf(p[i]);
    return r;
}

// ---------------------------------------------------------------------------
// K1: fused GEMM  h0 = x @ w0^T (cols 0..127),  s0 = x @ skip0^T (cols 128..255)
// MFMA 16x16x32 bf16 (fp32 inputs converted in-register). One block = 16 rows
// x 256 cols; 4 waves of 16x64. Weight fragments preloaded (K=128 -> 4 steps).
// ---------------------------------------------------------------------------
__global__ __launch_bounds__(256) void k_gemm0(
    const float* __restrict__ x, const float* __restrict__ w0,
    const float* __restrict__ skip0,
    float* __restrict__ h0, float* __restrict__ s0)
{
    const int tile = blockIdx.x;          // 3125 tiles of 16 rows
    const int wave = threadIdx.x >> 6;
    const int lane = threadIdx.x & 63;
    const int lrow = lane & 15;
    const int quad = lane >> 4;
    const int row0 = tile * 16;

    bf16x8 bfrag[4][4];
    #pragma unroll
    for (int t = 0; t < 4; t++) {
        const int jg = wave * 64 + t * 16 + lrow;
        const float* wsrc = (jg < 128) ? (w0 + (long)jg * 128)
                                       : (skip0 + (long)(jg - 128) * 128);
        #pragma unroll
        for (int ki = 0; ki < 4; ki++)
            bfrag[t][ki] = load_bf16x8(wsrc + ki * 32 + quad * 8);
    }

    const float* xrow = x + (long)(row0 + lrow) * 128;
    bf16x8 afrag[4];
    #pragma unroll
    for (int ki = 0; ki < 4; ki++)
        afrag[ki] = load_bf16x8(xrow + ki * 32 + quad * 8);

    f32x4 acc[4];
    #pragma unroll
    for (int t = 0; t < 4; t++) acc[t] = (f32x4){0.f, 0.f, 0.f, 0.f};

    #pragma unroll
    for (int ki = 0; ki < 4; ki++)
        #pragma unroll
        for (int t = 0; t < 4; t++)
            acc[t] = __builtin_amdgcn_mfma_f32_16x16x32_bf16(afrag[ki], bfrag[t][ki], acc[t], 0, 0, 0);

    // C/D layout: col = lane&15, row = (lane>>4)*4 + reg   [verified m89]
    #pragma unroll
    for (int t = 0; t < 4; t++) {
        const int jg = wave * 64 + t * 16 + lrow;
        float* dst = (jg < 128) ? (h0 + jg) : (s0 + (jg - 128));
        #pragma unroll
        for (int r = 0; r < 4; r++) {
            const int node = row0 + quad * 4 + r;
            dst[(long)node * 128] = acc[t][r];
        }
    }
}

// ---------------------------------------------------------------------------
// K1b: per-node attention coefficients  a_src0[n,h], a_dst0[n,h]
// ---------------------------------------------------------------------------
__global__ __launch_bounds__(256) void k_attn_coef0(
    const float* __restrict__ h0, const float* __restrict__ asrc0,
    const float* __restrict__ adst0,
    float* __restrict__ a_src0, float* __restrict__ a_dst0)
{
    int idx = blockIdx.x * 256 + threadIdx.x;
    if (idx >= NN * NHEAD) return;
    int h = idx & 7, n = idx >> 3;
    const float4* hp = (const float4*)(h0 + (long)n * 128 + h * 16);
    const float4* ap = (const float4*)(asrc0 + h * 16);
    const float4* dp = (const float4*)(adst0 + h * 16);
    float s = 0.f, d = 0.f;
    #pragma unroll
    for (int q = 0; q < 4; q++) {
        float4 hv = hp[q];
        float4 av = ap[q];
        float4 dv = dp[q];
        s += hv.x * av.x + hv.y * av.y + hv.z * av.z + hv.w * av.w;
        d += hv.x * dv.x + hv.y * dv.y + hv.z * dv.z + hv.w * dv.w;
    }
    a_src0[idx] = s;
    a_dst0[idx] = d;
}

// ---------------------------------------------------------------------------
// K2: layer-0 edge pass 1: denom[d,h] += exp(leaky_relu(a_src[s,h]+a_dst[d,h]))
// (softmax max-shift dropped: |alpha| = O(5), exp cannot overflow; the
//  attn ratio is shift-invariant so result is identical within fp32.)
// ---------------------------------------------------------------------------
__global__ __launch_bounds__(256) void k_edge0_a(
    const int* __restrict__ ei, const float* __restrict__ a_src0,
    const float* __restrict__ a_dst0, float* __restrict__ denom0)
{
    int e = blockIdx.x * 256 + threadIdx.x;
    if (e >= EE) return;
    int s = ei[e], d = ei[EE + e];
    float4 as0 = *(const float4*)(a_src0 + (long)s * 8);
    float4 as1 = *(const float4*)(a_src0 + (long)s * 8 + 4);
    float4 ad0 = *(const float4*)(a_dst0 + (long)d * 8);
    float4 ad1 = *(const float4*)(a_dst0 + (long)d * 8 + 4);
    float v[8];
    v[0] = as0.x + ad0.x; v[1] = as0.y + ad0.y; v[2] = as0.z + ad0.z; v[3] = as0.w + ad0.w;
    v[4] = as1.x + ad1.x; v[5] = as1.y + ad1.y; v[6] = as1.z + ad1.z; v[7] = as1.w + ad1.w;
    #pragma unroll
    for (int h = 0; h < 8; h++) {
        float a = v[h];
        a = a > 0.f ? a : 0.2f * a;
        atomicAdd(denom0 + (long)d * 8 + h, __expf(a));
    }
}

// ---------------------------------------------------------------------------
// K3: layer-0 message aggregation: out0[d] += attn * h0[s].  32 threads/edge,
// attn recomputed from per-node tables (saves E*8 ex-buffer round trip).
// ---------------------------------------------------------------------------
__global__ __launch_bounds__(256) void k_edge0_b(
    const int* __restrict__ ei, const float* __restrict__ h0,
    const float* __restrict__ a_src0, const float* __restrict__ a_dst0,
    const float* __restrict__ denom0, float* __restrict__ out0)
{
    long tid = (long)blockIdx.x * 256 + threadIdx.x;
    int e = (int)(tid >> 5);
    int c4 = (int)(tid & 31);
    if (e >= EE) return;
    int s = ei[e], d = ei[EE + e];
    int c = c4 * 4;
    int h = c >> 4;
    float a = a_src0[(long)s * 8 + h] + a_dst0[(long)d * 8 + h];
    a = a > 0.f ? a : 0.2f * a;
    float w = __expf(a) / (denom0[(long)d * 8 + h] + 1e-16f);
    float4 hv = *(const float4*)(h0 + (long)s * 128 + c);
    float* o = out0 + (long)d * 128 + c;
    atomicAdd(o + 0, w * hv.x);
    atomicAdd(o + 1, w * hv.y);
    atomicAdd(o + 2, w * hv.z);
    atomicAdd(o + 3, w * hv.w);
}

// ---------------------------------------------------------------------------
// K4: per-node fused: BN0 + skip + ELU -> h_act (LDS only), then
//     h1 = h_act@w1^T, s1 = h_act@skip1^T, a_src1/a_dst1 from h1.
// One wave per node; 4 waves per block.
// ---------------------------------------------------------------------------
__global__ __launch_bounds__(256) void k_post0(
    const float* __restrict__ out0, const float* __restrict__ s0,
    const float* __restrict__ b0, const float* __restrict__ g0,
    const float* __restrict__ bb0, const float* __restrict__ m0,
    const float* __restrict__ v0,
    const float* __restrict__ w1, const float* __restrict__ skip1,
    const float* __restrict__ asrc1, const float* __restrict__ adst1,
    float* __restrict__ h1, float* __restrict__ s1,
    float* __restrict__ a_src1, float* __restrict__ a_dst1)
{
    __shared__ float wls[2 * 2048];     // [0]: w1T[c*16+j]  [2048]: skip1T[c*16+j]
    __shared__ float hrow[4][128];
    const int tid = threadIdx.x;
    for (int idx = tid; idx < 4096; idx += 256) {
        int half = idx >> 11;
        int r = idx & 2047;
        int c = r & 127, j = r >> 7;
        const float* src = half ? skip1 : w1;
        wls[half * 2048 + c * 16 + j] = src[j * 128 + c];
    }
    __syncthreads();

    const int lane = tid & 63, wave = tid >> 6;
    const int c0 = lane, c1 = lane + 64;
    const float A0 = g0[c0] * rsqrtf(v0[c0] + 1e-5f);
    const float B0 = (b0[c0] - m0[c0]) * A0 + bb0[c0];
    const float A1 = g0[c1] * rsqrtf(v0[c1] + 1e-5f);
    const float B1 = (b0[c1] - m0[c1]) * A1 + bb0[c1];
    const int j = lane & 15;
    const int grp = lane >> 4;
    const float avec = asrc1[j];
    const float dvec = adst1[j];
    const float* wbase = (grp & 1) ? (wls + 2048) : wls;  // grp0/2: w1, grp1/3: skip1
    const int coff = (grp >> 1) * 64;

    for (int n = blockIdx.x * 4 + wave; n < NN; n += gridDim.x * 4) {
        float x0 = out0[(long)n * 128 + c0] * A0 + B0 + s0[(long)n * 128 + c0];
        float x1 = out0[(long)n * 128 + c1] * A1 + B1 + s0[(long)n * 128 + c1];
        x0 = x0 > 0.f ? x0 : __expf(x0) - 1.f;
        x1 = x1 > 0.f ? x1 : __expf(x1) - 1.f;
        hrow[wave][c0] = x0;
        hrow[wave][c1] = x1;
        // wave-local LDS RAW: DS pipe processes a wave's ops in order
        float acc = 0.f;
        #pragma unroll 8
        for (int c = 0; c < 64; c++)
            acc += hrow[wave][coff + c] * wbase[(coff + c) * 16 + j];
        acc += __shfl_xor(acc, 32);
        // lanes 0-15 & 32-47: full h1[j]; lanes 16-31 & 48-63: full s1[j]
        if (grp == 0) h1[(long)n * 16 + j] = acc;
        if (grp == 1) s1[(long)n * 16 + j] = acc;
        float p = (grp == 0) ? acc * avec : (grp == 2 ? acc * dvec : 0.f);
        p += __shfl_xor(p, 1); p += __shfl_xor(p, 2);
        p += __shfl_xor(p, 4); p += __shfl_xor(p, 8);
        if (lane == 0)  a_src1[n] = p;
        if (lane == 32) a_dst1[n] = p;
    }
}

// ---------------------------------------------------------------------------
// K5: layer-1 edge pass 1 (1 head)
// ---------------------------------------------------------------------------
__global__ __launch_bounds__(256) void k_edge1_a(
    const int* __restrict__ ei, const float* __restrict__ a_src1,
    const float* __restrict__ a_dst1, float* __restrict__ denom1)
{
    int e = blockIdx.x * 256 + threadIdx.x;
    if (e >= EE) return;
    int s = ei[e], d = ei[EE + e];
    float a = a_src1[s] + a_dst1[d];
    a = a > 0.f ? a : 0.2f * a;
    atomicAdd(denom1 + d, __expf(a));
}

// ---------------------------------------------------------------------------
// K6: layer-1 message aggregation. 4 threads/edge (float4 each), attn
// recomputed.
// ---------------------------------------------------------------------------
__global__ __launch_bounds__(256) void k_edge1_b(
    const int* __restrict__ ei, const float* __restrict__ h1,
    const float* __restrict__ a_src1, const float* __restrict__ a_dst1,
    const float* __restrict__ denom1, float* __restrict__ out1)
{
    long tid = (long)blockIdx.x * 256 + threadIdx.x;
    int e = (int)(tid >> 2);
    int q = (int)(tid & 3);
    if (e >= EE) return;
    int s = ei[e], d = ei[EE + e];
    float a = a_src1[s] + a_dst1[d];
    a = a > 0.f ? a : 0.2f * a;
    float w = __expf(a) / (denom1[d] + 1e-16f);
    float4 hv = *(const float4*)(h1 + (long)s * 16 + q * 4);
    float* o = out1 + (long)d * 16 + q * 4;
    atomicAdd(o + 0, w * hv.x);
    atomicAdd(o + 1, w * hv.y);
    atomicAdd(o + 2, w * hv.z);
    atomicAdd(o + 3, w * hv.w);
}

// ---------------------------------------------------------------------------
// K7: final BN1 + skip + ELU -> fp32 output
// ---------------------------------------------------------------------------
__global__ __launch_bounds__(256) void k_final(
    const float* __restrict__ out1, const float* __restrict__ s1,
    const float* __restrict__ b1, const float* __restrict__ g1,
    const float* __restrict__ bb1, const float* __restrict__ m1,
    const float* __restrict__ v1, float* __restrict__ out)
{
    int idx = blockIdx.x * 256 + threadIdx.x;
    if (idx >= NN * HIDC) return;
    int c = idx & 15;
    float A = g1[c] * rsqrtf(v1[c] + 1e-5f);
    float B = (b1[c] - m1[c]) * A + bb1[c];
    float v = out1[idx] * A + B + s1[idx];
    v = v > 0.f ? v : __expf(v) - 1.f;
    out[idx] = v;
}

extern "C" void kernel_launch(void* const* d_in, const int* in_sizes, int n_in,
                              void* d_out, int out_size, void* d_ws, size_t ws_size,
                              hipStream_t stream)
{
    (void)in_sizes; (void)n_in; (void)out_size; (void)ws_size;
    const float* x     = (const float*)d_in[0];
    const int*   ei    = (const int*)d_in[1];
    const float* w0    = (const float*)d_in[2];
    const float* asrc0 = (const float*)d_in[3];
    const float* adst0 = (const float*)d_in[4];
    const float* b0    = (const float*)d_in[5];
    const float* skip0 = (const float*)d_in[6];
    const float* bn0g  = (const float*)d_in[7];
    const float* bn0b  = (const float*)d_in[8];
    const float* bn0m  = (const float*)d_in[9];
    const float* bn0v  = (const float*)d_in[10];
    const float* w1    = (const float*)d_in[11];
    const float* asrc1 = (const float*)d_in[12];
    const float* adst1 = (const float*)d_in[13];
    const float* b1    = (const float*)d_in[14];
    const float* skip1 = (const float*)d_in[15];
    const float* bn1g  = (const float*)d_in[16];
    const float* bn1b  = (const float*)d_in[17];
    const float* bn1m  = (const float*)d_in[18];
    const float* bn1v  = (const float*)d_in[19];

    float* ws = (float*)d_ws;
    float* h0      = ws;                    // N*128
    float* s0      = h0 + (long)NN * 128;   // N*128
    float* out0    = s0 + (long)NN * 128;   // N*128   (zeroed)
    float* a_src0  = out0 + (long)NN * 128; // N*8
    float* a_dst0  = a_src0 + NN * 8;       // N*8
    float* denom0  = a_dst0 + NN * 8;       // N*8     (zeroed)
    float* h1      = denom0 + NN * 8;       // N*16
    float* s1      = h1 + NN * 16;          // N*16
    float* a_src1  = s1 + NN * 16;          // N
    float* a_dst1  = a_src1 + NN;           // N
    float* denom1  = a_dst1 + NN;           // N       (zeroed)
    float* out1    = denom1 + NN;           // N*16    (zeroed)
    // total ~22.95M floats = 91.8 MB

    hipMemsetAsync(out0,   0, (size_t)NN * 128 * 4, stream);
    hipMemsetAsync(denom0, 0, (size_t)NN * 8 * 4,   stream);
    hipMemsetAsync(denom1, 0, (size_t)NN * 4,       stream);
    hipMemsetAsync(out1,   0, (size_t)NN * 16 * 4,  stream);

    k_gemm0<<<NN / 16, 256, 0, stream>>>(x, w0, skip0, h0, s0);
    k_attn_coef0<<<(NN * NHEAD + 255) / 256, 256, 0, stream>>>(h0, asrc0, adst0, a_src0, a_dst0);
    k_edge0_a<<<(EE + 255) / 256, 256, 0, stream>>>(ei, a_src0, a_dst0, denom0);
    k_edge0_b<<<(EE * 32) / 256, 256, 0, stream>>>(ei, h0, a_src0, a_dst0, denom0, out0);
    k_post0<<<640, 256, 0, stream>>>(out0, s0, b0, bn0g, bn0b, bn0m, bn0v,
                                     w1, skip1, asrc1, adst1, h1, s1, a_src1, a_dst1);
    k_edge1_a<<<(EE + 255) / 256, 256, 0, stream>>>(ei, a_src1, a_dst1, denom1);
    k_edge1_b<<<(EE * 4) / 256, 256, 0, stream>>>(ei, h1, a_src1, a_dst1, denom1, out1);
    k_final<<<(NN * HIDC + 255) / 256, 256, 0, stream>>>(out1, s1, b1, bn1g, bn1b, bn1m, bn1v,
                                                         (float*)d_out);
}

// Round 3
// 613.507 us; speedup vs baseline: 3.4420x; 3.4420x over previous
//
#include <hip/hip_runtime.h>
#include <hip/hip_bf16.h>

#define NN 50000
#define EE 800000
#define INDIM 128
#define HIDC 16
#define NHEAD 8

typedef __attribute__((ext_vector_type(8))) short bf16x8;
typedef __attribute__((ext_vector_type(4))) float f32x4;

__device__ __forceinline__ unsigned short f2bf(float f) {
    union { float f; unsigned int i; } v; v.f = f;
    unsigned int r = v.i + 0x7FFFu + ((v.i >> 16) & 1u);
    return (unsigned short)(r >> 16);
}

__device__ __forceinline__ bf16x8 load_bf16x8(const float* __restrict__ p) {
    bf16x8 r;
    #pragma unroll
    for (int i = 0; i < 8; i++) r[i] = (short)f2bf(p[i]);
    return r;
}

// ---------------------------------------------------------------------------
// K1: fused GEMM  h0 = x @ w0^T (cols 0..127),  s0 = x @ skip0^T (cols 128..255)
// MFMA 16x16x32 bf16 (fp32 inputs converted in-register). One block = 16 rows
// x 256 cols; 4 waves of 16x64. Weight fragments preloaded (K=128 -> 4 steps).
// ---------------------------------------------------------------------------
__global__ __launch_bounds__(256) void k_gemm0(
    const float* __restrict__ x, const float* __restrict__ w0,
    const float* __restrict__ skip0,
    float* __restrict__ h0, float* __restrict__ s0)
{
    const int tile = blockIdx.x;          // 3125 tiles of 16 rows
    const int wave = threadIdx.x >> 6;
    const int lane = threadIdx.x & 63;
    const int lrow = lane & 15;
    const int quad = lane >> 4;
    const int row0 = tile * 16;

    bf16x8 bfrag[4][4];
    #pragma unroll
    for (int t = 0; t < 4; t++) {
        const int jg = wave * 64 + t * 16 + lrow;
        const float* wsrc = (jg < 128) ? (w0 + (long)jg * 128)
                                       : (skip0 + (long)(jg - 128) * 128);
        #pragma unroll
        for (int ki = 0; ki < 4; ki++)
            bfrag[t][ki] = load_bf16x8(wsrc + ki * 32 + quad * 8);
    }

    const float* xrow = x + (long)(row0 + lrow) * 128;
    bf16x8 afrag[4];
    #pragma unroll
    for (int ki = 0; ki < 4; ki++)
        afrag[ki] = load_bf16x8(xrow + ki * 32 + quad * 8);

    f32x4 acc[4];
    #pragma unroll
    for (int t = 0; t < 4; t++) acc[t] = (f32x4){0.f, 0.f, 0.f, 0.f};

    #pragma unroll
    for (int ki = 0; ki < 4; ki++)
        #pragma unroll
        for (int t = 0; t < 4; t++)
            acc[t] = __builtin_amdgcn_mfma_f32_16x16x32_bf16(afrag[ki], bfrag[t][ki], acc[t], 0, 0, 0);

    // C/D layout: col = lane&15, row = (lane>>4)*4 + reg
    #pragma unroll
    for (int t = 0; t < 4; t++) {
        const int jg = wave * 64 + t * 16 + lrow;
        float* dst = (jg < 128) ? (h0 + jg) : (s0 + (jg - 128));
        #pragma unroll
        for (int r = 0; r < 4; r++) {
            const int node = row0 + quad * 4 + r;
            dst[(long)node * 128] = acc[t][r];
        }
    }
}

// ---------------------------------------------------------------------------
// K1b: per-node attention coefficients  a_src0[n,h], a_dst0[n,h]
// ---------------------------------------------------------------------------
__global__ __launch_bounds__(256) void k_attn_coef0(
    const float* __restrict__ h0, const float* __restrict__ asrc0,
    const float* __restrict__ adst0,
    float* __restrict__ a_src0, float* __restrict__ a_dst0)
{
    int idx = blockIdx.x * 256 + threadIdx.x;
    if (idx >= NN * NHEAD) return;
    int h = idx & 7, n = idx >> 3;
    const float4* hp = (const float4*)(h0 + (long)n * 128 + h * 16);
    const float4* ap = (const float4*)(asrc0 + h * 16);
    const float4* dp = (const float4*)(adst0 + h * 16);
    float s = 0.f, d = 0.f;
    #pragma unroll
    for (int q = 0; q < 4; q++) {
        float4 hv = hp[q];
        float4 av = ap[q];
        float4 dv = dp[q];
        s += hv.x * av.x + hv.y * av.y + hv.z * av.z + hv.w * av.w;
        d += hv.x * dv.x + hv.y * dv.y + hv.z * dv.z + hv.w * dv.w;
    }
    a_src0[idx] = s;
    a_dst0[idx] = d;
}

// ---------------------------------------------------------------------------
// CSR build (shared by both layers): deg histogram -> scan -> scatter src ids
// ---------------------------------------------------------------------------
__global__ __launch_bounds__(256) void k_hist(const int* __restrict__ ei,
                                              int* __restrict__ deg)
{
    int e = blockIdx.x * 256 + threadIdx.x;
    if (e >= EE) return;
    atomicAdd(deg + ei[EE + e], 1);
}

__global__ __launch_bounds__(1024) void k_scan(const int* __restrict__ deg,
                                               int* __restrict__ rowptr,
                                               int* __restrict__ cursor)
{
    __shared__ int part[1024];
    const int t = threadIdx.x;
    const int chunk = (NN + 1023) / 1024;                 // 49
    const int start = t * chunk;
    const int end = min(start + chunk, NN);
    int s = 0;
    for (int i = start; i < end; i++) s += deg[i];
    part[t] = s;
    __syncthreads();
    // Hillis-Steele inclusive scan over 1024 partials
    for (int off = 1; off < 1024; off <<= 1) {
        int v = (t >= off) ? part[t - off] : 0;
        __syncthreads();
        part[t] += v;
        __syncthreads();
    }
    int base = (t == 0) ? 0 : part[t - 1];
    for (int i = start; i < end; i++) {
        rowptr[i] = base;
        cursor[i] = base;
        base += deg[i];
    }
    if (t == 1023) rowptr[NN] = part[1023];               // == EE
}

__global__ __launch_bounds__(256) void k_scatter(const int* __restrict__ ei,
                                                 int* __restrict__ cursor,
                                                 int* __restrict__ srcidx)
{
    int e = blockIdx.x * 256 + threadIdx.x;
    if (e >= EE) return;
    int s = ei[e], d = ei[EE + e];
    int pos = atomicAdd(cursor + d, 1);
    srcidx[pos] = s;
}

// ---------------------------------------------------------------------------
// K3: layer-0 aggregation, gather-style. One wave per dst node.
// Pass 1: per-head softmax denominator (each lane covers head lane>>3).
// Pass 2: weighted sum; each lane owns channels {2*lane, 2*lane+1} (same head).
// out0 row written exactly once -> no atomics, minimal HBM writes.
// ---------------------------------------------------------------------------
__global__ __launch_bounds__(256) void k_agg0(
    const int* __restrict__ rowptr, const int* __restrict__ srcidx,
    const float* __restrict__ h0, const float* __restrict__ a_src0,
    const float* __restrict__ a_dst0, float* __restrict__ out0)
{
    const int d = (blockIdx.x * 256 + threadIdx.x) >> 6;  // one wave per node
    if (d >= NN) return;
    const int lane = threadIdx.x & 63;
    const int beg = rowptr[d], end = rowptr[d + 1];
    const int h = lane >> 3;                              // head for this lane
    const float adst = a_dst0[(long)d * 8 + h];

    float den = 0.f;
    for (int i = beg; i < end; i++) {
        int s = srcidx[i];
        float a = a_src0[(long)s * 8 + h] + adst;
        a = a > 0.f ? a : 0.2f * a;
        den += __expf(a);
    }
    const float inv = 1.f / (den + 1e-16f);

    const int c = lane * 2;                               // (c>>4) == h
    float2 acc = make_float2(0.f, 0.f);
    for (int i = beg; i < end; i++) {
        int s = srcidx[i];
        float a = a_src0[(long)s * 8 + h] + adst;
        a = a > 0.f ? a : 0.2f * a;
        float w = __expf(a) * inv;
        float2 hv = *(const float2*)(h0 + (long)s * 128 + c);
        acc.x += w * hv.x;
        acc.y += w * hv.y;
    }
    *(float2*)(out0 + (long)d * 128 + c) = acc;
}

// ---------------------------------------------------------------------------
// K4: per-node fused: BN0 + skip + ELU -> h_act (LDS only), then
//     h1 = h_act@w1^T, s1 = h_act@skip1^T, a_src1/a_dst1 from h1.
// One wave per node; 4 waves per block.
// ---------------------------------------------------------------------------
__global__ __launch_bounds__(256) void k_post0(
    const float* __restrict__ out0, const float* __restrict__ s0,
    const float* __restrict__ b0, const float* __restrict__ g0,
    const float* __restrict__ bb0, const float* __restrict__ m0,
    const float* __restrict__ v0,
    const float* __restrict__ w1, const float* __restrict__ skip1,
    const float* __restrict__ asrc1, const float* __restrict__ adst1,
    float* __restrict__ h1, float* __restrict__ s1,
    float* __restrict__ a_src1, float* __restrict__ a_dst1)
{
    __shared__ float wls[2 * 2048];     // [0]: w1T[c*16+j]  [2048]: skip1T[c*16+j]
    __shared__ float hrow[4][128];
    const int tid = threadIdx.x;
    for (int idx = tid; idx < 4096; idx += 256) {
        int half = idx >> 11;
        int r = idx & 2047;
        int c = r & 127, j = r >> 7;
        const float* src = half ? skip1 : w1;
        wls[half * 2048 + c * 16 + j] = src[j * 128 + c];
    }
    __syncthreads();

    const int lane = tid & 63, wave = tid >> 6;
    const int c0 = lane, c1 = lane + 64;
    const float A0 = g0[c0] * rsqrtf(v0[c0] + 1e-5f);
    const float B0 = (b0[c0] - m0[c0]) * A0 + bb0[c0];
    const float A1 = g0[c1] * rsqrtf(v0[c1] + 1e-5f);
    const float B1 = (b0[c1] - m0[c1]) * A1 + bb0[c1];
    const int j = lane & 15;
    const int grp = lane >> 4;
    const float avec = asrc1[j];
    const float dvec = adst1[j];
    const float* wbase = (grp & 1) ? (wls + 2048) : wls;  // grp0/2: w1, grp1/3: skip1
    const int coff = (grp >> 1) * 64;

    for (int n = blockIdx.x * 4 + wave; n < NN; n += gridDim.x * 4) {
        float x0 = out0[(long)n * 128 + c0] * A0 + B0 + s0[(long)n * 128 + c0];
        float x1 = out0[(long)n * 128 + c1] * A1 + B1 + s0[(long)n * 128 + c1];
        x0 = x0 > 0.f ? x0 : __expf(x0) - 1.f;
        x1 = x1 > 0.f ? x1 : __expf(x1) - 1.f;
        hrow[wave][c0] = x0;
        hrow[wave][c1] = x1;
        // wave-local LDS RAW: DS pipe processes a wave's ops in order
        float acc = 0.f;
        #pragma unroll 8
        for (int c = 0; c < 64; c++)
            acc += hrow[wave][coff + c] * wbase[(coff + c) * 16 + j];
        acc += __shfl_xor(acc, 32);
        // lanes 0-15 & 32-47: full h1[j]; lanes 16-31 & 48-63: full s1[j]
        if (grp == 0) h1[(long)n * 16 + j] = acc;
        if (grp == 1) s1[(long)n * 16 + j] = acc;
        float p = (grp == 0) ? acc * avec : (grp == 2 ? acc * dvec : 0.f);
        p += __shfl_xor(p, 1); p += __shfl_xor(p, 2);
        p += __shfl_xor(p, 4); p += __shfl_xor(p, 8);
        if (lane == 0)  a_src1[n] = p;
        if (lane == 32) a_dst1[n] = p;
    }
}

// ---------------------------------------------------------------------------
// K5: layer-1 aggregation + BN1 + skip + ELU -> d_out, gather-style.
// 16 threads per dst node (one per channel); denominator recomputed per group.
// ---------------------------------------------------------------------------
__global__ __launch_bounds__(256) void k_agg1_final(
    const int* __restrict__ rowptr, const int* __restrict__ srcidx,
    const float* __restrict__ h1, const float* __restrict__ a_src1,
    const float* __restrict__ a_dst1, const float* __restrict__ s1,
    const float* __restrict__ b1, const float* __restrict__ g1,
    const float* __restrict__ bb1, const float* __restrict__ m1,
    const float* __restrict__ v1, float* __restrict__ out)
{
    const int gid = blockIdx.x * 256 + threadIdx.x;
    const int d = gid >> 4;
    if (d >= NN) return;
    const int c = gid & 15;
    const int beg = rowptr[d], end = rowptr[d + 1];
    const float adst = a_dst1[d];

    float den = 0.f;
    for (int i = beg; i < end; i++) {
        int s = srcidx[i];
        float a = a_src1[s] + adst;
        a = a > 0.f ? a : 0.2f * a;
        den += __expf(a);
    }
    const float inv = 1.f / (den + 1e-16f);

    float acc = 0.f;
    for (int i = beg; i < end; i++) {
        int s = srcidx[i];
        float a = a_src1[s] + adst;
        a = a > 0.f ? a : 0.2f * a;
        acc += __expf(a) * inv * h1[(long)s * 16 + c];
    }
    const float A = g1[c] * rsqrtf(v1[c] + 1e-5f);
    const float B = (b1[c] - m1[c]) * A + bb1[c];
    float v = acc * A + B + s1[gid];
    v = v > 0.f ? v : __expf(v) - 1.f;
    out[gid] = v;
}

extern "C" void kernel_launch(void* const* d_in, const int* in_sizes, int n_in,
                              void* d_out, int out_size, void* d_ws, size_t ws_size,
                              hipStream_t stream)
{
    (void)in_sizes; (void)n_in; (void)out_size; (void)ws_size;
    const float* x     = (const float*)d_in[0];
    const int*   ei    = (const int*)d_in[1];
    const float* w0    = (const float*)d_in[2];
    const float* asrc0 = (const float*)d_in[3];
    const float* adst0 = (const float*)d_in[4];
    const float* b0    = (const float*)d_in[5];
    const float* skip0 = (const float*)d_in[6];
    const float* bn0g  = (const float*)d_in[7];
    const float* bn0b  = (const float*)d_in[8];
    const float* bn0m  = (const float*)d_in[9];
    const float* bn0v  = (const float*)d_in[10];
    const float* w1    = (const float*)d_in[11];
    const float* asrc1 = (const float*)d_in[12];
    const float* adst1 = (const float*)d_in[13];
    const float* b1    = (const float*)d_in[14];
    const float* skip1 = (const float*)d_in[15];
    const float* bn1g  = (const float*)d_in[16];
    const float* bn1b  = (const float*)d_in[17];
    const float* bn1m  = (const float*)d_in[18];
    const float* bn1v  = (const float*)d_in[19];

    float* ws = (float*)d_ws;
    float* h0      = ws;                    // N*128
    float* s0      = h0 + (long)NN * 128;   // N*128
    float* out0    = s0 + (long)NN * 128;   // N*128
    float* a_src0  = out0 + (long)NN * 128; // N*8
    float* a_dst0  = a_src0 + NN * 8;       // N*8
    float* h1      = a_dst0 + NN * 8;       // N*16
    float* s1      = h1 + NN * 16;          // N*16
    float* a_src1  = s1 + NN * 16;          // N
    float* a_dst1  = a_src1 + NN;           // N
    int*   deg     = (int*)(a_dst1 + NN);   // N (zeroed)
    int*   rowptr  = deg + NN;              // N+1
    int*   cursor  = rowptr + NN + 1;       // N
    int*   srcidx  = cursor + NN;           // E
    // total ~21.8M words = 87.2 MB

    hipMemsetAsync(deg, 0, (size_t)NN * 4, stream);

    // CSR build (independent of features; shared by both layers)
    k_hist<<<(EE + 255) / 256, 256, 0, stream>>>(ei, deg);
    k_scan<<<1, 1024, 0, stream>>>(deg, rowptr, cursor);
    k_scatter<<<(EE + 255) / 256, 256, 0, stream>>>(ei, cursor, srcidx);

    k_gemm0<<<NN / 16, 256, 0, stream>>>(x, w0, skip0, h0, s0);
    k_attn_coef0<<<(NN * NHEAD + 255) / 256, 256, 0, stream>>>(h0, asrc0, adst0, a_src0, a_dst0);
    k_agg0<<<(NN * 64 + 255) / 256, 256, 0, stream>>>(rowptr, srcidx, h0, a_src0, a_dst0, out0);
    k_post0<<<640, 256, 0, stream>>>(out0, s0, b0, bn0g, bn0b, bn0m, bn0v,
                                     w1, skip1, asrc1, adst1, h1, s1, a_src1, a_dst1);
    k_agg1_final<<<(NN * 16 + 255) / 256, 256, 0, stream>>>(rowptr, srcidx, h1, a_src1, a_dst1,
                                                            s1, b1, bn1g, bn1b, bn1m, bn1v,
                                                            (float*)d_out);
}

// Round 4
// 495.113 us; speedup vs baseline: 4.2651x; 1.2391x over previous
//
#include <hip/hip_runtime.h>
#include <hip/hip_bf16.h>

#define NN 50000
#define EE 800000
#define INDIM 128
#define HIDC 16
#define NHEAD 8

typedef __attribute__((ext_vector_type(8))) short bf16x8;
typedef __attribute__((ext_vector_type(4))) float f32x4;

__device__ __forceinline__ unsigned short f2bf(float f) {
    union { float f; unsigned int i; } v; v.f = f;
    unsigned int r = v.i + 0x7FFFu + ((v.i >> 16) & 1u);
    return (unsigned short)(r >> 16);
}

__device__ __forceinline__ bf16x8 load_bf16x8(const float* __restrict__ p) {
    bf16x8 r;
    #pragma unroll
    for (int i = 0; i < 8; i++) r[i] = (short)f2bf(p[i]);
    return r;
}

// ---------------------------------------------------------------------------
// K1: fused GEMM  h0 = x @ w0^T (cols 0..127),  s0 = x @ skip0^T (cols 128..255)
// MFMA 16x16x32 bf16 (fp32 inputs converted in-register). One block = 16 rows
// x 256 cols; 4 waves of 16x64. Weight fragments preloaded (K=128 -> 4 steps).
// ---------------------------------------------------------------------------
__global__ __launch_bounds__(256) void k_gemm0(
    const float* __restrict__ x, const float* __restrict__ w0,
    const float* __restrict__ skip0,
    float* __restrict__ h0, float* __restrict__ s0)
{
    const int tile = blockIdx.x;          // 3125 tiles of 16 rows
    const int wave = threadIdx.x >> 6;
    const int lane = threadIdx.x & 63;
    const int lrow = lane & 15;
    const int quad = lane >> 4;
    const int row0 = tile * 16;

    bf16x8 bfrag[4][4];
    #pragma unroll
    for (int t = 0; t < 4; t++) {
        const int jg = wave * 64 + t * 16 + lrow;
        const float* wsrc = (jg < 128) ? (w0 + (long)jg * 128)
                                       : (skip0 + (long)(jg - 128) * 128);
        #pragma unroll
        for (int ki = 0; ki < 4; ki++)
            bfrag[t][ki] = load_bf16x8(wsrc + ki * 32 + quad * 8);
    }

    const float* xrow = x + (long)(row0 + lrow) * 128;
    bf16x8 afrag[4];
    #pragma unroll
    for (int ki = 0; ki < 4; ki++)
        afrag[ki] = load_bf16x8(xrow + ki * 32 + quad * 8);

    f32x4 acc[4];
    #pragma unroll
    for (int t = 0; t < 4; t++) acc[t] = (f32x4){0.f, 0.f, 0.f, 0.f};

    #pragma unroll
    for (int ki = 0; ki < 4; ki++)
        #pragma unroll
        for (int t = 0; t < 4; t++)
            acc[t] = __builtin_amdgcn_mfma_f32_16x16x32_bf16(afrag[ki], bfrag[t][ki], acc[t], 0, 0, 0);

    // C/D layout: col = lane&15, row = (lane>>4)*4 + reg
    #pragma unroll
    for (int t = 0; t < 4; t++) {
        const int jg = wave * 64 + t * 16 + lrow;
        float* dst = (jg < 128) ? (h0 + jg) : (s0 + (jg - 128));
        #pragma unroll
        for (int r = 0; r < 4; r++) {
            const int node = row0 + quad * 4 + r;
            dst[(long)node * 128] = acc[t][r];
        }
    }
}

// ---------------------------------------------------------------------------
// K1b: per-node attention coefficients  a_src0[n,h], a_dst0[n,h]
// ---------------------------------------------------------------------------
__global__ __launch_bounds__(256) void k_attn_coef0(
    const float* __restrict__ h0, const float* __restrict__ asrc0,
    const float* __restrict__ adst0,
    float* __restrict__ a_src0, float* __restrict__ a_dst0)
{
    int idx = blockIdx.x * 256 + threadIdx.x;
    if (idx >= NN * NHEAD) return;
    int h = idx & 7, n = idx >> 3;
    const float4* hp = (const float4*)(h0 + (long)n * 128 + h * 16);
    const float4* ap = (const float4*)(asrc0 + h * 16);
    const float4* dp = (const float4*)(adst0 + h * 16);
    float s = 0.f, d = 0.f;
    #pragma unroll
    for (int q = 0; q < 4; q++) {
        float4 hv = hp[q];
        float4 av = ap[q];
        float4 dv = dp[q];
        s += hv.x * av.x + hv.y * av.y + hv.z * av.z + hv.w * av.w;
        d += hv.x * dv.x + hv.y * dv.y + hv.z * dv.z + hv.w * dv.w;
    }
    a_src0[idx] = s;
    a_dst0[idx] = d;
}

// ---------------------------------------------------------------------------
// CSR build (shared by both layers): deg histogram -> scan -> scatter src ids
// ---------------------------------------------------------------------------
__global__ __launch_bounds__(256) void k_hist(const int* __restrict__ ei,
                                              int* __restrict__ deg)
{
    int e = blockIdx.x * 256 + threadIdx.x;
    if (e >= EE) return;
    atomicAdd(deg + ei[EE + e], 1);
}

__global__ __launch_bounds__(1024) void k_scan(const int* __restrict__ deg,
                                               int* __restrict__ rowptr,
                                               int* __restrict__ cursor)
{
    __shared__ int part[1024];
    const int t = threadIdx.x;
    const int chunk = (NN + 1023) / 1024;                 // 49
    const int start = t * chunk;
    const int end = min(start + chunk, NN);
    int s = 0;
    for (int i = start; i < end; i++) s += deg[i];
    part[t] = s;
    __syncthreads();
    // Hillis-Steele inclusive scan over 1024 partials
    for (int off = 1; off < 1024; off <<= 1) {
        int v = (t >= off) ? part[t - off] : 0;
        __syncthreads();
        part[t] += v;
        __syncthreads();
    }
    int base = (t == 0) ? 0 : part[t - 1];
    for (int i = start; i < end; i++) {
        rowptr[i] = base;
        cursor[i] = base;
        base += deg[i];
    }
    if (t == 1023) rowptr[NN] = part[1023];               // == EE
}

__global__ __launch_bounds__(256) void k_scatter(const int* __restrict__ ei,
                                                 int* __restrict__ cursor,
                                                 int* __restrict__ srcidx)
{
    int e = blockIdx.x * 256 + threadIdx.x;
    if (e >= EE) return;
    int s = ei[e], d = ei[EE + e];
    int pos = atomicAdd(cursor + d, 1);
    srcidx[pos] = s;
}

// ---------------------------------------------------------------------------
// K3: layer-0 aggregation, gather-style, SINGLE PASS with post-normalization:
//   out0[d] = (sum_i ex_i * h0[s_i]) / (sum_i ex_i + eps)
// One wave per dst node; lane owns channels {2*lane, 2*lane+1} (head lane>>3).
// 2x unrolled with independent accumulators to overlap gather latency.
// ---------------------------------------------------------------------------
__global__ __launch_bounds__(256) void k_agg0(
    const int* __restrict__ rowptr, const int* __restrict__ srcidx,
    const float* __restrict__ h0, const float* __restrict__ a_src0,
    const float* __restrict__ a_dst0, float* __restrict__ out0)
{
    const int d = (blockIdx.x * 256 + threadIdx.x) >> 6;  // one wave per node
    if (d >= NN) return;
    const int lane = threadIdx.x & 63;
    const int beg = rowptr[d], end = rowptr[d + 1];
    const int h = lane >> 3;                              // head for this lane
    const int c = lane * 2;                               // (c>>4) == h
    const float adst = a_dst0[(long)d * 8 + h];

    float den = 0.f, denB = 0.f;
    float2 acc = make_float2(0.f, 0.f), accB = make_float2(0.f, 0.f);
    int i = beg;
    for (; i + 2 <= end; i += 2) {
        int sA = srcidx[i], sB = srcidx[i + 1];
        float aA = a_src0[(long)sA * 8 + h] + adst;
        float aB = a_src0[(long)sB * 8 + h] + adst;
        float2 hA = *(const float2*)(h0 + (long)sA * 128 + c);
        float2 hB = *(const float2*)(h0 + (long)sB * 128 + c);
        aA = aA > 0.f ? aA : 0.2f * aA;
        aB = aB > 0.f ? aB : 0.2f * aB;
        float eA = __expf(aA), eB = __expf(aB);
        den  += eA;  acc.x  += eA * hA.x;  acc.y  += eA * hA.y;
        denB += eB;  accB.x += eB * hB.x;  accB.y += eB * hB.y;
    }
    if (i < end) {
        int sA = srcidx[i];
        float aA = a_src0[(long)sA * 8 + h] + adst;
        float2 hA = *(const float2*)(h0 + (long)sA * 128 + c);
        aA = aA > 0.f ? aA : 0.2f * aA;
        float eA = __expf(aA);
        den += eA;  acc.x += eA * hA.x;  acc.y += eA * hA.y;
    }
    den += denB; acc.x += accB.x; acc.y += accB.y;
    const float inv = 1.f / (den + 1e-16f);
    *(float2*)(out0 + (long)d * 128 + c) = make_float2(acc.x * inv, acc.y * inv);
}

// ---------------------------------------------------------------------------
// K4: per-node fused: BN0 + skip + ELU -> h_act (LDS only), then
//     h1 = h_act@w1^T, s1 = h_act@skip1^T, a_src1/a_dst1 from h1.
// One wave per node; 4 waves per block.
// ---------------------------------------------------------------------------
__global__ __launch_bounds__(256) void k_post0(
    const float* __restrict__ out0, const float* __restrict__ s0,
    const float* __restrict__ b0, const float* __restrict__ g0,
    const float* __restrict__ bb0, const float* __restrict__ m0,
    const float* __restrict__ v0,
    const float* __restrict__ w1, const float* __restrict__ skip1,
    const float* __restrict__ asrc1, const float* __restrict__ adst1,
    float* __restrict__ h1, float* __restrict__ s1,
    float* __restrict__ a_src1, float* __restrict__ a_dst1)
{
    __shared__ float wls[2 * 2048];     // [0]: w1T[c*16+j]  [2048]: skip1T[c*16+j]
    __shared__ float hrow[4][128];
    const int tid = threadIdx.x;
    for (int idx = tid; idx < 4096; idx += 256) {
        int half = idx >> 11;
        int r = idx & 2047;
        int c = r & 127, j = r >> 7;
        const float* src = half ? skip1 : w1;
        wls[half * 2048 + c * 16 + j] = src[j * 128 + c];
    }
    __syncthreads();

    const int lane = tid & 63, wave = tid >> 6;
    const int c0 = lane, c1 = lane + 64;
    const float A0 = g0[c0] * rsqrtf(v0[c0] + 1e-5f);
    const float B0 = (b0[c0] - m0[c0]) * A0 + bb0[c0];
    const float A1 = g0[c1] * rsqrtf(v0[c1] + 1e-5f);
    const float B1 = (b0[c1] - m0[c1]) * A1 + bb0[c1];
    const int j = lane & 15;
    const int grp = lane >> 4;
    const float avec = asrc1[j];
    const float dvec = adst1[j];
    const float* wbase = (grp & 1) ? (wls + 2048) : wls;  // grp0/2: w1, grp1/3: skip1
    const int coff = (grp >> 1) * 64;

    for (int n = blockIdx.x * 4 + wave; n < NN; n += gridDim.x * 4) {
        float x0 = out0[(long)n * 128 + c0] * A0 + B0 + s0[(long)n * 128 + c0];
        float x1 = out0[(long)n * 128 + c1] * A1 + B1 + s0[(long)n * 128 + c1];
        x0 = x0 > 0.f ? x0 : __expf(x0) - 1.f;
        x1 = x1 > 0.f ? x1 : __expf(x1) - 1.f;
        hrow[wave][c0] = x0;
        hrow[wave][c1] = x1;
        // wave-local LDS RAW: DS pipe processes a wave's ops in order
        float acc = 0.f;
        #pragma unroll 8
        for (int c = 0; c < 64; c++)
            acc += hrow[wave][coff + c] * wbase[(coff + c) * 16 + j];
        acc += __shfl_xor(acc, 32);
        // lanes 0-15 & 32-47: full h1[j]; lanes 16-31 & 48-63: full s1[j]
        if (grp == 0) h1[(long)n * 16 + j] = acc;
        if (grp == 1) s1[(long)n * 16 + j] = acc;
        float p = (grp == 0) ? acc * avec : (grp == 2 ? acc * dvec : 0.f);
        p += __shfl_xor(p, 1); p += __shfl_xor(p, 2);
        p += __shfl_xor(p, 4); p += __shfl_xor(p, 8);
        if (lane == 0)  a_src1[n] = p;
        if (lane == 32) a_dst1[n] = p;
    }
}

// ---------------------------------------------------------------------------
// K5: layer-1 aggregation + BN1 + skip + ELU -> d_out, gather-style,
// SINGLE PASS with post-normalization. 16 threads per dst node.
// ---------------------------------------------------------------------------
__global__ __launch_bounds__(256) void k_agg1_final(
    const int* __restrict__ rowptr, const int* __restrict__ srcidx,
    const float* __restrict__ h1, const float* __restrict__ a_src1,
    const float* __restrict__ a_dst1, const float* __restrict__ s1,
    const float* __restrict__ b1, const float* __restrict__ g1,
    const float* __restrict__ bb1, const float* __restrict__ m1,
    const float* __restrict__ v1, float* __restrict__ out)
{
    const int gid = blockIdx.x * 256 + threadIdx.x;
    const int d = gid >> 4;
    if (d >= NN) return;
    const int c = gid & 15;
    const int beg = rowptr[d], end = rowptr[d + 1];
    const float adst = a_dst1[d];

    float den = 0.f, denB = 0.f, acc = 0.f, accB = 0.f;
    int i = beg;
    for (; i + 2 <= end; i += 2) {
        int sA = srcidx[i], sB = srcidx[i + 1];
        float aA = a_src1[sA] + adst;
        float aB = a_src1[sB] + adst;
        float hA = h1[(long)sA * 16 + c];
        float hB = h1[(long)sB * 16 + c];
        aA = aA > 0.f ? aA : 0.2f * aA;
        aB = aB > 0.f ? aB : 0.2f * aB;
        float eA = __expf(aA), eB = __expf(aB);
        den  += eA;  acc  += eA * hA;
        denB += eB;  accB += eB * hB;
    }
    if (i < end) {
        int sA = srcidx[i];
        float aA = a_src1[sA] + adst;
        float hA = h1[(long)sA * 16 + c];
        aA = aA > 0.f ? aA : 0.2f * aA;
        float eA = __expf(aA);
        den += eA;  acc += eA * hA;
    }
    den += denB; acc += accB;
    const float inv = 1.f / (den + 1e-16f);

    const float A = g1[c] * rsqrtf(v1[c] + 1e-5f);
    const float B = (b1[c] - m1[c]) * A + bb1[c];
    float v = acc * inv * A + B + s1[gid];
    v = v > 0.f ? v : __expf(v) - 1.f;
    out[gid] = v;
}

extern "C" void kernel_launch(void* const* d_in, const int* in_sizes, int n_in,
                              void* d_out, int out_size, void* d_ws, size_t ws_size,
                              hipStream_t stream)
{
    (void)in_sizes; (void)n_in; (void)out_size; (void)ws_size;
    const float* x     = (const float*)d_in[0];
    const int*   ei    = (const int*)d_in[1];
    const float* w0    = (const float*)d_in[2];
    const float* asrc0 = (const float*)d_in[3];
    const float* adst0 = (const float*)d_in[4];
    const float* b0    = (const float*)d_in[5];
    const float* skip0 = (const float*)d_in[6];
    const float* bn0g  = (const float*)d_in[7];
    const float* bn0b  = (const float*)d_in[8];
    const float* bn0m  = (const float*)d_in[9];
    const float* bn0v  = (const float*)d_in[10];
    const float* w1    = (const float*)d_in[11];
    const float* asrc1 = (const float*)d_in[12];
    const float* adst1 = (const float*)d_in[13];
    const float* b1    = (const float*)d_in[14];
    const float* skip1 = (const float*)d_in[15];
    const float* bn1g  = (const float*)d_in[16];
    const float* bn1b  = (const float*)d_in[17];
    const float* bn1m  = (const float*)d_in[18];
    const float* bn1v  = (const float*)d_in[19];

    float* ws = (float*)d_ws;
    float* h0      = ws;                    // N*128
    float* s0      = h0 + (long)NN * 128;   // N*128
    float* out0    = s0 + (long)NN * 128;   // N*128
    float* a_src0  = out0 + (long)NN * 128; // N*8
    float* a_dst0  = a_src0 + NN * 8;       // N*8
    float* h1      = a_dst0 + NN * 8;       // N*16
    float* s1      = h1 + NN * 16;          // N*16
    float* a_src1  = s1 + NN * 16;          // N
    float* a_dst1  = a_src1 + NN;           // N
    int*   deg     = (int*)(a_dst1 + NN);   // N (zeroed)
    int*   rowptr  = deg + NN;              // N+1
    int*   cursor  = rowptr + NN + 1;       // N
    int*   srcidx  = cursor + NN;           // E

    hipMemsetAsync(deg, 0, (size_t)NN * 4, stream);

    // CSR build (independent of features; shared by both layers)
    k_hist<<<(EE + 255) / 256, 256, 0, stream>>>(ei, deg);
    k_scan<<<1, 1024, 0, stream>>>(deg, rowptr, cursor);
    k_scatter<<<(EE + 255) / 256, 256, 0, stream>>>(ei, cursor, srcidx);

    k_gemm0<<<NN / 16, 256, 0, stream>>>(x, w0, skip0, h0, s0);
    k_attn_coef0<<<(NN * NHEAD + 255) / 256, 256, 0, stream>>>(h0, asrc0, adst0, a_src0, a_dst0);
    k_agg0<<<(NN * 64 + 255) / 256, 256, 0, stream>>>(rowptr, srcidx, h0, a_src0, a_dst0, out0);
    k_post0<<<640, 256, 0, stream>>>(out0, s0, b0, bn0g, bn0b, bn0m, bn0v,
                                     w1, skip1, asrc1, adst1, h1, s1, a_src1, a_dst1);
    k_agg1_final<<<(NN * 16 + 255) / 256, 256, 0, stream>>>(rowptr, srcidx, h1, a_src1, a_dst1,
                                                            s1, b1, bn1g, bn1b, bn1m, bn1v,
                                                            (float*)d_out);
}

// Round 5
// 388.359 us; speedup vs baseline: 5.4375x; 1.2749x over previous
//
#include <hip/hip_runtime.h>
#include <hip/hip_bf16.h>

#define NN 50000
#define EE 800000
#define INDIM 128
#define HIDC 16
#define NHEAD 8

typedef __attribute__((ext_vector_type(8))) short bf16x8;
typedef __attribute__((ext_vector_type(4))) float f32x4;

__device__ __forceinline__ unsigned short f2bf(float f) {
    union { float f; unsigned int i; } v; v.f = f;
    unsigned int r = v.i + 0x7FFFu + ((v.i >> 16) & 1u);
    return (unsigned short)(r >> 16);
}

__device__ __forceinline__ bf16x8 load_bf16x8(const float* __restrict__ p) {
    bf16x8 r;
    #pragma unroll
    for (int i = 0; i < 8; i++) r[i] = (short)f2bf(p[i]);
    return r;
}

// ---------------------------------------------------------------------------
// K1: fused GEMM  h0 = x @ w0^T (cols 0..127),  s0 = x @ skip0^T (cols 128..255)
// MFMA 16x16x32 bf16 (fp32 inputs converted in-register). One block = 16 rows
// x 256 cols; 4 waves of 16x64. Weight fragments preloaded (K=128 -> 4 steps).
// ---------------------------------------------------------------------------
__global__ __launch_bounds__(256) void k_gemm0(
    const float* __restrict__ x, const float* __restrict__ w0,
    const float* __restrict__ skip0,
    float* __restrict__ h0, float* __restrict__ s0)
{
    const int tile = blockIdx.x;          // 3125 tiles of 16 rows
    const int wave = threadIdx.x >> 6;
    const int lane = threadIdx.x & 63;
    const int lrow = lane & 15;
    const int quad = lane >> 4;
    const int row0 = tile * 16;

    bf16x8 bfrag[4][4];
    #pragma unroll
    for (int t = 0; t < 4; t++) {
        const int jg = wave * 64 + t * 16 + lrow;
        const float* wsrc = (jg < 128) ? (w0 + (long)jg * 128)
                                       : (skip0 + (long)(jg - 128) * 128);
        #pragma unroll
        for (int ki = 0; ki < 4; ki++)
            bfrag[t][ki] = load_bf16x8(wsrc + ki * 32 + quad * 8);
    }

    const float* xrow = x + (long)(row0 + lrow) * 128;
    bf16x8 afrag[4];
    #pragma unroll
    for (int ki = 0; ki < 4; ki++)
        afrag[ki] = load_bf16x8(xrow + ki * 32 + quad * 8);

    f32x4 acc[4];
    #pragma unroll
    for (int t = 0; t < 4; t++) acc[t] = (f32x4){0.f, 0.f, 0.f, 0.f};

    #pragma unroll
    for (int ki = 0; ki < 4; ki++)
        #pragma unroll
        for (int t = 0; t < 4; t++)
            acc[t] = __builtin_amdgcn_mfma_f32_16x16x32_bf16(afrag[ki], bfrag[t][ki], acc[t], 0, 0, 0);

    // C/D layout: col = lane&15, row = (lane>>4)*4 + reg
    #pragma unroll
    for (int t = 0; t < 4; t++) {
        const int jg = wave * 64 + t * 16 + lrow;
        float* dst = (jg < 128) ? (h0 + jg) : (s0 + (jg - 128));
        #pragma unroll
        for (int r = 0; r < 4; r++) {
            const int node = row0 + quad * 4 + r;
            dst[(long)node * 128] = acc[t][r];
        }
    }
}

// ---------------------------------------------------------------------------
// K1b: per-node attention coefficients  a_src0[n,h], a_dst0[n,h]
// ---------------------------------------------------------------------------
__global__ __launch_bounds__(256) void k_attn_coef0(
    const float* __restrict__ h0, const float* __restrict__ asrc0,
    const float* __restrict__ adst0,
    float* __restrict__ a_src0, float* __restrict__ a_dst0)
{
    int idx = blockIdx.x * 256 + threadIdx.x;
    if (idx >= NN * NHEAD) return;
    int h = idx & 7, n = idx >> 3;
    const float4* hp = (const float4*)(h0 + (long)n * 128 + h * 16);
    const float4* ap = (const float4*)(asrc0 + h * 16);
    const float4* dp = (const float4*)(adst0 + h * 16);
    float s = 0.f, d = 0.f;
    #pragma unroll
    for (int q = 0; q < 4; q++) {
        float4 hv = hp[q];
        float4 av = ap[q];
        float4 dv = dp[q];
        s += hv.x * av.x + hv.y * av.y + hv.z * av.z + hv.w * av.w;
        d += hv.x * dv.x + hv.y * dv.y + hv.z * dv.z + hv.w * dv.w;
    }
    a_src0[idx] = s;
    a_dst0[idx] = d;
}

// ---------------------------------------------------------------------------
// CSR build. Bucket offsets need NOT be an ordered prefix sum — any disjoint
// contiguous range per node works (consumers use beg + deg). So: per-wave
// shuffle-scan of degrees + one atomicAdd per block on a global counter.
// ---------------------------------------------------------------------------
__global__ __launch_bounds__(256) void k_hist(const int* __restrict__ ei,
                                              int* __restrict__ deg)
{
    int e = blockIdx.x * 256 + threadIdx.x;
    if (e >= EE) return;
    atomicAdd(deg + ei[EE + e], 1);
}

__global__ __launch_bounds__(256) void k_rowoff(const int* __restrict__ deg,
                                                int* __restrict__ rowbeg,
                                                int* __restrict__ cursor,
                                                int* __restrict__ counter)
{
    __shared__ int wave_tot[4];
    __shared__ int blockbase;
    const int n = blockIdx.x * 256 + threadIdx.x;
    const int lane = threadIdx.x & 63;
    const int wid = threadIdx.x >> 6;
    int v = (n < NN) ? deg[n] : 0;
    int incl = v;
    #pragma unroll
    for (int off = 1; off < 64; off <<= 1) {
        int t = __shfl_up(incl, off);
        if (lane >= off) incl += t;
    }
    if (lane == 63) wave_tot[wid] = incl;
    __syncthreads();
    if (threadIdx.x == 0) {
        int tot = wave_tot[0] + wave_tot[1] + wave_tot[2] + wave_tot[3];
        blockbase = atomicAdd(counter, tot);
    }
    __syncthreads();
    int base = blockbase;
    for (int w = 0; w < wid; w++) base += wave_tot[w];
    if (n < NN) {
        int off = base + incl - v;
        rowbeg[n] = off;
        cursor[n] = off;
    }
}

__global__ __launch_bounds__(256) void k_scatter(const int* __restrict__ ei,
                                                 int* __restrict__ cursor,
                                                 int* __restrict__ srcidx)
{
    int e = blockIdx.x * 256 + threadIdx.x;
    if (e >= EE) return;
    int s = ei[e], d = ei[EE + e];
    int pos = atomicAdd(cursor + d, 1);
    srcidx[pos] = s;
}

// ---------------------------------------------------------------------------
// K3: layer-0 aggregation, gather-style, single pass w/ post-normalization:
//   out0[d] = (sum_i ex_i * h0[s_i]) / (sum_i ex_i + eps)
// One wave per dst node; lane owns channels {2*lane, 2*lane+1} (head lane>>3).
// 4x unrolled with independent accumulators to overlap gather latency.
// ---------------------------------------------------------------------------
__global__ __launch_bounds__(256) void k_agg0(
    const int* __restrict__ rowbeg, const int* __restrict__ deg,
    const int* __restrict__ srcidx,
    const float* __restrict__ h0, const float* __restrict__ a_src0,
    const float* __restrict__ a_dst0, float* __restrict__ out0)
{
    const int d = (blockIdx.x * 256 + threadIdx.x) >> 6;  // one wave per node
    if (d >= NN) return;
    const int lane = threadIdx.x & 63;
    const int beg = rowbeg[d], end = beg + deg[d];
    const int h = lane >> 3;                              // head for this lane
    const int c = lane * 2;                               // (c>>4) == h
    const float adst = a_dst0[(long)d * 8 + h];

    float den0 = 0.f, den1 = 0.f, den2 = 0.f, den3 = 0.f;
    float2 ac0 = {0.f, 0.f}, ac1 = {0.f, 0.f}, ac2 = {0.f, 0.f}, ac3 = {0.f, 0.f};
    int i = beg;
    for (; i + 4 <= end; i += 4) {
        int sA = srcidx[i], sB = srcidx[i + 1], sC = srcidx[i + 2], sD = srcidx[i + 3];
        float aA = a_src0[(long)sA * 8 + h] + adst;
        float aB = a_src0[(long)sB * 8 + h] + adst;
        float aC = a_src0[(long)sC * 8 + h] + adst;
        float aD = a_src0[(long)sD * 8 + h] + adst;
        float2 hA = *(const float2*)(h0 + (long)sA * 128 + c);
        float2 hB = *(const float2*)(h0 + (long)sB * 128 + c);
        float2 hC = *(const float2*)(h0 + (long)sC * 128 + c);
        float2 hD = *(const float2*)(h0 + (long)sD * 128 + c);
        aA = aA > 0.f ? aA : 0.2f * aA;
        aB = aB > 0.f ? aB : 0.2f * aB;
        aC = aC > 0.f ? aC : 0.2f * aC;
        aD = aD > 0.f ? aD : 0.2f * aD;
        float eA = __expf(aA), eB = __expf(aB), eC = __expf(aC), eD = __expf(aD);
        den0 += eA; ac0.x += eA * hA.x; ac0.y += eA * hA.y;
        den1 += eB; ac1.x += eB * hB.x; ac1.y += eB * hB.y;
        den2 += eC; ac2.x += eC * hC.x; ac2.y += eC * hC.y;
        den3 += eD; ac3.x += eD * hD.x; ac3.y += eD * hD.y;
    }
    for (; i < end; i++) {
        int sA = srcidx[i];
        float aA = a_src0[(long)sA * 8 + h] + adst;
        float2 hA = *(const float2*)(h0 + (long)sA * 128 + c);
        aA = aA > 0.f ? aA : 0.2f * aA;
        float eA = __expf(aA);
        den0 += eA; ac0.x += eA * hA.x; ac0.y += eA * hA.y;
    }
    float den = (den0 + den1) + (den2 + den3);
    float ax = (ac0.x + ac1.x) + (ac2.x + ac3.x);
    float ay = (ac0.y + ac1.y) + (ac2.y + ac3.y);
    const float inv = 1.f / (den + 1e-16f);
    *(float2*)(out0 + (long)d * 128 + c) = make_float2(ax * inv, ay * inv);
}

// ---------------------------------------------------------------------------
// K4: per-node fused: BN0 + skip + ELU -> h_act (LDS only), then
//     h1 = h_act@w1^T, s1 = h_act@skip1^T, a_src1/a_dst1 from h1.
// One wave per node; 4 waves per block.
// ---------------------------------------------------------------------------
__global__ __launch_bounds__(256) void k_post0(
    const float* __restrict__ out0, const float* __restrict__ s0,
    const float* __restrict__ b0, const float* __restrict__ g0,
    const float* __restrict__ bb0, const float* __restrict__ m0,
    const float* __restrict__ v0,
    const float* __restrict__ w1, const float* __restrict__ skip1,
    const float* __restrict__ asrc1, const float* __restrict__ adst1,
    float* __restrict__ h1, float* __restrict__ s1,
    float* __restrict__ a_src1, float* __restrict__ a_dst1)
{
    __shared__ float wls[2 * 2048];     // [0]: w1T[c*16+j]  [2048]: skip1T[c*16+j]
    __shared__ float hrow[4][128];
    const int tid = threadIdx.x;
    for (int idx = tid; idx < 4096; idx += 256) {
        int half = idx >> 11;
        int r = idx & 2047;
        int c = r & 127, j = r >> 7;
        const float* src = half ? skip1 : w1;
        wls[half * 2048 + c * 16 + j] = src[j * 128 + c];
    }
    __syncthreads();

    const int lane = tid & 63, wave = tid >> 6;
    const int c0 = lane, c1 = lane + 64;
    const float A0 = g0[c0] * rsqrtf(v0[c0] + 1e-5f);
    const float B0 = (b0[c0] - m0[c0]) * A0 + bb0[c0];
    const float A1 = g0[c1] * rsqrtf(v0[c1] + 1e-5f);
    const float B1 = (b0[c1] - m0[c1]) * A1 + bb0[c1];
    const int j = lane & 15;
    const int grp = lane >> 4;
    const float avec = asrc1[j];
    const float dvec = adst1[j];
    const float* wbase = (grp & 1) ? (wls + 2048) : wls;  // grp0/2: w1, grp1/3: skip1
    const int coff = (grp >> 1) * 64;

    for (int n = blockIdx.x * 4 + wave; n < NN; n += gridDim.x * 4) {
        float x0 = out0[(long)n * 128 + c0] * A0 + B0 + s0[(long)n * 128 + c0];
        float x1 = out0[(long)n * 128 + c1] * A1 + B1 + s0[(long)n * 128 + c1];
        x0 = x0 > 0.f ? x0 : __expf(x0) - 1.f;
        x1 = x1 > 0.f ? x1 : __expf(x1) - 1.f;
        hrow[wave][c0] = x0;
        hrow[wave][c1] = x1;
        // wave-local LDS RAW: DS pipe processes a wave's ops in order
        float acc = 0.f;
        #pragma unroll 8
        for (int c = 0; c < 64; c++)
            acc += hrow[wave][coff + c] * wbase[(coff + c) * 16 + j];
        acc += __shfl_xor(acc, 32);
        // lanes 0-15 & 32-47: full h1[j]; lanes 16-31 & 48-63: full s1[j]
        if (grp == 0) h1[(long)n * 16 + j] = acc;
        if (grp == 1) s1[(long)n * 16 + j] = acc;
        float p = (grp == 0) ? acc * avec : (grp == 2 ? acc * dvec : 0.f);
        p += __shfl_xor(p, 1); p += __shfl_xor(p, 2);
        p += __shfl_xor(p, 4); p += __shfl_xor(p, 8);
        if (lane == 0)  a_src1[n] = p;
        if (lane == 32) a_dst1[n] = p;
    }
}

// ---------------------------------------------------------------------------
// K5: layer-1 aggregation + BN1 + skip + ELU -> d_out, gather-style,
// single pass w/ post-normalization. 16 threads per dst node. 4x unrolled.
// ---------------------------------------------------------------------------
__global__ __launch_bounds__(256) void k_agg1_final(
    const int* __restrict__ rowbeg, const int* __restrict__ deg,
    const int* __restrict__ srcidx,
    const float* __restrict__ h1, const float* __restrict__ a_src1,
    const float* __restrict__ a_dst1, const float* __restrict__ s1,
    const float* __restrict__ b1, const float* __restrict__ g1,
    const float* __restrict__ bb1, const float* __restrict__ m1,
    const float* __restrict__ v1, float* __restrict__ out)
{
    const int gid = blockIdx.x * 256 + threadIdx.x;
    const int d = gid >> 4;
    if (d >= NN) return;
    const int c = gid & 15;
    const int beg = rowbeg[d], end = beg + deg[d];
    const float adst = a_dst1[d];

    float den0 = 0.f, den1 = 0.f, den2 = 0.f, den3 = 0.f;
    float ac0 = 0.f, ac1 = 0.f, ac2 = 0.f, ac3 = 0.f;
    int i = beg;
    for (; i + 4 <= end; i += 4) {
        int sA = srcidx[i], sB = srcidx[i + 1], sC = srcidx[i + 2], sD = srcidx[i + 3];
        float aA = a_src1[sA] + adst;
        float aB = a_src1[sB] + adst;
        float aC = a_src1[sC] + adst;
        float aD = a_src1[sD] + adst;
        float hA = h1[(long)sA * 16 + c];
        float hB = h1[(long)sB * 16 + c];
        float hC = h1[(long)sC * 16 + c];
        float hD = h1[(long)sD * 16 + c];
        aA = aA > 0.f ? aA : 0.2f * aA;
        aB = aB > 0.f ? aB : 0.2f * aB;
        aC = aC > 0.f ? aC : 0.2f * aC;
        aD = aD > 0.f ? aD : 0.2f * aD;
        float eA = __expf(aA), eB = __expf(aB), eC = __expf(aC), eD = __expf(aD);
        den0 += eA; ac0 += eA * hA;
        den1 += eB; ac1 += eB * hB;
        den2 += eC; ac2 += eC * hC;
        den3 += eD; ac3 += eD * hD;
    }
    for (; i < end; i++) {
        int sA = srcidx[i];
        float aA = a_src1[sA] + adst;
        float hA = h1[(long)sA * 16 + c];
        aA = aA > 0.f ? aA : 0.2f * aA;
        float eA = __expf(aA);
        den0 += eA; ac0 += eA * hA;
    }
    float den = (den0 + den1) + (den2 + den3);
    float acc = (ac0 + ac1) + (ac2 + ac3);
    const float inv = 1.f / (den + 1e-16f);

    const float A = g1[c] * rsqrtf(v1[c] + 1e-5f);
    const float B = (b1[c] - m1[c]) * A + bb1[c];
    float v = acc * inv * A + B + s1[gid];
    v = v > 0.f ? v : __expf(v) - 1.f;
    out[gid] = v;
}

extern "C" void kernel_launch(void* const* d_in, const int* in_sizes, int n_in,
                              void* d_out, int out_size, void* d_ws, size_t ws_size,
                              hipStream_t stream)
{
    (void)in_sizes; (void)n_in; (void)out_size; (void)ws_size;
    const float* x     = (const float*)d_in[0];
    const int*   ei    = (const int*)d_in[1];
    const float* w0    = (const float*)d_in[2];
    const float* asrc0 = (const float*)d_in[3];
    const float* adst0 = (const float*)d_in[4];
    const float* b0    = (const float*)d_in[5];
    const float* skip0 = (const float*)d_in[6];
    const float* bn0g  = (const float*)d_in[7];
    const float* bn0b  = (const float*)d_in[8];
    const float* bn0m  = (const float*)d_in[9];
    const float* bn0v  = (const float*)d_in[10];
    const float* w1    = (const float*)d_in[11];
    const float* asrc1 = (const float*)d_in[12];
    const float* adst1 = (const float*)d_in[13];
    const float* b1    = (const float*)d_in[14];
    const float* skip1 = (const float*)d_in[15];
    const float* bn1g  = (const float*)d_in[16];
    const float* bn1b  = (const float*)d_in[17];
    const float* bn1m  = (const float*)d_in[18];
    const float* bn1v  = (const float*)d_in[19];

    float* ws = (float*)d_ws;
    float* h0      = ws;                    // N*128
    float* s0      = h0 + (long)NN * 128;   // N*128
    float* out0    = s0 + (long)NN * 128;   // N*128
    float* a_src0  = out0 + (long)NN * 128; // N*8
    float* a_dst0  = a_src0 + NN * 8;       // N*8
    float* h1      = a_dst0 + NN * 8;       // N*16
    float* s1      = h1 + NN * 16;          // N*16
    float* a_src1  = s1 + NN * 16;          // N
    float* a_dst1  = a_src1 + NN;           // N
    int*   deg     = (int*)(a_dst1 + NN);   // N   (zeroed)
    int*   counter = deg + NN;              // 1   (zeroed, same memset)
    int*   rowbeg  = counter + 1;           // N
    int*   cursor  = rowbeg + NN;           // N
    int*   srcidx  = cursor + NN;           // E

    hipMemsetAsync(deg, 0, (size_t)(NN + 1) * 4, stream);

    // CSR build (independent of features; shared by both layers)
    k_hist<<<(EE + 255) / 256, 256, 0, stream>>>(ei, deg);
    k_rowoff<<<(NN + 255) / 256, 256, 0, stream>>>(deg, rowbeg, cursor, counter);
    k_scatter<<<(EE + 255) / 256, 256, 0, stream>>>(ei, cursor, srcidx);

    k_gemm0<<<NN / 16, 256, 0, stream>>>(x, w0, skip0, h0, s0);
    k_attn_coef0<<<(NN * NHEAD + 255) / 256, 256, 0, stream>>>(h0, asrc0, adst0, a_src0, a_dst0);
    k_agg0<<<(NN * 64 + 255) / 256, 256, 0, stream>>>(rowbeg, deg, srcidx, h0, a_src0, a_dst0, out0);
    k_post0<<<640, 256, 0, stream>>>(out0, s0, b0, bn0g, bn0b, bn0m, bn0v,
                                     w1, skip1, asrc1, adst1, h1, s1, a_src1, a_dst1);
    k_agg1_final<<<(NN * 16 + 255) / 256, 256, 0, stream>>>(rowbeg, deg, srcidx, h1, a_src1, a_dst1,
                                                            s1, b1, bn1g, bn1b, bn1m, bn1v,
                                                            (float*)d_out);
}

// Round 6
// 335.393 us; speedup vs baseline: 6.2962x; 1.1579x over previous
//
#include <hip/hip_runtime.h>
#include <hip/hip_bf16.h>

#define NN 50000
#define EE 800000
#define INDIM 128
#define HIDC 16
#define NHEAD 8

typedef __attribute__((ext_vector_type(8))) short bf16x8;
typedef __attribute__((ext_vector_type(4))) float f32x4;

__device__ __forceinline__ float bf2f(unsigned short u) {
    union { float f; unsigned int i; } v; v.i = ((unsigned int)u) << 16; return v.f;
}
__device__ __forceinline__ unsigned short f2bf(float f) {
    union { float f; unsigned int i; } v; v.f = f;
    unsigned int r = v.i + 0x7FFFu + ((v.i >> 16) & 1u);
    return (unsigned short)(r >> 16);
}

// ---------------------------------------------------------------------------
// K0a: convert x (fp32) -> xb (bf16). Elementwise, memory-bound.
// ---------------------------------------------------------------------------
__global__ __launch_bounds__(256) void k_cvt_x(const float* __restrict__ x,
                                               unsigned int* __restrict__ xb2)
{
    int i = blockIdx.x * 256 + threadIdx.x;          // one float4 per thread
    if (i >= NN * 128 / 4) return;
    float4 v = ((const float4*)x)[i];
    unsigned int lo = (unsigned int)f2bf(v.x) | ((unsigned int)f2bf(v.y) << 16);
    unsigned int hi = (unsigned int)f2bf(v.z) | ((unsigned int)f2bf(v.w) << 16);
    xb2[i * 2]     = lo;
    xb2[i * 2 + 1] = hi;
}

// ---------------------------------------------------------------------------
// K0b: convert weights -> wb (bf16): rows 0..127 = w0, 128..255 = skip0.
// ---------------------------------------------------------------------------
__global__ __launch_bounds__(256) void k_cvt_w(const float* __restrict__ w0,
                                               const float* __restrict__ skip0,
                                               unsigned int* __restrict__ wb2)
{
    int i = blockIdx.x * 256 + threadIdx.x;          // one float4 per thread
    if (i >= 256 * 128 / 4) return;
    const float4* src = (i < 128 * 128 / 4) ? ((const float4*)w0 + i)
                                            : ((const float4*)skip0 + (i - 128 * 128 / 4));
    float4 v = *src;
    wb2[i * 2]     = (unsigned int)f2bf(v.x) | ((unsigned int)f2bf(v.y) << 16);
    wb2[i * 2 + 1] = (unsigned int)f2bf(v.z) | ((unsigned int)f2bf(v.w) << 16);
}

// ---------------------------------------------------------------------------
// K1: fused GEMM  h0b = bf16(x @ w0^T) (cols 0..127), s0 = x @ skip0^T (128..255)
// Pure-bf16 MFMA 16x16x32. One block = 64 rows x 256 cols; 4 waves, each wave
// owns 64 cols, loops 4 row-subtiles of 16 with weights held in registers.
// ---------------------------------------------------------------------------
__global__ __launch_bounds__(256) void k_gemm0(
    const unsigned short* __restrict__ xb, const unsigned short* __restrict__ wb,
    unsigned short* __restrict__ h0b, float* __restrict__ s0)
{
    const int wave = threadIdx.x >> 6;
    const int lane = threadIdx.x & 63;
    const int lrow = lane & 15;
    const int quad = lane >> 4;
    const int rowbase = blockIdx.x * 64;

    bf16x8 bfrag[4][4];
    #pragma unroll
    for (int t = 0; t < 4; t++) {
        const int jg = wave * 64 + t * 16 + lrow;
        #pragma unroll
        for (int ki = 0; ki < 4; ki++)
            bfrag[t][ki] = *(const bf16x8*)(wb + (long)jg * 128 + ki * 32 + quad * 8);
    }

    #pragma unroll
    for (int sub = 0; sub < 4; sub++) {
        const int row0 = rowbase + sub * 16;
        if (row0 >= NN) break;
        const unsigned short* xrow = xb + (long)(row0 + lrow) * 128;
        bf16x8 afrag[4];
        #pragma unroll
        for (int ki = 0; ki < 4; ki++)
            afrag[ki] = *(const bf16x8*)(xrow + ki * 32 + quad * 8);

        f32x4 acc[4];
        #pragma unroll
        for (int t = 0; t < 4; t++) acc[t] = (f32x4){0.f, 0.f, 0.f, 0.f};

        #pragma unroll
        for (int ki = 0; ki < 4; ki++)
            #pragma unroll
            for (int t = 0; t < 4; t++)
                acc[t] = __builtin_amdgcn_mfma_f32_16x16x32_bf16(afrag[ki], bfrag[t][ki], acc[t], 0, 0, 0);

        // C/D layout: col = lane&15, row = (lane>>4)*4 + reg
        #pragma unroll
        for (int t = 0; t < 4; t++) {
            const int jg = wave * 64 + t * 16 + lrow;
            #pragma unroll
            for (int r = 0; r < 4; r++) {
                const int node = row0 + quad * 4 + r;
                if (jg < 128) h0b[(long)node * 128 + jg] = f2bf(acc[t][r]);
                else          s0[(long)node * 128 + (jg - 128)] = acc[t][r];
            }
        }
    }
}

// ---------------------------------------------------------------------------
// K1b: per-node attention coefficients  a_src0[n,h], a_dst0[n,h]  (bf16 h)
// ---------------------------------------------------------------------------
__global__ __launch_bounds__(256) void k_attn_coef0(
    const unsigned short* __restrict__ h0b, const float* __restrict__ asrc0,
    const float* __restrict__ adst0,
    float* __restrict__ a_src0, float* __restrict__ a_dst0)
{
    int idx = blockIdx.x * 256 + threadIdx.x;
    if (idx >= NN * NHEAD) return;
    int h = idx & 7, n = idx >> 3;
    const unsigned int* hp = (const unsigned int*)(h0b + (long)n * 128 + h * 16);
    const float* ap = asrc0 + h * 16;
    const float* dp = adst0 + h * 16;
    float s = 0.f, d = 0.f;
    #pragma unroll
    for (int q = 0; q < 8; q++) {
        unsigned int u = hp[q];
        float lo = bf2f((unsigned short)u);
        float hi = bf2f((unsigned short)(u >> 16));
        s += lo * ap[q * 2] + hi * ap[q * 2 + 1];
        d += lo * dp[q * 2] + hi * dp[q * 2 + 1];
    }
    a_src0[idx] = s;
    a_dst0[idx] = d;
}

// ---------------------------------------------------------------------------
// CSR build. Bucket offsets need NOT be an ordered prefix sum — any disjoint
// contiguous range per node works (consumers use beg + deg).
// ---------------------------------------------------------------------------
__global__ __launch_bounds__(256) void k_hist(const int* __restrict__ ei,
                                              int* __restrict__ deg)
{
    int e = blockIdx.x * 256 + threadIdx.x;
    if (e >= EE) return;
    atomicAdd(deg + ei[EE + e], 1);
}

__global__ __launch_bounds__(256) void k_rowoff(const int* __restrict__ deg,
                                                int* __restrict__ rowbeg,
                                                int* __restrict__ cursor,
                                                int* __restrict__ counter)
{
    __shared__ int wave_tot[4];
    __shared__ int blockbase;
    const int n = blockIdx.x * 256 + threadIdx.x;
    const int lane = threadIdx.x & 63;
    const int wid = threadIdx.x >> 6;
    int v = (n < NN) ? deg[n] : 0;
    int incl = v;
    #pragma unroll
    for (int off = 1; off < 64; off <<= 1) {
        int t = __shfl_up(incl, off);
        if (lane >= off) incl += t;
    }
    if (lane == 63) wave_tot[wid] = incl;
    __syncthreads();
    if (threadIdx.x == 0) {
        int tot = wave_tot[0] + wave_tot[1] + wave_tot[2] + wave_tot[3];
        blockbase = atomicAdd(counter, tot);
    }
    __syncthreads();
    int base = blockbase;
    for (int w = 0; w < wid; w++) base += wave_tot[w];
    if (n < NN) {
        int off = base + incl - v;
        rowbeg[n] = off;
        cursor[n] = off;
    }
}

__global__ __launch_bounds__(256) void k_scatter(const int* __restrict__ ei,
                                                 int* __restrict__ cursor,
                                                 int* __restrict__ srcidx)
{
    int e = blockIdx.x * 256 + threadIdx.x;
    if (e >= EE) return;
    int s = ei[e], d = ei[EE + e];
    int pos = atomicAdd(cursor + d, 1);
    srcidx[pos] = s;
}

// ---------------------------------------------------------------------------
// K3: layer-0 aggregation, gather-style, single pass w/ post-normalization:
//   out0[d] = (sum_i ex_i * h0[s_i]) / (sum_i ex_i + eps)
// One wave per dst node; lane owns channels {2*lane, 2*lane+1} (head lane>>3).
// 4x unrolled; h gathers are 4B bf16x2 (halved footprint -> better L2 hit).
// ---------------------------------------------------------------------------
__global__ __launch_bounds__(256) void k_agg0(
    const int* __restrict__ rowbeg, const int* __restrict__ deg,
    const int* __restrict__ srcidx,
    const unsigned short* __restrict__ h0b, const float* __restrict__ a_src0,
    const float* __restrict__ a_dst0, float* __restrict__ out0)
{
    const int d = (blockIdx.x * 256 + threadIdx.x) >> 6;  // one wave per node
    if (d >= NN) return;
    const int lane = threadIdx.x & 63;
    const int beg = rowbeg[d], end = beg + deg[d];
    const int h = lane >> 3;                              // head for this lane
    const int c = lane * 2;                               // (c>>4) == h
    const float adst = a_dst0[(long)d * 8 + h];

    float den0 = 0.f, den1 = 0.f, den2 = 0.f, den3 = 0.f;
    float2 ac0 = {0.f, 0.f}, ac1 = {0.f, 0.f}, ac2 = {0.f, 0.f}, ac3 = {0.f, 0.f};
    int i = beg;
    for (; i + 4 <= end; i += 4) {
        int sA = srcidx[i], sB = srcidx[i + 1], sC = srcidx[i + 2], sD = srcidx[i + 3];
        float aA = a_src0[(long)sA * 8 + h] + adst;
        float aB = a_src0[(long)sB * 8 + h] + adst;
        float aC = a_src0[(long)sC * 8 + h] + adst;
        float aD = a_src0[(long)sD * 8 + h] + adst;
        unsigned int uA = *(const unsigned int*)(h0b + (long)sA * 128 + c);
        unsigned int uB = *(const unsigned int*)(h0b + (long)sB * 128 + c);
        unsigned int uC = *(const unsigned int*)(h0b + (long)sC * 128 + c);
        unsigned int uD = *(const unsigned int*)(h0b + (long)sD * 128 + c);
        aA = aA > 0.f ? aA : 0.2f * aA;
        aB = aB > 0.f ? aB : 0.2f * aB;
        aC = aC > 0.f ? aC : 0.2f * aC;
        aD = aD > 0.f ? aD : 0.2f * aD;
        float eA = __expf(aA), eB = __expf(aB), eC = __expf(aC), eD = __expf(aD);
        den0 += eA; ac0.x += eA * bf2f((unsigned short)uA); ac0.y += eA * bf2f((unsigned short)(uA >> 16));
        den1 += eB; ac1.x += eB * bf2f((unsigned short)uB); ac1.y += eB * bf2f((unsigned short)(uB >> 16));
        den2 += eC; ac2.x += eC * bf2f((unsigned short)uC); ac2.y += eC * bf2f((unsigned short)(uC >> 16));
        den3 += eD; ac3.x += eD * bf2f((unsigned short)uD); ac3.y += eD * bf2f((unsigned short)(uD >> 16));
    }
    for (; i < end; i++) {
        int sA = srcidx[i];
        float aA = a_src0[(long)sA * 8 + h] + adst;
        unsigned int uA = *(const unsigned int*)(h0b + (long)sA * 128 + c);
        aA = aA > 0.f ? aA : 0.2f * aA;
        float eA = __expf(aA);
        den0 += eA; ac0.x += eA * bf2f((unsigned short)uA); ac0.y += eA * bf2f((unsigned short)(uA >> 16));
    }
    float den = (den0 + den1) + (den2 + den3);
    float ax = (ac0.x + ac1.x) + (ac2.x + ac3.x);
    float ay = (ac0.y + ac1.y) + (ac2.y + ac3.y);
    const float inv = 1.f / (den + 1e-16f);
    *(float2*)(out0 + (long)d * 128 + c) = make_float2(ax * inv, ay * inv);
}

// ---------------------------------------------------------------------------
// K4: per-node fused: BN0 + skip + ELU -> h_act (LDS only), then
//     h1 = h_act@w1^T, s1 = h_act@skip1^T, a_src1/a_dst1 from h1.
// One wave per node; 4 waves per block.
// ---------------------------------------------------------------------------
__global__ __launch_bounds__(256) void k_post0(
    const float* __restrict__ out0, const float* __restrict__ s0,
    const float* __restrict__ b0, const float* __restrict__ g0,
    const float* __restrict__ bb0, const float* __restrict__ m0,
    const float* __restrict__ v0,
    const float* __restrict__ w1, const float* __restrict__ skip1,
    const float* __restrict__ asrc1, const float* __restrict__ adst1,
    float* __restrict__ h1, float* __restrict__ s1,
    float* __restrict__ a_src1, float* __restrict__ a_dst1)
{
    __shared__ float wls[2 * 2048];     // [0]: w1T[c*16+j]  [2048]: skip1T[c*16+j]
    __shared__ float hrow[4][128];
    const int tid = threadIdx.x;
    for (int idx = tid; idx < 4096; idx += 256) {
        int half = idx >> 11;
        int r = idx & 2047;
        int c = r & 127, j = r >> 7;
        const float* src = half ? skip1 : w1;
        wls[half * 2048 + c * 16 + j] = src[j * 128 + c];
    }
    __syncthreads();

    const int lane = tid & 63, wave = tid >> 6;
    const int c0 = lane, c1 = lane + 64;
    const float A0 = g0[c0] * rsqrtf(v0[c0] + 1e-5f);
    const float B0 = (b0[c0] - m0[c0]) * A0 + bb0[c0];
    const float A1 = g0[c1] * rsqrtf(v0[c1] + 1e-5f);
    const float B1 = (b0[c1] - m0[c1]) * A1 + bb0[c1];
    const int j = lane & 15;
    const int grp = lane >> 4;
    const float avec = asrc1[j];
    const float dvec = adst1[j];
    const float* wbase = (grp & 1) ? (wls + 2048) : wls;  // grp0/2: w1, grp1/3: skip1
    const int coff = (grp >> 1) * 64;

    for (int n = blockIdx.x * 4 + wave; n < NN; n += gridDim.x * 4) {
        float x0 = out0[(long)n * 128 + c0] * A0 + B0 + s0[(long)n * 128 + c0];
        float x1 = out0[(long)n * 128 + c1] * A1 + B1 + s0[(long)n * 128 + c1];
        x0 = x0 > 0.f ? x0 : __expf(x0) - 1.f;
        x1 = x1 > 0.f ? x1 : __expf(x1) - 1.f;
        hrow[wave][c0] = x0;
        hrow[wave][c1] = x1;
        // wave-local LDS RAW: DS pipe processes a wave's ops in order
        float acc = 0.f;
        #pragma unroll 8
        for (int c = 0; c < 64; c++)
            acc += hrow[wave][coff + c] * wbase[(coff + c) * 16 + j];
        acc += __shfl_xor(acc, 32);
        // lanes 0-15 & 32-47: full h1[j]; lanes 16-31 & 48-63: full s1[j]
        if (grp == 0) h1[(long)n * 16 + j] = acc;
        if (grp == 1) s1[(long)n * 16 + j] = acc;
        float p = (grp == 0) ? acc * avec : (grp == 2 ? acc * dvec : 0.f);
        p += __shfl_xor(p, 1); p += __shfl_xor(p, 2);
        p += __shfl_xor(p, 4); p += __shfl_xor(p, 8);
        if (lane == 0)  a_src1[n] = p;
        if (lane == 32) a_dst1[n] = p;
    }
}

// ---------------------------------------------------------------------------
// K5: layer-1 aggregation + BN1 + skip + ELU -> d_out, gather-style,
// single pass w/ post-normalization. 16 threads per dst node. 4x unrolled.
// ---------------------------------------------------------------------------
__global__ __launch_bounds__(256) void k_agg1_final(
    const int* __restrict__ rowbeg, const int* __restrict__ deg,
    const int* __restrict__ srcidx,
    const float* __restrict__ h1, const float* __restrict__ a_src1,
    const float* __restrict__ a_dst1, const float* __restrict__ s1,
    const float* __restrict__ b1, const float* __restrict__ g1,
    const float* __restrict__ bb1, const float* __restrict__ m1,
    const float* __restrict__ v1, float* __restrict__ out)
{
    const int gid = blockIdx.x * 256 + threadIdx.x;
    const int d = gid >> 4;
    if (d >= NN) return;
    const int c = gid & 15;
    const int beg = rowbeg[d], end = beg + deg[d];
    const float adst = a_dst1[d];

    float den0 = 0.f, den1 = 0.f, den2 = 0.f, den3 = 0.f;
    float ac0 = 0.f, ac1 = 0.f, ac2 = 0.f, ac3 = 0.f;
    int i = beg;
    for (; i + 4 <= end; i += 4) {
        int sA = srcidx[i], sB = srcidx[i + 1], sC = srcidx[i + 2], sD = srcidx[i + 3];
        float aA = a_src1[sA] + adst;
        float aB = a_src1[sB] + adst;
        float aC = a_src1[sC] + adst;
        float aD = a_src1[sD] + adst;
        float hA = h1[(long)sA * 16 + c];
        float hB = h1[(long)sB * 16 + c];
        float hC = h1[(long)sC * 16 + c];
        float hD = h1[(long)sD * 16 + c];
        aA = aA > 0.f ? aA : 0.2f * aA;
        aB = aB > 0.f ? aB : 0.2f * aB;
        aC = aC > 0.f ? aC : 0.2f * aC;
        aD = aD > 0.f ? aD : 0.2f * aD;
        float eA = __expf(aA), eB = __expf(aB), eC = __expf(aC), eD = __expf(aD);
        den0 += eA; ac0 += eA * hA;
        den1 += eB; ac1 += eB * hB;
        den2 += eC; ac2 += eC * hC;
        den3 += eD; ac3 += eD * hD;
    }
    for (; i < end; i++) {
        int sA = srcidx[i];
        float aA = a_src1[sA] + adst;
        float hA = h1[(long)sA * 16 + c];
        aA = aA > 0.f ? aA : 0.2f * aA;
        float eA = __expf(aA);
        den0 += eA; ac0 += eA * hA;
    }
    float den = (den0 + den1) + (den2 + den3);
    float acc = (ac0 + ac1) + (ac2 + ac3);
    const float inv = 1.f / (den + 1e-16f);

    const float A = g1[c] * rsqrtf(v1[c] + 1e-5f);
    const float B = (b1[c] - m1[c]) * A + bb1[c];
    float v = acc * inv * A + B + s1[gid];
    v = v > 0.f ? v : __expf(v) - 1.f;
    out[gid] = v;
}

extern "C" void kernel_launch(void* const* d_in, const int* in_sizes, int n_in,
                              void* d_out, int out_size, void* d_ws, size_t ws_size,
                              hipStream_t stream)
{
    (void)in_sizes; (void)n_in; (void)out_size; (void)ws_size;
    const float* x     = (const float*)d_in[0];
    const int*   ei    = (const int*)d_in[1];
    const float* w0    = (const float*)d_in[2];
    const float* asrc0 = (const float*)d_in[3];
    const float* adst0 = (const float*)d_in[4];
    const float* b0    = (const float*)d_in[5];
    const float* skip0 = (const float*)d_in[6];
    const float* bn0g  = (const float*)d_in[7];
    const float* bn0b  = (const float*)d_in[8];
    const float* bn0m  = (const float*)d_in[9];
    const float* bn0v  = (const float*)d_in[10];
    const float* w1    = (const float*)d_in[11];
    const float* asrc1 = (const float*)d_in[12];
    const float* adst1 = (const float*)d_in[13];
    const float* b1    = (const float*)d_in[14];
    const float* skip1 = (const float*)d_in[15];
    const float* bn1g  = (const float*)d_in[16];
    const float* bn1b  = (const float*)d_in[17];
    const float* bn1m  = (const float*)d_in[18];
    const float* bn1v  = (const float*)d_in[19];

    float* ws = (float*)d_ws;
    unsigned short* xb  = (unsigned short*)ws;       // N*128 bf16  (N*64 f32 slots)
    unsigned short* wb  = xb + (long)NN * 128;       // 256*128 bf16
    unsigned short* h0b = wb + 256 * 128;            // N*128 bf16
    float* s0      = (float*)(h0b + (long)NN * 128); // N*128 f32
    float* out0    = s0 + (long)NN * 128;            // N*128
    float* a_src0  = out0 + (long)NN * 128;          // N*8
    float* a_dst0  = a_src0 + NN * 8;                // N*8
    float* h1      = a_dst0 + NN * 8;                // N*16
    float* s1      = h1 + NN * 16;                   // N*16
    float* a_src1  = s1 + NN * 16;                   // N
    float* a_dst1  = a_src1 + NN;                    // N
    int*   deg     = (int*)(a_dst1 + NN);            // N   (zeroed)
    int*   counter = deg + NN;                       // 1   (zeroed, same memset)
    int*   rowbeg  = counter + 1;                    // N
    int*   cursor  = rowbeg + NN;                    // N
    int*   srcidx  = cursor + NN;                    // E

    hipMemsetAsync(deg, 0, (size_t)(NN + 1) * 4, stream);

    // CSR build (independent of features; shared by both layers)
    k_hist<<<(EE + 255) / 256, 256, 0, stream>>>(ei, deg);
    k_rowoff<<<(NN + 255) / 256, 256, 0, stream>>>(deg, rowbeg, cursor, counter);
    k_scatter<<<(EE + 255) / 256, 256, 0, stream>>>(ei, cursor, srcidx);

    // bf16 conversions (once)
    k_cvt_x<<<(NN * 128 / 4 + 255) / 256, 256, 0, stream>>>(x, (unsigned int*)xb);
    k_cvt_w<<<(256 * 128 / 4 + 255) / 256, 256, 0, stream>>>(w0, skip0, (unsigned int*)wb);

    k_gemm0<<<(NN + 63) / 64, 256, 0, stream>>>(xb, wb, h0b, s0);
    k_attn_coef0<<<(NN * NHEAD + 255) / 256, 256, 0, stream>>>(h0b, asrc0, adst0, a_src0, a_dst0);
    k_agg0<<<(NN * 64 + 255) / 256, 256, 0, stream>>>(rowbeg, deg, srcidx, h0b, a_src0, a_dst0, out0);
    k_post0<<<640, 256, 0, stream>>>(out0, s0, b0, bn0g, bn0b, bn0m, bn0v,
                                     w1, skip1, asrc1, adst1, h1, s1, a_src1, a_dst1);
    k_agg1_final<<<(NN * 16 + 255) / 256, 256, 0, stream>>>(rowbeg, deg, srcidx, h1, a_src1, a_dst1,
                                                            s1, b1, bn1g, bn1b, bn1m, bn1v,
                                                            (float*)d_out);
}

// Round 7
// 288.805 us; speedup vs baseline: 7.3119x; 1.1613x over previous
//
#include <hip/hip_runtime.h>
#include <hip/hip_bf16.h>

#define NN 50000
#define EE 800000
#define INDIM 128
#define HIDC 16
#define NHEAD 8
#define COARSE 196          // ceil(NN/256)
#define EPB 2048            // edges per block in partition pass A
#define CAPB 8192           // per-coarse-bin capacity in pass B (avg ~4082)

typedef __attribute__((ext_vector_type(8))) short bf16x8;
typedef __attribute__((ext_vector_type(4))) float f32x4;

__device__ __forceinline__ float bf2f(unsigned short u) {
    union { float f; unsigned int i; } v; v.i = ((unsigned int)u) << 16; return v.f;
}
__device__ __forceinline__ unsigned short f2bf(float f) {
    union { float f; unsigned int i; } v; v.f = f;
    unsigned int r = v.i + 0x7FFFu + ((v.i >> 16) & 1u);
    return (unsigned short)(r >> 16);
}

// ---------------------------------------------------------------------------
// K0: fused fp32->bf16 conversion of x (first NX float4 blocks) and weights.
// ---------------------------------------------------------------------------
__global__ __launch_bounds__(256) void k_cvt(const float* __restrict__ x,
                                             const float* __restrict__ w0,
                                             const float* __restrict__ skip0,
                                             unsigned int* __restrict__ xb2,
                                             unsigned int* __restrict__ wb2)
{
    const long NX = (long)NN * 128 / 4;
    long i = (long)blockIdx.x * 256 + threadIdx.x;
    if (i < NX) {
        float4 v = ((const float4*)x)[i];
        xb2[i * 2]     = (unsigned int)f2bf(v.x) | ((unsigned int)f2bf(v.y) << 16);
        xb2[i * 2 + 1] = (unsigned int)f2bf(v.z) | ((unsigned int)f2bf(v.w) << 16);
    } else {
        long j = i - NX;
        if (j < 256 * 128 / 4) {
            const float4* src = (j < 128 * 128 / 4) ? ((const float4*)w0 + j)
                                                    : ((const float4*)skip0 + (j - 128 * 128 / 4));
            float4 v = *src;
            wb2[j * 2]     = (unsigned int)f2bf(v.x) | ((unsigned int)f2bf(v.y) << 16);
            wb2[j * 2 + 1] = (unsigned int)f2bf(v.z) | ((unsigned int)f2bf(v.w) << 16);
        }
    }
}

// ---------------------------------------------------------------------------
// CSR build, dense-write partition sort.
// Pass 0: coarse histogram (196 bins = dst>>8).
// ---------------------------------------------------------------------------
__global__ __launch_bounds__(256) void k_chist(const int* __restrict__ ei,
                                               int* __restrict__ ccnt)
{
    __shared__ int h[256];
    h[threadIdx.x] = 0;
    __syncthreads();
    int base = blockIdx.x * 1024 + threadIdx.x;
    #pragma unroll
    for (int k = 0; k < 4; k++) {
        int e = base + k * 256;
        if (e < EE) atomicAdd(&h[ei[EE + e] >> 8], 1);
    }
    __syncthreads();
    if (threadIdx.x < COARSE && h[threadIdx.x])
        atomicAdd(&ccnt[threadIdx.x], h[threadIdx.x]);
}

// Ordered exclusive scan of the 196 coarse counts (1 block).
__global__ __launch_bounds__(256) void k_cbase(const int* __restrict__ ccnt,
                                               int* __restrict__ cbase,
                                               int* __restrict__ ccur)
{
    __shared__ int s[256];
    const int t = threadIdx.x;
    int v = (t < COARSE) ? ccnt[t] : 0;
    s[t] = v;
    __syncthreads();
    for (int off = 1; off < 256; off <<= 1) {
        int u = (t >= off) ? s[t - off] : 0;
        __syncthreads();
        s[t] += u;
        __syncthreads();
    }
    if (t < COARSE) { int ex = s[t] - v; cbase[t] = ex; ccur[t] = ex; }
    if (t == 255) cbase[COARSE] = s[255];
}

// Pass A: coarse scatter of packed (dst<<32|src) with LDS staging so global
// writes are contiguous runs (dense cachelines).
__global__ __launch_bounds__(256) void k_partA(const int* __restrict__ ei,
                                               int* __restrict__ ccur,
                                               unsigned long long* __restrict__ pairs)
{
    __shared__ int bcnt[256];
    __shared__ int lofs[256];
    __shared__ int gofs[256];
    __shared__ unsigned long long stage[EPB];
    __shared__ int gpos[EPB];
    const int t = threadIdx.x;
    const int e0 = blockIdx.x * EPB;

    bcnt[t] = 0;
    __syncthreads();

    int mybin[8], myrank[8];
    unsigned long long mypair[8];
    #pragma unroll
    for (int k = 0; k < 8; k++) {
        int e = e0 + k * 256 + t;
        mybin[k] = -1;
        if (e < EE) {
            int s = ei[e], d = ei[EE + e];
            int b = d >> 8;
            myrank[k] = atomicAdd(&bcnt[b], 1);
            mybin[k] = b;
            mypair[k] = ((unsigned long long)(unsigned)d << 32) | (unsigned)s;
        }
    }
    __syncthreads();

    int v = bcnt[t];
    lofs[t] = v;
    __syncthreads();
    for (int off = 1; off < 256; off <<= 1) {
        int u = (t >= off) ? lofs[t - off] : 0;
        __syncthreads();
        lofs[t] += u;
        __syncthreads();
    }
    if (t < COARSE && v > 0) gofs[t] = atomicAdd(&ccur[t], v);
    __syncthreads();

    #pragma unroll
    for (int k = 0; k < 8; k++) {
        int b = mybin[k];
        if (b >= 0) {
            int slot = (lofs[b] - bcnt[b]) + myrank[k];
            stage[slot] = mypair[k];
            gpos[slot]  = gofs[b] + myrank[k];
        }
    }
    __syncthreads();

    const int total = lofs[255];
    for (int i = t; i < total; i += 256)
        pairs[gpos[i]] = stage[i];
}

// Pass B: one block per coarse bin. LDS counting-sort by exact dst; emits
// rowbeg/deg AND fully-contiguous srcidx (uint16).
__global__ __launch_bounds__(256) void k_partB(const unsigned long long* __restrict__ pairs,
                                               const int* __restrict__ cbase,
                                               unsigned short* __restrict__ srcidx,
                                               int* __restrict__ rowbeg,
                                               int* __restrict__ deg)
{
    __shared__ int fcnt[256], fofs[256], fcur[256];
    __shared__ unsigned short stage[CAPB];
    const int b = blockIdx.x, t = threadIdx.x;
    const int beg = cbase[b], end = cbase[b + 1];
    const int cnt = end - beg;

    fcnt[t] = 0;
    __syncthreads();
    for (int i = t; i < cnt; i += 256) {
        int d = (int)(pairs[beg + i] >> 32);
        atomicAdd(&fcnt[d & 255], 1);
    }
    __syncthreads();

    int v = fcnt[t];
    fofs[t] = v;
    __syncthreads();
    for (int off = 1; off < 256; off <<= 1) {
        int u = (t >= off) ? fofs[t - off] : 0;
        __syncthreads();
        fofs[t] += u;
        __syncthreads();
    }
    int ex = fofs[t] - v;
    int node = b * 256 + t;
    if (node < NN) { rowbeg[node] = beg + ex; deg[node] = v; }
    fcur[t] = ex;
    __syncthreads();

    const bool ovf = (cnt > CAPB);
    for (int i = t; i < cnt; i += 256) {
        unsigned long long p = pairs[beg + i];
        int d = (int)(p >> 32);
        int slot = atomicAdd(&fcur[d & 255], 1);
        unsigned short s = (unsigned short)(p & 0xFFFFu);   // src < 65536
        if (!ovf) stage[slot] = s;
        else      srcidx[beg + slot] = s;                   // fallback (never for random input)
    }
    __syncthreads();
    if (!ovf)
        for (int i = t; i < cnt; i += 256)
            srcidx[beg + i] = stage[i];
}

// ---------------------------------------------------------------------------
// K1: fused GEMM  h0b = bf16(x@w0^T), s0b = bf16(x@skip0^T), PLUS attention
// coefficients a_src0/a_dst0 folded into the epilogue (waves 0,1; head=4w+t).
// One block = 64 rows x 256 cols; 4 waves; weights live in registers.
// ---------------------------------------------------------------------------
__global__ __launch_bounds__(256) void k_gemm0(
    const unsigned short* __restrict__ xb, const unsigned short* __restrict__ wb,
    const float* __restrict__ asrc0, const float* __restrict__ adst0,
    unsigned short* __restrict__ h0b, unsigned short* __restrict__ s0b,
    float* __restrict__ a_src0, float* __restrict__ a_dst0)
{
    const int wave = threadIdx.x >> 6;
    const int lane = threadIdx.x & 63;
    const int lrow = lane & 15;
    const int quad = lane >> 4;
    const int rowbase = blockIdx.x * 64;

    bf16x8 bfrag[4][4];
    float asv[4], adv[4];
    #pragma unroll
    for (int t = 0; t < 4; t++) {
        const int jg = wave * 64 + t * 16 + lrow;
        #pragma unroll
        for (int ki = 0; ki < 4; ki++)
            bfrag[t][ki] = *(const bf16x8*)(wb + (long)jg * 128 + ki * 32 + quad * 8);
        if (wave < 2) { asv[t] = asrc0[jg]; adv[t] = adst0[jg]; }
    }

    #pragma unroll
    for (int sub = 0; sub < 4; sub++) {
        const int row0 = rowbase + sub * 16;
        if (row0 >= NN) break;
        const unsigned short* xrow = xb + (long)(row0 + lrow) * 128;
        bf16x8 afrag[4];
        #pragma unroll
        for (int ki = 0; ki < 4; ki++)
            afrag[ki] = *(const bf16x8*)(xrow + ki * 32 + quad * 8);

        f32x4 acc[4];
        #pragma unroll
        for (int t = 0; t < 4; t++) acc[t] = (f32x4){0.f, 0.f, 0.f, 0.f};

        #pragma unroll
        for (int ki = 0; ki < 4; ki++)
            #pragma unroll
            for (int t = 0; t < 4; t++)
                acc[t] = __builtin_amdgcn_mfma_f32_16x16x32_bf16(afrag[ki], bfrag[t][ki], acc[t], 0, 0, 0);

        // C/D layout: col = lane&15, row = (lane>>4)*4 + reg
        if (wave < 2) {
            #pragma unroll
            for (int t = 0; t < 4; t++) {
                const int jg = wave * 64 + t * 16 + lrow;
                #pragma unroll
                for (int r = 0; r < 4; r++) {
                    const int n = row0 + quad * 4 + r;
                    float val = acc[t][r];
                    h0b[(long)n * 128 + jg] = f2bf(val);
                    float ps = val * asv[t];
                    float pd = val * adv[t];
                    ps += __shfl_xor(ps, 1); ps += __shfl_xor(ps, 2);
                    ps += __shfl_xor(ps, 4); ps += __shfl_xor(ps, 8);
                    pd += __shfl_xor(pd, 1); pd += __shfl_xor(pd, 2);
                    pd += __shfl_xor(pd, 4); pd += __shfl_xor(pd, 8);
                    if (lrow == 0) {
                        const int h = wave * 4 + t;
                        a_src0[(long)n * 8 + h] = ps;
                        a_dst0[(long)n * 8 + h] = pd;
                    }
                }
            }
        } else {
            #pragma unroll
            for (int t = 0; t < 4; t++) {
                const int jg = wave * 64 + t * 16 + lrow - 128;
                #pragma unroll
                for (int r = 0; r < 4; r++) {
                    const int n = row0 + quad * 4 + r;
                    s0b[(long)n * 128 + jg] = f2bf(acc[t][r]);
                }
            }
        }
    }
}

// ---------------------------------------------------------------------------
// K3: layer-0 aggregation, gather-style, single pass w/ post-normalization.
// One wave per dst node; lane owns channels {2*lane,2*lane+1}; out0 in bf16.
// ---------------------------------------------------------------------------
__global__ __launch_bounds__(256) void k_agg0(
    const int* __restrict__ rowbeg, const int* __restrict__ deg,
    const unsigned short* __restrict__ srcidx,
    const unsigned short* __restrict__ h0b, const float* __restrict__ a_src0,
    const float* __restrict__ a_dst0, unsigned int* __restrict__ out0b2)
{
    const int d = (blockIdx.x * 256 + threadIdx.x) >> 6;  // one wave per node
    if (d >= NN) return;
    const int lane = threadIdx.x & 63;
    const int beg = rowbeg[d], end = beg + deg[d];
    const int h = lane >> 3;
    const int c = lane * 2;
    const float adst = a_dst0[(long)d * 8 + h];

    float den0 = 0.f, den1 = 0.f, den2 = 0.f, den3 = 0.f;
    float2 ac0 = {0.f, 0.f}, ac1 = {0.f, 0.f}, ac2 = {0.f, 0.f}, ac3 = {0.f, 0.f};
    int i = beg;
    for (; i + 4 <= end; i += 4) {
        int sA = srcidx[i], sB = srcidx[i + 1], sC = srcidx[i + 2], sD = srcidx[i + 3];
        float aA = a_src0[(long)sA * 8 + h] + adst;
        float aB = a_src0[(long)sB * 8 + h] + adst;
        float aC = a_src0[(long)sC * 8 + h] + adst;
        float aD = a_src0[(long)sD * 8 + h] + adst;
        unsigned int uA = *(const unsigned int*)(h0b + (long)sA * 128 + c);
        unsigned int uB = *(const unsigned int*)(h0b + (long)sB * 128 + c);
        unsigned int uC = *(const unsigned int*)(h0b + (long)sC * 128 + c);
        unsigned int uD = *(const unsigned int*)(h0b + (long)sD * 128 + c);
        aA = aA > 0.f ? aA : 0.2f * aA;
        aB = aB > 0.f ? aB : 0.2f * aB;
        aC = aC > 0.f ? aC : 0.2f * aC;
        aD = aD > 0.f ? aD : 0.2f * aD;
        float eA = __expf(aA), eB = __expf(aB), eC = __expf(aC), eD = __expf(aD);
        den0 += eA; ac0.x += eA * bf2f((unsigned short)uA); ac0.y += eA * bf2f((unsigned short)(uA >> 16));
        den1 += eB; ac1.x += eB * bf2f((unsigned short)uB); ac1.y += eB * bf2f((unsigned short)(uB >> 16));
        den2 += eC; ac2.x += eC * bf2f((unsigned short)uC); ac2.y += eC * bf2f((unsigned short)(uC >> 16));
        den3 += eD; ac3.x += eD * bf2f((unsigned short)uD); ac3.y += eD * bf2f((unsigned short)(uD >> 16));
    }
    for (; i < end; i++) {
        int sA = srcidx[i];
        float aA = a_src0[(long)sA * 8 + h] + adst;
        unsigned int uA = *(const unsigned int*)(h0b + (long)sA * 128 + c);
        aA = aA > 0.f ? aA : 0.2f * aA;
        float eA = __expf(aA);
        den0 += eA; ac0.x += eA * bf2f((unsigned short)uA); ac0.y += eA * bf2f((unsigned short)(uA >> 16));
    }
    float den = (den0 + den1) + (den2 + den3);
    float ax = (ac0.x + ac1.x) + (ac2.x + ac3.x);
    float ay = (ac0.y + ac1.y) + (ac2.y + ac3.y);
    const float inv = 1.f / (den + 1e-16f);
    out0b2[(long)d * 64 + lane] =
        (unsigned int)f2bf(ax * inv) | ((unsigned int)f2bf(ay * inv) << 16);
}

// ---------------------------------------------------------------------------
// K4: per-node fused: BN0 + skip + ELU (bf16 in), then h1b/s1/a_src1/a_dst1.
// One wave per node; 4 waves per block.
// ---------------------------------------------------------------------------
__global__ __launch_bounds__(256) void k_post0(
    const unsigned short* __restrict__ out0b, const unsigned short* __restrict__ s0b,
    const float* __restrict__ b0, const float* __restrict__ g0,
    const float* __restrict__ bb0, const float* __restrict__ m0,
    const float* __restrict__ v0,
    const float* __restrict__ w1, const float* __restrict__ skip1,
    const float* __restrict__ asrc1, const float* __restrict__ adst1,
    unsigned short* __restrict__ h1b, float* __restrict__ s1,
    float* __restrict__ a_src1, float* __restrict__ a_dst1)
{
    __shared__ float wls[2 * 2048];     // [0]: w1T[c*16+j]  [2048]: skip1T[c*16+j]
    __shared__ float hrow[4][128];
    const int tid = threadIdx.x;
    for (int idx = tid; idx < 4096; idx += 256) {
        int half = idx >> 11;
        int r = idx & 2047;
        int c = r & 127, j = r >> 7;
        const float* src = half ? skip1 : w1;
        wls[half * 2048 + c * 16 + j] = src[j * 128 + c];
    }
    __syncthreads();

    const int lane = tid & 63, wave = tid >> 6;
    const int c0 = lane, c1 = lane + 64;
    const float A0 = g0[c0] * rsqrtf(v0[c0] + 1e-5f);
    const float B0 = (b0[c0] - m0[c0]) * A0 + bb0[c0];
    const float A1 = g0[c1] * rsqrtf(v0[c1] + 1e-5f);
    const float B1 = (b0[c1] - m0[c1]) * A1 + bb0[c1];
    const int j = lane & 15;
    const int grp = lane >> 4;
    const float avec = asrc1[j];
    const float dvec = adst1[j];
    const float* wbase = (grp & 1) ? (wls + 2048) : wls;
    const int coff = (grp >> 1) * 64;

    for (int n = blockIdx.x * 4 + wave; n < NN; n += gridDim.x * 4) {
        float x0 = bf2f(out0b[(long)n * 128 + c0]) * A0 + B0 + bf2f(s0b[(long)n * 128 + c0]);
        float x1 = bf2f(out0b[(long)n * 128 + c1]) * A1 + B1 + bf2f(s0b[(long)n * 128 + c1]);
        x0 = x0 > 0.f ? x0 : __expf(x0) - 1.f;
        x1 = x1 > 0.f ? x1 : __expf(x1) - 1.f;
        hrow[wave][c0] = x0;
        hrow[wave][c1] = x1;
        float acc = 0.f;
        #pragma unroll 8
        for (int c = 0; c < 64; c++)
            acc += hrow[wave][coff + c] * wbase[(coff + c) * 16 + j];
        acc += __shfl_xor(acc, 32);
        if (grp == 0) h1b[(long)n * 16 + j] = f2bf(acc);
        if (grp == 1) s1[(long)n * 16 + j] = acc;
        float p = (grp == 0) ? acc * avec : (grp == 2 ? acc * dvec : 0.f);
        p += __shfl_xor(p, 1); p += __shfl_xor(p, 2);
        p += __shfl_xor(p, 4); p += __shfl_xor(p, 8);
        if (lane == 0)  a_src1[n] = p;
        if (lane == 32) a_dst1[n] = p;
    }
}

// ---------------------------------------------------------------------------
// K5: layer-1 aggregation + BN1 + skip + ELU -> d_out. 16 threads/node.
// ---------------------------------------------------------------------------
__global__ __launch_bounds__(256) void k_agg1_final(
    const int* __restrict__ rowbeg, const int* __restrict__ deg,
    const unsigned short* __restrict__ srcidx,
    const unsigned short* __restrict__ h1b, const float* __restrict__ a_src1,
    const float* __restrict__ a_dst1, const float* __restrict__ s1,
    const float* __restrict__ b1, const float* __restrict__ g1,
    const float* __restrict__ bb1, const float* __restrict__ m1,
    const float* __restrict__ v1, float* __restrict__ out)
{
    const int gid = blockIdx.x * 256 + threadIdx.x;
    const int d = gid >> 4;
    if (d >= NN) return;
    const int c = gid & 15;
    const int beg = rowbeg[d], end = beg + deg[d];
    const float adst = a_dst1[d];

    float den0 = 0.f, den1 = 0.f, den2 = 0.f, den3 = 0.f;
    float ac0 = 0.f, ac1 = 0.f, ac2 = 0.f, ac3 = 0.f;
    int i = beg;
    for (; i + 4 <= end; i += 4) {
        int sA = srcidx[i], sB = srcidx[i + 1], sC = srcidx[i + 2], sD = srcidx[i + 3];
        float aA = a_src1[sA] + adst;
        float aB = a_src1[sB] + adst;
        float aC = a_src1[sC] + adst;
        float aD = a_src1[sD] + adst;
        float hA = bf2f(h1b[(long)sA * 16 + c]);
        float hB = bf2f(h1b[(long)sB * 16 + c]);
        float hC = bf2f(h1b[(long)sC * 16 + c]);
        float hD = bf2f(h1b[(long)sD * 16 + c]);
        aA = aA > 0.f ? aA : 0.2f * aA;
        aB = aB > 0.f ? aB : 0.2f * aB;
        aC = aC > 0.f ? aC : 0.2f * aC;
        aD = aD > 0.f ? aD : 0.2f * aD;
        float eA = __expf(aA), eB = __expf(aB), eC = __expf(aC), eD = __expf(aD);
        den0 += eA; ac0 += eA * hA;
        den1 += eB; ac1 += eB * hB;
        den2 += eC; ac2 += eC * hC;
        den3 += eD; ac3 += eD * hD;
    }
    for (; i < end; i++) {
        int sA = srcidx[i];
        float aA = a_src1[sA] + adst;
        float hA = bf2f(h1b[(long)sA * 16 + c]);
        aA = aA > 0.f ? aA : 0.2f * aA;
        float eA = __expf(aA);
        den0 += eA; ac0 += eA * hA;
    }
    float den = (den0 + den1) + (den2 + den3);
    float acc = (ac0 + ac1) + (ac2 + ac3);
    const float inv = 1.f / (den + 1e-16f);

    const float A = g1[c] * rsqrtf(v1[c] + 1e-5f);
    const float B = (b1[c] - m1[c]) * A + bb1[c];
    float v = acc * inv * A + B + s1[gid];
    v = v > 0.f ? v : __expf(v) - 1.f;
    out[gid] = v;
}

extern "C" void kernel_launch(void* const* d_in, const int* in_sizes, int n_in,
                              void* d_out, int out_size, void* d_ws, size_t ws_size,
                              hipStream_t stream)
{
    (void)in_sizes; (void)n_in; (void)out_size; (void)ws_size;
    const float* x     = (const float*)d_in[0];
    const int*   ei    = (const int*)d_in[1];
    const float* w0    = (const float*)d_in[2];
    const float* asrc0 = (const float*)d_in[3];
    const float* adst0 = (const float*)d_in[4];
    const float* b0    = (const float*)d_in[5];   (void)b0; // bias0 (zeros) folded via BN path below
    const float* skip0 = (const float*)d_in[6];
    const float* bn0g  = (const float*)d_in[7];
    const float* bn0b  = (const float*)d_in[8];
    const float* bn0m  = (const float*)d_in[9];
    const float* bn0v  = (const float*)d_in[10];
    const float* w1    = (const float*)d_in[11];
    const float* asrc1 = (const float*)d_in[12];
    const float* adst1 = (const float*)d_in[13];
    const float* b1    = (const float*)d_in[14];
    const float* skip1 = (const float*)d_in[15];
    const float* bn1g  = (const float*)d_in[16];
    const float* bn1b  = (const float*)d_in[17];
    const float* bn1m  = (const float*)d_in[18];
    const float* bn1v  = (const float*)d_in[19];

    // workspace layout (pairs first for 8B alignment)
    unsigned long long* pairs = (unsigned long long*)d_ws;          // EE
    unsigned short* xb    = (unsigned short*)(pairs + EE);          // NN*128
    unsigned short* wb    = xb + (long)NN * 128;                    // 256*128
    unsigned short* h0b   = wb + 256 * 128;                         // NN*128
    unsigned short* s0b   = h0b + (long)NN * 128;                   // NN*128
    unsigned short* out0b = s0b + (long)NN * 128;                   // NN*128
    unsigned short* h1b   = out0b + (long)NN * 128;                 // NN*16
    unsigned short* srcidx= h1b + (long)NN * 16;                    // EE
    float* a_src0 = (float*)(srcidx + EE);                          // NN*8
    float* a_dst0 = a_src0 + (long)NN * 8;                          // NN*8
    float* s1     = a_dst0 + (long)NN * 8;                          // NN*16
    float* a_src1 = s1 + (long)NN * 16;                             // NN
    float* a_dst1 = a_src1 + NN;                                    // NN
    int* ccnt   = (int*)(a_dst1 + NN);                              // COARSE (zeroed)
    int* cbase  = ccnt + COARSE;                                    // COARSE+1
    int* ccur   = cbase + COARSE + 1;                               // COARSE
    int* rowbeg = ccur + COARSE;                                    // NN
    int* deg    = rowbeg + NN;                                      // NN

    hipMemsetAsync(ccnt, 0, (size_t)COARSE * 4, stream);

    // bf16 conversions (x + weights, one kernel)
    const long NX = (long)NN * 128 / 4;
    k_cvt<<<(unsigned)((NX + 256 * 128 / 4 + 255) / 256), 256, 0, stream>>>(
        x, w0, skip0, (unsigned int*)xb, (unsigned int*)wb);

    // CSR build: dense-write partition sort (shared by both layers)
    k_chist<<<(EE + 1023) / 1024, 256, 0, stream>>>(ei, ccnt);
    k_cbase<<<1, 256, 0, stream>>>(ccnt, cbase, ccur);
    k_partA<<<(EE + EPB - 1) / EPB, 256, 0, stream>>>(ei, ccur, pairs);
    k_partB<<<COARSE, 256, 0, stream>>>(pairs, cbase, srcidx, rowbeg, deg);

    // layer 0
    k_gemm0<<<(NN + 63) / 64, 256, 0, stream>>>(xb, wb, asrc0, adst0,
                                                h0b, s0b, a_src0, a_dst0);
    k_agg0<<<(NN * 64 + 255) / 256, 256, 0, stream>>>(rowbeg, deg, srcidx, h0b,
                                                      a_src0, a_dst0, (unsigned int*)out0b);
    k_post0<<<640, 256, 0, stream>>>(out0b, s0b, b0, bn0g, bn0b, bn0m, bn0v,
                                     w1, skip1, asrc1, adst1, h1b, s1, a_src1, a_dst1);
    // layer 1 + epilogue
    k_agg1_final<<<(NN * 16 + 255) / 256, 256, 0, stream>>>(rowbeg, deg, srcidx, h1b,
                                                            a_src1, a_dst1, s1,
                                                            b1, bn1g, bn1b, bn1m, bn1v,
                                                            (float*)d_out);
}

// Round 8
// 259.042 us; speedup vs baseline: 8.1520x; 1.1149x over previous
//
#include <hip/hip_runtime.h>
#include <hip/hip_bf16.h>

#define NN 50000
#define EE 800000
#define INDIM 128
#define HIDC 16
#define NHEAD 8
#define COARSE 196          // ceil(NN/256)
#define EPB 2048            // edges per block in partition pass A
#define CAPB 8192           // per-coarse-bin capacity in pass B (avg ~4082)

typedef __attribute__((ext_vector_type(8))) short bf16x8;
typedef __attribute__((ext_vector_type(4))) float f32x4;

__device__ __forceinline__ float bf2f(unsigned short u) {
    union { float f; unsigned int i; } v; v.i = ((unsigned int)u) << 16; return v.f;
}
__device__ __forceinline__ unsigned short f2bf(float f) {
    union { float f; unsigned int i; } v; v.f = f;
    unsigned int r = v.i + 0x7FFFu + ((v.i >> 16) & 1u);
    return (unsigned short)(r >> 16);
}

// ---------------------------------------------------------------------------
// K0: fp32->bf16 conversions: x, [w0|skip0] (GEMM0 B), [w1|skip1] (POST0 B).
// ---------------------------------------------------------------------------
__global__ __launch_bounds__(256) void k_cvt(const float* __restrict__ x,
                                             const float* __restrict__ w0,
                                             const float* __restrict__ skip0,
                                             const float* __restrict__ w1,
                                             const float* __restrict__ skip1,
                                             unsigned int* __restrict__ xb2,
                                             unsigned int* __restrict__ wb2,
                                             unsigned int* __restrict__ wb1_2)
{
    const long NX = (long)NN * 128 / 4;      // x float4 blocks
    const long NW = 256 * 128 / 4;           // w0|skip0
    const long NW1 = 32 * 128 / 4;           // w1|skip1
    long i = (long)blockIdx.x * 256 + threadIdx.x;
    if (i < NX) {
        float4 v = ((const float4*)x)[i];
        xb2[i * 2]     = (unsigned int)f2bf(v.x) | ((unsigned int)f2bf(v.y) << 16);
        xb2[i * 2 + 1] = (unsigned int)f2bf(v.z) | ((unsigned int)f2bf(v.w) << 16);
    } else if (i < NX + NW) {
        long j = i - NX;
        const float4* src = (j < 128 * 128 / 4) ? ((const float4*)w0 + j)
                                                : ((const float4*)skip0 + (j - 128 * 128 / 4));
        float4 v = *src;
        wb2[j * 2]     = (unsigned int)f2bf(v.x) | ((unsigned int)f2bf(v.y) << 16);
        wb2[j * 2 + 1] = (unsigned int)f2bf(v.z) | ((unsigned int)f2bf(v.w) << 16);
    } else if (i < NX + NW + NW1) {
        long j = i - NX - NW;
        const float4* src = (j < 16 * 128 / 4) ? ((const float4*)w1 + j)
                                               : ((const float4*)skip1 + (j - 16 * 128 / 4));
        float4 v = *src;
        wb1_2[j * 2]     = (unsigned int)f2bf(v.x) | ((unsigned int)f2bf(v.y) << 16);
        wb1_2[j * 2 + 1] = (unsigned int)f2bf(v.z) | ((unsigned int)f2bf(v.w) << 16);
    }
}

// ---------------------------------------------------------------------------
// CSR build, dense-write partition sort.
// ---------------------------------------------------------------------------
__global__ __launch_bounds__(256) void k_chist(const int* __restrict__ ei,
                                               int* __restrict__ ccnt)
{
    __shared__ int h[256];
    h[threadIdx.x] = 0;
    __syncthreads();
    int base = blockIdx.x * 1024 + threadIdx.x;
    #pragma unroll
    for (int k = 0; k < 4; k++) {
        int e = base + k * 256;
        if (e < EE) atomicAdd(&h[ei[EE + e] >> 8], 1);
    }
    __syncthreads();
    if (threadIdx.x < COARSE && h[threadIdx.x])
        atomicAdd(&ccnt[threadIdx.x], h[threadIdx.x]);
}

__global__ __launch_bounds__(256) void k_cbase(const int* __restrict__ ccnt,
                                               int* __restrict__ cbase,
                                               int* __restrict__ ccur)
{
    __shared__ int s[256];
    const int t = threadIdx.x;
    int v = (t < COARSE) ? ccnt[t] : 0;
    s[t] = v;
    __syncthreads();
    for (int off = 1; off < 256; off <<= 1) {
        int u = (t >= off) ? s[t - off] : 0;
        __syncthreads();
        s[t] += u;
        __syncthreads();
    }
    if (t < COARSE) { int ex = s[t] - v; cbase[t] = ex; ccur[t] = ex; }
    if (t == 255) cbase[COARSE] = s[255];
}

__global__ __launch_bounds__(256) void k_partA(const int* __restrict__ ei,
                                               int* __restrict__ ccur,
                                               unsigned long long* __restrict__ pairs)
{
    __shared__ int bcnt[256];
    __shared__ int lofs[256];
    __shared__ int gofs[256];
    __shared__ unsigned long long stage[EPB];
    __shared__ int gpos[EPB];
    const int t = threadIdx.x;
    const int e0 = blockIdx.x * EPB;

    bcnt[t] = 0;
    __syncthreads();

    int mybin[8], myrank[8];
    unsigned long long mypair[8];
    #pragma unroll
    for (int k = 0; k < 8; k++) {
        int e = e0 + k * 256 + t;
        mybin[k] = -1;
        if (e < EE) {
            int s = ei[e], d = ei[EE + e];
            int b = d >> 8;
            myrank[k] = atomicAdd(&bcnt[b], 1);
            mybin[k] = b;
            mypair[k] = ((unsigned long long)(unsigned)d << 32) | (unsigned)s;
        }
    }
    __syncthreads();

    int v = bcnt[t];
    lofs[t] = v;
    __syncthreads();
    for (int off = 1; off < 256; off <<= 1) {
        int u = (t >= off) ? lofs[t - off] : 0;
        __syncthreads();
        lofs[t] += u;
        __syncthreads();
    }
    if (t < COARSE && v > 0) gofs[t] = atomicAdd(&ccur[t], v);
    __syncthreads();

    #pragma unroll
    for (int k = 0; k < 8; k++) {
        int b = mybin[k];
        if (b >= 0) {
            int slot = (lofs[b] - bcnt[b]) + myrank[k];
            stage[slot] = mypair[k];
            gpos[slot]  = gofs[b] + myrank[k];
        }
    }
    __syncthreads();

    const int total = lofs[255];
    for (int i = t; i < total; i += 256)
        pairs[gpos[i]] = stage[i];
}

__global__ __launch_bounds__(256) void k_partB(const unsigned long long* __restrict__ pairs,
                                               const int* __restrict__ cbase,
                                               unsigned short* __restrict__ srcidx,
                                               int* __restrict__ rowbeg,
                                               int* __restrict__ deg)
{
    __shared__ int fcnt[256], fofs[256], fcur[256];
    __shared__ unsigned short stage[CAPB];
    const int b = blockIdx.x, t = threadIdx.x;
    const int beg = cbase[b], end = cbase[b + 1];
    const int cnt = end - beg;

    fcnt[t] = 0;
    __syncthreads();
    for (int i = t; i < cnt; i += 256) {
        int d = (int)(pairs[beg + i] >> 32);
        atomicAdd(&fcnt[d & 255], 1);
    }
    __syncthreads();

    int v = fcnt[t];
    fofs[t] = v;
    __syncthreads();
    for (int off = 1; off < 256; off <<= 1) {
        int u = (t >= off) ? fofs[t - off] : 0;
        __syncthreads();
        fofs[t] += u;
        __syncthreads();
    }
    int ex = fofs[t] - v;
    int node = b * 256 + t;
    if (node < NN) { rowbeg[node] = beg + ex; deg[node] = v; }
    fcur[t] = ex;
    __syncthreads();

    const bool ovf = (cnt > CAPB);
    for (int i = t; i < cnt; i += 256) {
        unsigned long long p = pairs[beg + i];
        int d = (int)(p >> 32);
        int slot = atomicAdd(&fcur[d & 255], 1);
        unsigned short s = (unsigned short)(p & 0xFFFFu);   // src < 65536
        if (!ovf) stage[slot] = s;
        else      srcidx[beg + slot] = s;                   // fallback
    }
    __syncthreads();
    if (!ovf)
        for (int i = t; i < cnt; i += 256)
            srcidx[beg + i] = stage[i];
}

// ---------------------------------------------------------------------------
// K1: fused GEMM  h0b = bf16(x@w0^T), s0b = bf16(x@skip0^T), + attention
// coefficients a_src0/a_dst0 in the epilogue.
// ---------------------------------------------------------------------------
__global__ __launch_bounds__(256) void k_gemm0(
    const unsigned short* __restrict__ xb, const unsigned short* __restrict__ wb,
    const float* __restrict__ asrc0, const float* __restrict__ adst0,
    unsigned short* __restrict__ h0b, unsigned short* __restrict__ s0b,
    float* __restrict__ a_src0, float* __restrict__ a_dst0)
{
    const int wave = threadIdx.x >> 6;
    const int lane = threadIdx.x & 63;
    const int lrow = lane & 15;
    const int quad = lane >> 4;
    const int rowbase = blockIdx.x * 64;

    bf16x8 bfrag[4][4];
    float asv[4], adv[4];
    #pragma unroll
    for (int t = 0; t < 4; t++) {
        const int jg = wave * 64 + t * 16 + lrow;
        #pragma unroll
        for (int ki = 0; ki < 4; ki++)
            bfrag[t][ki] = *(const bf16x8*)(wb + (long)jg * 128 + ki * 32 + quad * 8);
        if (wave < 2) { asv[t] = asrc0[jg]; adv[t] = adst0[jg]; }
    }

    #pragma unroll
    for (int sub = 0; sub < 4; sub++) {
        const int row0 = rowbase + sub * 16;
        if (row0 >= NN) break;
        const unsigned short* xrow = xb + (long)(row0 + lrow) * 128;
        bf16x8 afrag[4];
        #pragma unroll
        for (int ki = 0; ki < 4; ki++)
            afrag[ki] = *(const bf16x8*)(xrow + ki * 32 + quad * 8);

        f32x4 acc[4];
        #pragma unroll
        for (int t = 0; t < 4; t++) acc[t] = (f32x4){0.f, 0.f, 0.f, 0.f};

        #pragma unroll
        for (int ki = 0; ki < 4; ki++)
            #pragma unroll
            for (int t = 0; t < 4; t++)
                acc[t] = __builtin_amdgcn_mfma_f32_16x16x32_bf16(afrag[ki], bfrag[t][ki], acc[t], 0, 0, 0);

        if (wave < 2) {
            #pragma unroll
            for (int t = 0; t < 4; t++) {
                const int jg = wave * 64 + t * 16 + lrow;
                #pragma unroll
                for (int r = 0; r < 4; r++) {
                    const int n = row0 + quad * 4 + r;
                    float val = acc[t][r];
                    h0b[(long)n * 128 + jg] = f2bf(val);
                    float ps = val * asv[t];
                    float pd = val * adv[t];
                    ps += __shfl_xor(ps, 1); ps += __shfl_xor(ps, 2);
                    ps += __shfl_xor(ps, 4); ps += __shfl_xor(ps, 8);
                    pd += __shfl_xor(pd, 1); pd += __shfl_xor(pd, 2);
                    pd += __shfl_xor(pd, 4); pd += __shfl_xor(pd, 8);
                    if (lrow == 0) {
                        const int h = wave * 4 + t;
                        a_src0[(long)n * 8 + h] = ps;
                        a_dst0[(long)n * 8 + h] = pd;
                    }
                }
            }
        } else {
            #pragma unroll
            for (int t = 0; t < 4; t++) {
                const int jg = wave * 64 + t * 16 + lrow - 128;
                #pragma unroll
                for (int r = 0; r < 4; r++) {
                    const int n = row0 + quad * 4 + r;
                    s0b[(long)n * 128 + jg] = f2bf(acc[t][r]);
                }
            }
        }
    }
}

// ---------------------------------------------------------------------------
// K3: layer-0 aggregation, gather-style, single pass w/ post-normalization.
// ---------------------------------------------------------------------------
__global__ __launch_bounds__(256) void k_agg0(
    const int* __restrict__ rowbeg, const int* __restrict__ deg,
    const unsigned short* __restrict__ srcidx,
    const unsigned short* __restrict__ h0b, const float* __restrict__ a_src0,
    const float* __restrict__ a_dst0, unsigned int* __restrict__ out0b2)
{
    const int d = (blockIdx.x * 256 + threadIdx.x) >> 6;  // one wave per node
    if (d >= NN) return;
    const int lane = threadIdx.x & 63;
    const int beg = rowbeg[d], end = beg + deg[d];
    const int h = lane >> 3;
    const int c = lane * 2;
    const float adst = a_dst0[(long)d * 8 + h];

    float den0 = 0.f, den1 = 0.f, den2 = 0.f, den3 = 0.f;
    float2 ac0 = {0.f, 0.f}, ac1 = {0.f, 0.f}, ac2 = {0.f, 0.f}, ac3 = {0.f, 0.f};
    int i = beg;
    for (; i + 4 <= end; i += 4) {
        int sA = srcidx[i], sB = srcidx[i + 1], sC = srcidx[i + 2], sD = srcidx[i + 3];
        float aA = a_src0[(long)sA * 8 + h] + adst;
        float aB = a_src0[(long)sB * 8 + h] + adst;
        float aC = a_src0[(long)sC * 8 + h] + adst;
        float aD = a_src0[(long)sD * 8 + h] + adst;
        unsigned int uA = *(const unsigned int*)(h0b + (long)sA * 128 + c);
        unsigned int uB = *(const unsigned int*)(h0b + (long)sB * 128 + c);
        unsigned int uC = *(const unsigned int*)(h0b + (long)sC * 128 + c);
        unsigned int uD = *(const unsigned int*)(h0b + (long)sD * 128 + c);
        aA = aA > 0.f ? aA : 0.2f * aA;
        aB = aB > 0.f ? aB : 0.2f * aB;
        aC = aC > 0.f ? aC : 0.2f * aC;
        aD = aD > 0.f ? aD : 0.2f * aD;
        float eA = __expf(aA), eB = __expf(aB), eC = __expf(aC), eD = __expf(aD);
        den0 += eA; ac0.x += eA * bf2f((unsigned short)uA); ac0.y += eA * bf2f((unsigned short)(uA >> 16));
        den1 += eB; ac1.x += eB * bf2f((unsigned short)uB); ac1.y += eB * bf2f((unsigned short)(uB >> 16));
        den2 += eC; ac2.x += eC * bf2f((unsigned short)uC); ac2.y += eC * bf2f((unsigned short)(uC >> 16));
        den3 += eD; ac3.x += eD * bf2f((unsigned short)uD); ac3.y += eD * bf2f((unsigned short)(uD >> 16));
    }
    for (; i < end; i++) {
        int sA = srcidx[i];
        float aA = a_src0[(long)sA * 8 + h] + adst;
        unsigned int uA = *(const unsigned int*)(h0b + (long)sA * 128 + c);
        aA = aA > 0.f ? aA : 0.2f * aA;
        float eA = __expf(aA);
        den0 += eA; ac0.x += eA * bf2f((unsigned short)uA); ac0.y += eA * bf2f((unsigned short)(uA >> 16));
    }
    float den = (den0 + den1) + (den2 + den3);
    float ax = (ac0.x + ac1.x) + (ac2.x + ac3.x);
    float ay = (ac0.y + ac1.y) + (ac2.y + ac3.y);
    const float inv = 1.f / (den + 1e-16f);
    out0b2[(long)d * 64 + lane] =
        (unsigned int)f2bf(ax * inv) | ((unsigned int)f2bf(ay * inv) << 16);
}

// ---------------------------------------------------------------------------
// K4: MFMA-based post0: h_act = ELU(BN(out0)+s0) computed in registers, then
// [h1|s1] = h_act @ [w1^T|skip1^T] via two 16x16x32 MFMA tiles per 16 nodes.
// a_src1/a_dst1 from shuffle-reduction of the h1 C-tile. No LDS dot-product.
// ---------------------------------------------------------------------------
__global__ __launch_bounds__(256) void k_post0(
    const unsigned short* __restrict__ out0b, const unsigned short* __restrict__ s0b,
    const float* __restrict__ b0, const float* __restrict__ g0,
    const float* __restrict__ bb0, const float* __restrict__ m0,
    const float* __restrict__ v0,
    const unsigned short* __restrict__ wb1,     // [32][128] bf16: w1 rows, skip1 rows
    const float* __restrict__ asrc1, const float* __restrict__ adst1,
    unsigned short* __restrict__ h1b, float* __restrict__ s1,
    float* __restrict__ a_src1, float* __restrict__ a_dst1)
{
    __shared__ float Ac[128], Bc[128];
    const int tid = threadIdx.x;
    if (tid < 128) {
        float A = g0[tid] * rsqrtf(v0[tid] + 1e-5f);
        Ac[tid] = A;
        Bc[tid] = (b0[tid] - m0[tid]) * A + bb0[tid];
    }
    __syncthreads();

    const int lane = tid & 63, wave = tid >> 6;
    const int lrow = lane & 15, quad = lane >> 4;

    bf16x8 bfrag[2][4];
    #pragma unroll
    for (int t = 0; t < 2; t++)
        #pragma unroll
        for (int ki = 0; ki < 4; ki++)
            bfrag[t][ki] = *(const bf16x8*)(wb1 + (long)(t * 16 + lrow) * 128 + ki * 32 + quad * 8);
    const float avec = asrc1[lrow];
    const float dvec = adst1[lrow];

    const int tile = blockIdx.x * 4 + wave;           // 16 nodes per tile
    if (tile * 16 >= NN) return;
    const int n0 = tile * 16;
    const long arow = (long)(n0 + lrow) * 128;

    bf16x8 afrag[4];
    #pragma unroll
    for (int ki = 0; ki < 4; ki++) {
        const int ch = ki * 32 + quad * 8;
        uint4 uo = *(const uint4*)(out0b + arow + ch);
        uint4 us = *(const uint4*)(s0b + arow + ch);
        const unsigned int uov[4] = {uo.x, uo.y, uo.z, uo.w};
        const unsigned int usv[4] = {us.x, us.y, us.z, us.w};
        bf16x8 af;
        #pragma unroll
        for (int e = 0; e < 4; e++) {
            const int c0 = ch + e * 2, c1 = c0 + 1;
            float x0 = bf2f((unsigned short)uov[e]) * Ac[c0] + Bc[c0] + bf2f((unsigned short)usv[e]);
            float x1 = bf2f((unsigned short)(uov[e] >> 16)) * Ac[c1] + Bc[c1] + bf2f((unsigned short)(usv[e] >> 16));
            x0 = x0 > 0.f ? x0 : __expf(x0) - 1.f;
            x1 = x1 > 0.f ? x1 : __expf(x1) - 1.f;
            af[e * 2]     = (short)f2bf(x0);
            af[e * 2 + 1] = (short)f2bf(x1);
        }
        afrag[ki] = af;
    }

    f32x4 acc0 = (f32x4){0.f, 0.f, 0.f, 0.f};   // h1 tile
    f32x4 acc1 = (f32x4){0.f, 0.f, 0.f, 0.f};   // s1 tile
    #pragma unroll
    for (int ki = 0; ki < 4; ki++) {
        acc0 = __builtin_amdgcn_mfma_f32_16x16x32_bf16(afrag[ki], bfrag[0][ki], acc0, 0, 0, 0);
        acc1 = __builtin_amdgcn_mfma_f32_16x16x32_bf16(afrag[ki], bfrag[1][ki], acc1, 0, 0, 0);
    }

    // C layout: col = lane&15 (=j), row = quad*4+r (= node - n0)
    #pragma unroll
    for (int r = 0; r < 4; r++) {
        const int node = n0 + quad * 4 + r;
        h1b[(long)node * 16 + lrow] = f2bf(acc0[r]);
        s1[(long)node * 16 + lrow] = acc1[r];
        float ps = acc0[r] * avec;
        float pd = acc0[r] * dvec;
        ps += __shfl_xor(ps, 1); ps += __shfl_xor(ps, 2);
        ps += __shfl_xor(ps, 4); ps += __shfl_xor(ps, 8);
        pd += __shfl_xor(pd, 1); pd += __shfl_xor(pd, 2);
        pd += __shfl_xor(pd, 4); pd += __shfl_xor(pd, 8);
        if (lrow == 0) { a_src1[node] = ps; a_dst1[node] = pd; }
    }
}

// ---------------------------------------------------------------------------
// K5: layer-1 aggregation + BN1 + skip + ELU -> d_out. 16 threads/node.
// ---------------------------------------------------------------------------
__global__ __launch_bounds__(256) void k_agg1_final(
    const int* __restrict__ rowbeg, const int* __restrict__ deg,
    const unsigned short* __restrict__ srcidx,
    const unsigned short* __restrict__ h1b, const float* __restrict__ a_src1,
    const float* __restrict__ a_dst1, const float* __restrict__ s1,
    const float* __restrict__ b1, const float* __restrict__ g1,
    const float* __restrict__ bb1, const float* __restrict__ m1,
    const float* __restrict__ v1, float* __restrict__ out)
{
    const int gid = blockIdx.x * 256 + threadIdx.x;
    const int d = gid >> 4;
    if (d >= NN) return;
    const int c = gid & 15;
    const int beg = rowbeg[d], end = beg + deg[d];
    const float adst = a_dst1[d];

    float den0 = 0.f, den1 = 0.f, den2 = 0.f, den3 = 0.f;
    float ac0 = 0.f, ac1 = 0.f, ac2 = 0.f, ac3 = 0.f;
    int i = beg;
    for (; i + 4 <= end; i += 4) {
        int sA = srcidx[i], sB = srcidx[i + 1], sC = srcidx[i + 2], sD = srcidx[i + 3];
        float aA = a_src1[sA] + adst;
        float aB = a_src1[sB] + adst;
        float aC = a_src1[sC] + adst;
        float aD = a_src1[sD] + adst;
        float hA = bf2f(h1b[(long)sA * 16 + c]);
        float hB = bf2f(h1b[(long)sB * 16 + c]);
        float hC = bf2f(h1b[(long)sC * 16 + c]);
        float hD = bf2f(h1b[(long)sD * 16 + c]);
        aA = aA > 0.f ? aA : 0.2f * aA;
        aB = aB > 0.f ? aB : 0.2f * aB;
        aC = aC > 0.f ? aC : 0.2f * aC;
        aD = aD > 0.f ? aD : 0.2f * aD;
        float eA = __expf(aA), eB = __expf(aB), eC = __expf(aC), eD = __expf(aD);
        den0 += eA; ac0 += eA * hA;
        den1 += eB; ac1 += eB * hB;
        den2 += eC; ac2 += eC * hC;
        den3 += eD; ac3 += eD * hD;
    }
    for (; i < end; i++) {
        int sA = srcidx[i];
        float aA = a_src1[sA] + adst;
        float hA = bf2f(h1b[(long)sA * 16 + c]);
        aA = aA > 0.f ? aA : 0.2f * aA;
        float eA = __expf(aA);
        den0 += eA; ac0 += eA * hA;
    }
    float den = (den0 + den1) + (den2 + den3);
    float acc = (ac0 + ac1) + (ac2 + ac3);
    const float inv = 1.f / (den + 1e-16f);

    const float A = g1[c] * rsqrtf(v1[c] + 1e-5f);
    const float B = (b1[c] - m1[c]) * A + bb1[c];
    float v = acc * inv * A + B + s1[gid];
    v = v > 0.f ? v : __expf(v) - 1.f;
    out[gid] = v;
}

extern "C" void kernel_launch(void* const* d_in, const int* in_sizes, int n_in,
                              void* d_out, int out_size, void* d_ws, size_t ws_size,
                              hipStream_t stream)
{
    (void)in_sizes; (void)n_in; (void)out_size; (void)ws_size;
    const float* x     = (const float*)d_in[0];
    const int*   ei    = (const int*)d_in[1];
    const float* w0    = (const float*)d_in[2];
    const float* asrc0 = (const float*)d_in[3];
    const float* adst0 = (const float*)d_in[4];
    const float* b0    = (const float*)d_in[5];
    const float* skip0 = (const float*)d_in[6];
    const float* bn0g  = (const float*)d_in[7];
    const float* bn0b  = (const float*)d_in[8];
    const float* bn0m  = (const float*)d_in[9];
    const float* bn0v  = (const float*)d_in[10];
    const float* w1    = (const float*)d_in[11];
    const float* asrc1 = (const float*)d_in[12];
    const float* adst1 = (const float*)d_in[13];
    const float* b1    = (const float*)d_in[14];
    const float* skip1 = (const float*)d_in[15];
    const float* bn1g  = (const float*)d_in[16];
    const float* bn1b  = (const float*)d_in[17];
    const float* bn1m  = (const float*)d_in[18];
    const float* bn1v  = (const float*)d_in[19];

    // workspace layout (pairs first for 8B alignment)
    unsigned long long* pairs = (unsigned long long*)d_ws;          // EE
    unsigned short* xb    = (unsigned short*)(pairs + EE);          // NN*128
    unsigned short* wb    = xb + (long)NN * 128;                    // 256*128
    unsigned short* wb1   = wb + 256 * 128;                         // 32*128
    unsigned short* h0b   = wb1 + 32 * 128;                         // NN*128
    unsigned short* s0b   = h0b + (long)NN * 128;                   // NN*128
    unsigned short* out0b = s0b + (long)NN * 128;                   // NN*128
    unsigned short* h1b   = out0b + (long)NN * 128;                 // NN*16
    unsigned short* srcidx= h1b + (long)NN * 16;                    // EE
    float* a_src0 = (float*)(srcidx + EE);                          // NN*8
    float* a_dst0 = a_src0 + (long)NN * 8;                          // NN*8
    float* s1     = a_dst0 + (long)NN * 8;                          // NN*16
    float* a_src1 = s1 + (long)NN * 16;                             // NN
    float* a_dst1 = a_src1 + NN;                                    // NN
    int* ccnt   = (int*)(a_dst1 + NN);                              // COARSE (zeroed)
    int* cbase  = ccnt + COARSE;                                    // COARSE+1
    int* ccur   = cbase + COARSE + 1;                               // COARSE
    int* rowbeg = ccur + COARSE;                                    // NN
    int* deg    = rowbeg + NN;                                      // NN

    hipMemsetAsync(ccnt, 0, (size_t)COARSE * 4, stream);

    // bf16 conversions (x + all weights, one kernel)
    const long NTOT = (long)NN * 128 / 4 + 256 * 128 / 4 + 32 * 128 / 4;
    k_cvt<<<(unsigned)((NTOT + 255) / 256), 256, 0, stream>>>(
        x, w0, skip0, w1, skip1,
        (unsigned int*)xb, (unsigned int*)wb, (unsigned int*)wb1);

    // CSR build: dense-write partition sort (shared by both layers)
    k_chist<<<(EE + 1023) / 1024, 256, 0, stream>>>(ei, ccnt);
    k_cbase<<<1, 256, 0, stream>>>(ccnt, cbase, ccur);
    k_partA<<<(EE + EPB - 1) / EPB, 256, 0, stream>>>(ei, ccur, pairs);
    k_partB<<<COARSE, 256, 0, stream>>>(pairs, cbase, srcidx, rowbeg, deg);

    // layer 0
    k_gemm0<<<(NN + 63) / 64, 256, 0, stream>>>(xb, wb, asrc0, adst0,
                                                h0b, s0b, a_src0, a_dst0);
    k_agg0<<<(NN * 64 + 255) / 256, 256, 0, stream>>>(rowbeg, deg, srcidx, h0b,
                                                      a_src0, a_dst0, (unsigned int*)out0b);
    k_post0<<<(NN / 16 + 3) / 4, 256, 0, stream>>>(out0b, s0b, b0, bn0g, bn0b, bn0m, bn0v,
                                                   wb1, asrc1, adst1, h1b, s1, a_src1, a_dst1);
    // layer 1 + epilogue
    k_agg1_final<<<(NN * 16 + 255) / 256, 256, 0, stream>>>(rowbeg, deg, srcidx, h1b,
                                                            a_src1, a_dst1, s1,
                                                            b1, bn1g, bn1b, bn1m, bn1v,
                                                            (float*)d_out);
}

// Round 9
// 251.737 us; speedup vs baseline: 8.3885x; 1.0290x over previous
//
#include <hip/hip_runtime.h>
#include <hip/hip_bf16.h>

#define NN 50000
#define EE 800000
#define INDIM 128
#define HIDC 16
#define NHEAD 8
#define COARSE 196          // ceil(NN/256)
#define EPB 2048            // edges per block in partition pass A
#define CAPB 8192           // per-coarse-bin capacity in pass B (avg ~4082)

typedef __attribute__((ext_vector_type(8))) short bf16x8;
typedef __attribute__((ext_vector_type(4))) float f32x4;

__device__ __forceinline__ float bf2f(unsigned short u) {
    union { float f; unsigned int i; } v; v.i = ((unsigned int)u) << 16; return v.f;
}
__device__ __forceinline__ unsigned short f2bf(float f) {
    union { float f; unsigned int i; } v; v.f = f;
    unsigned int r = v.i + 0x7FFFu + ((v.i >> 16) & 1u);
    return (unsigned short)(r >> 16);
}

// ---------------------------------------------------------------------------
// K0: fp32->bf16 conversions: x, [w0|skip0] (GEMM0 B), [w1|skip1] (POST0 B).
// ---------------------------------------------------------------------------
__global__ __launch_bounds__(256) void k_cvt(const float* __restrict__ x,
                                             const float* __restrict__ w0,
                                             const float* __restrict__ skip0,
                                             const float* __restrict__ w1,
                                             const float* __restrict__ skip1,
                                             unsigned int* __restrict__ xb2,
                                             unsigned int* __restrict__ wb2,
                                             unsigned int* __restrict__ wb1_2)
{
    const long NX = (long)NN * 128 / 4;      // x float4 blocks
    const long NW = 256 * 128 / 4;           // w0|skip0
    const long NW1 = 32 * 128 / 4;           // w1|skip1
    long i = (long)blockIdx.x * 256 + threadIdx.x;
    if (i < NX) {
        float4 v = ((const float4*)x)[i];
        xb2[i * 2]     = (unsigned int)f2bf(v.x) | ((unsigned int)f2bf(v.y) << 16);
        xb2[i * 2 + 1] = (unsigned int)f2bf(v.z) | ((unsigned int)f2bf(v.w) << 16);
    } else if (i < NX + NW) {
        long j = i - NX;
        const float4* src = (j < 128 * 128 / 4) ? ((const float4*)w0 + j)
                                                : ((const float4*)skip0 + (j - 128 * 128 / 4));
        float4 v = *src;
        wb2[j * 2]     = (unsigned int)f2bf(v.x) | ((unsigned int)f2bf(v.y) << 16);
        wb2[j * 2 + 1] = (unsigned int)f2bf(v.z) | ((unsigned int)f2bf(v.w) << 16);
    } else if (i < NX + NW + NW1) {
        long j = i - NX - NW;
        const float4* src = (j < 16 * 128 / 4) ? ((const float4*)w1 + j)
                                               : ((const float4*)skip1 + (j - 16 * 128 / 4));
        float4 v = *src;
        wb1_2[j * 2]     = (unsigned int)f2bf(v.x) | ((unsigned int)f2bf(v.y) << 16);
        wb1_2[j * 2 + 1] = (unsigned int)f2bf(v.z) | ((unsigned int)f2bf(v.w) << 16);
    }
}

// ---------------------------------------------------------------------------
// CSR build, dense-write partition sort.
// ---------------------------------------------------------------------------
__global__ __launch_bounds__(256) void k_chist(const int* __restrict__ ei,
                                               int* __restrict__ ccnt)
{
    __shared__ int h[256];
    h[threadIdx.x] = 0;
    __syncthreads();
    int base = blockIdx.x * 1024 + threadIdx.x;
    #pragma unroll
    for (int k = 0; k < 4; k++) {
        int e = base + k * 256;
        if (e < EE) atomicAdd(&h[ei[EE + e] >> 8], 1);
    }
    __syncthreads();
    if (threadIdx.x < COARSE && h[threadIdx.x])
        atomicAdd(&ccnt[threadIdx.x], h[threadIdx.x]);
}

__global__ __launch_bounds__(256) void k_cbase(const int* __restrict__ ccnt,
                                               int* __restrict__ cbase,
                                               int* __restrict__ ccur)
{
    __shared__ int s[256];
    const int t = threadIdx.x;
    int v = (t < COARSE) ? ccnt[t] : 0;
    s[t] = v;
    __syncthreads();
    for (int off = 1; off < 256; off <<= 1) {
        int u = (t >= off) ? s[t - off] : 0;
        __syncthreads();
        s[t] += u;
        __syncthreads();
    }
    if (t < COARSE) { int ex = s[t] - v; cbase[t] = ex; ccur[t] = ex; }
    if (t == 255) cbase[COARSE] = s[255];
}

__global__ __launch_bounds__(256) void k_partA(const int* __restrict__ ei,
                                               int* __restrict__ ccur,
                                               unsigned long long* __restrict__ pairs)
{
    __shared__ int bcnt[256];
    __shared__ int lofs[256];
    __shared__ int gofs[256];
    __shared__ unsigned long long stage[EPB];
    __shared__ int gpos[EPB];
    const int t = threadIdx.x;
    const int e0 = blockIdx.x * EPB;

    bcnt[t] = 0;
    __syncthreads();

    int mybin[8], myrank[8];
    unsigned long long mypair[8];
    #pragma unroll
    for (int k = 0; k < 8; k++) {
        int e = e0 + k * 256 + t;
        mybin[k] = -1;
        if (e < EE) {
            int s = ei[e], d = ei[EE + e];
            int b = d >> 8;
            myrank[k] = atomicAdd(&bcnt[b], 1);
            mybin[k] = b;
            mypair[k] = ((unsigned long long)(unsigned)d << 32) | (unsigned)s;
        }
    }
    __syncthreads();

    int v = bcnt[t];
    lofs[t] = v;
    __syncthreads();
    for (int off = 1; off < 256; off <<= 1) {
        int u = (t >= off) ? lofs[t - off] : 0;
        __syncthreads();
        lofs[t] += u;
        __syncthreads();
    }
    if (t < COARSE && v > 0) gofs[t] = atomicAdd(&ccur[t], v);
    __syncthreads();

    #pragma unroll
    for (int k = 0; k < 8; k++) {
        int b = mybin[k];
        if (b >= 0) {
            int slot = (lofs[b] - bcnt[b]) + myrank[k];
            stage[slot] = mypair[k];
            gpos[slot]  = gofs[b] + myrank[k];
        }
    }
    __syncthreads();

    const int total = lofs[255];
    for (int i = t; i < total; i += 256)
        pairs[gpos[i]] = stage[i];
}

__global__ __launch_bounds__(256) void k_partB(const unsigned long long* __restrict__ pairs,
                                               const int* __restrict__ cbase,
                                               unsigned short* __restrict__ srcidx,
                                               int* __restrict__ rowbeg,
                                               int* __restrict__ deg)
{
    __shared__ int fcnt[256], fofs[256], fcur[256];
    __shared__ unsigned short stage[CAPB];
    const int b = blockIdx.x, t = threadIdx.x;
    const int beg = cbase[b], end = cbase[b + 1];
    const int cnt = end - beg;

    fcnt[t] = 0;
    __syncthreads();
    for (int i = t; i < cnt; i += 256) {
        int d = (int)(pairs[beg + i] >> 32);
        atomicAdd(&fcnt[d & 255], 1);
    }
    __syncthreads();

    int v = fcnt[t];
    fofs[t] = v;
    __syncthreads();
    for (int off = 1; off < 256; off <<= 1) {
        int u = (t >= off) ? fofs[t - off] : 0;
        __syncthreads();
        fofs[t] += u;
        __syncthreads();
    }
    int ex = fofs[t] - v;
    int node = b * 256 + t;
    if (node < NN) { rowbeg[node] = beg + ex; deg[node] = v; }
    fcur[t] = ex;
    __syncthreads();

    const bool ovf = (cnt > CAPB);
    for (int i = t; i < cnt; i += 256) {
        unsigned long long p = pairs[beg + i];
        int d = (int)(p >> 32);
        int slot = atomicAdd(&fcur[d & 255], 1);
        unsigned short s = (unsigned short)(p & 0xFFFFu);   // src < 65536
        if (!ovf) stage[slot] = s;
        else      srcidx[beg + slot] = s;                   // fallback
    }
    __syncthreads();
    if (!ovf)
        for (int i = t; i < cnt; i += 256)
            srcidx[beg + i] = stage[i];
}

// ---------------------------------------------------------------------------
// K1: fused GEMM  h0b = bf16(x@w0^T), s0b = bf16(x@skip0^T), + attention
// coefficients a_src0/a_dst0 in the epilogue.
// ---------------------------------------------------------------------------
__global__ __launch_bounds__(256) void k_gemm0(
    const unsigned short* __restrict__ xb, const unsigned short* __restrict__ wb,
    const float* __restrict__ asrc0, const float* __restrict__ adst0,
    unsigned short* __restrict__ h0b, unsigned short* __restrict__ s0b,
    float* __restrict__ a_src0, float* __restrict__ a_dst0)
{
    const int wave = threadIdx.x >> 6;
    const int lane = threadIdx.x & 63;
    const int lrow = lane & 15;
    const int quad = lane >> 4;
    const int rowbase = blockIdx.x * 64;

    bf16x8 bfrag[4][4];
    float asv[4], adv[4];
    #pragma unroll
    for (int t = 0; t < 4; t++) {
        const int jg = wave * 64 + t * 16 + lrow;
        #pragma unroll
        for (int ki = 0; ki < 4; ki++)
            bfrag[t][ki] = *(const bf16x8*)(wb + (long)jg * 128 + ki * 32 + quad * 8);
        if (wave < 2) { asv[t] = asrc0[jg]; adv[t] = adst0[jg]; }
    }

    #pragma unroll
    for (int sub = 0; sub < 4; sub++) {
        const int row0 = rowbase + sub * 16;
        if (row0 >= NN) break;
        const unsigned short* xrow = xb + (long)(row0 + lrow) * 128;
        bf16x8 afrag[4];
        #pragma unroll
        for (int ki = 0; ki < 4; ki++)
            afrag[ki] = *(const bf16x8*)(xrow + ki * 32 + quad * 8);

        f32x4 acc[4];
        #pragma unroll
        for (int t = 0; t < 4; t++) acc[t] = (f32x4){0.f, 0.f, 0.f, 0.f};

        #pragma unroll
        for (int ki = 0; ki < 4; ki++)
            #pragma unroll
            for (int t = 0; t < 4; t++)
                acc[t] = __builtin_amdgcn_mfma_f32_16x16x32_bf16(afrag[ki], bfrag[t][ki], acc[t], 0, 0, 0);

        if (wave < 2) {
            #pragma unroll
            for (int t = 0; t < 4; t++) {
                const int jg = wave * 64 + t * 16 + lrow;
                #pragma unroll
                for (int r = 0; r < 4; r++) {
                    const int n = row0 + quad * 4 + r;
                    float val = acc[t][r];
                    h0b[(long)n * 128 + jg] = f2bf(val);
                    float ps = val * asv[t];
                    float pd = val * adv[t];
                    ps += __shfl_xor(ps, 1); ps += __shfl_xor(ps, 2);
                    ps += __shfl_xor(ps, 4); ps += __shfl_xor(ps, 8);
                    pd += __shfl_xor(pd, 1); pd += __shfl_xor(pd, 2);
                    pd += __shfl_xor(pd, 4); pd += __shfl_xor(pd, 8);
                    if (lrow == 0) {
                        const int h = wave * 4 + t;
                        a_src0[(long)n * 8 + h] = ps;
                        a_dst0[(long)n * 8 + h] = pd;
                    }
                }
            }
        } else {
            #pragma unroll
            for (int t = 0; t < 4; t++) {
                const int jg = wave * 64 + t * 16 + lrow - 128;
                #pragma unroll
                for (int r = 0; r < 4; r++) {
                    const int n = row0 + quad * 4 + r;
                    s0b[(long)n * 128 + jg] = f2bf(acc[t][r]);
                }
            }
        }
    }
}

// ---------------------------------------------------------------------------
// K3: layer-0 aggregation with two-phase batch-8 weight dedup.
// One wave per dst node. Per 8-edge batch:
//  phase 1: lane l computes w for (edge l>>3, head l&7) -- one exp per lane.
//  phase 2: 8 rounds; w & src broadcast via shuffle; dense 4B h0b loads.
// Denominator: per-lane accumulate + shfl_xor(8/16/32) reduction at end.
// ---------------------------------------------------------------------------
__global__ __launch_bounds__(256) void k_agg0(
    const int* __restrict__ rowbeg, const int* __restrict__ deg,
    const unsigned short* __restrict__ srcidx,
    const unsigned short* __restrict__ h0b, const float* __restrict__ a_src0,
    const float* __restrict__ a_dst0, unsigned int* __restrict__ out0b2)
{
    const int d = (blockIdx.x * 256 + threadIdx.x) >> 6;  // one wave per node
    if (d >= NN) return;
    const int lane = threadIdx.x & 63;
    const int beg = rowbeg[d], end = beg + deg[d];
    const int eslot = lane >> 3;                          // phase-1 edge slot
    const int hph1 = lane & 7;                            // phase-1 head
    const int c = lane * 2;                               // phase-2 channels
    const float adst = a_dst0[(long)d * 8 + hph1];

    float den = 0.f;
    float2 acc = {0.f, 0.f};
    for (int i = beg; i < end; i += 8) {
        // ---- phase 1: 8 edges x 8 heads, one weight per lane ----
        const int idx = i + eslot;
        const bool valid = idx < end;
        const int s_l = valid ? (int)srcidx[idx] : 0;
        float a = a_src0[(long)s_l * 8 + hph1] + adst;
        a = a > 0.f ? a : 0.2f * a;
        float w_l = valid ? __expf(a) : 0.f;
        den += w_l;
        // ---- phase 2: 8 rounds, dense h0b row loads ----
        #pragma unroll
        for (int j = 0; j < 8; j++) {
            const float wj = __shfl(w_l, j * 8 + (lane >> 3));
            const int sj = __shfl(s_l, j * 8);
            const unsigned int u = *(const unsigned int*)(h0b + (long)sj * 128 + c);
            acc.x += wj * bf2f((unsigned short)u);
            acc.y += wj * bf2f((unsigned short)(u >> 16));
        }
    }
    // reduce den over edge slots (lanes with equal lane&7)
    den += __shfl_xor(den, 8);
    den += __shfl_xor(den, 16);
    den += __shfl_xor(den, 32);
    // lane needs den of head lane>>3; lane (lane>>3) holds head (lane>>3)
    const float denh = __shfl(den, lane >> 3);
    const float inv = 1.f / (denh + 1e-16f);
    out0b2[(long)d * 64 + lane] =
        (unsigned int)f2bf(acc.x * inv) | ((unsigned int)f2bf(acc.y * inv) << 16);
}

// ---------------------------------------------------------------------------
// K4: MFMA-based post0: h_act = ELU(BN(out0)+s0) in registers, then
// [h1|s1] = h_act @ [w1^T|skip1^T] via two 16x16x32 MFMA tiles per 16 nodes.
// ---------------------------------------------------------------------------
__global__ __launch_bounds__(256) void k_post0(
    const unsigned short* __restrict__ out0b, const unsigned short* __restrict__ s0b,
    const float* __restrict__ b0, const float* __restrict__ g0,
    const float* __restrict__ bb0, const float* __restrict__ m0,
    const float* __restrict__ v0,
    const unsigned short* __restrict__ wb1,     // [32][128] bf16: w1 rows, skip1 rows
    const float* __restrict__ asrc1, const float* __restrict__ adst1,
    unsigned short* __restrict__ h1b, float* __restrict__ s1,
    float* __restrict__ a_src1, float* __restrict__ a_dst1)
{
    __shared__ float Ac[128], Bc[128];
    const int tid = threadIdx.x;
    if (tid < 128) {
        float A = g0[tid] * rsqrtf(v0[tid] + 1e-5f);
        Ac[tid] = A;
        Bc[tid] = (b0[tid] - m0[tid]) * A + bb0[tid];
    }
    __syncthreads();

    const int lane = tid & 63, wave = tid >> 6;
    const int lrow = lane & 15, quad = lane >> 4;

    bf16x8 bfrag[2][4];
    #pragma unroll
    for (int t = 0; t < 2; t++)
        #pragma unroll
        for (int ki = 0; ki < 4; ki++)
            bfrag[t][ki] = *(const bf16x8*)(wb1 + (long)(t * 16 + lrow) * 128 + ki * 32 + quad * 8);
    const float avec = asrc1[lrow];
    const float dvec = adst1[lrow];

    const int tile = blockIdx.x * 4 + wave;           // 16 nodes per tile
    if (tile * 16 >= NN) return;
    const int n0 = tile * 16;
    const long arow = (long)(n0 + lrow) * 128;

    bf16x8 afrag[4];
    #pragma unroll
    for (int ki = 0; ki < 4; ki++) {
        const int ch = ki * 32 + quad * 8;
        uint4 uo = *(const uint4*)(out0b + arow + ch);
        uint4 us = *(const uint4*)(s0b + arow + ch);
        const unsigned int uov[4] = {uo.x, uo.y, uo.z, uo.w};
        const unsigned int usv[4] = {us.x, us.y, us.z, us.w};
        bf16x8 af;
        #pragma unroll
        for (int e = 0; e < 4; e++) {
            const int c0 = ch + e * 2, c1 = c0 + 1;
            float x0 = bf2f((unsigned short)uov[e]) * Ac[c0] + Bc[c0] + bf2f((unsigned short)usv[e]);
            float x1 = bf2f((unsigned short)(uov[e] >> 16)) * Ac[c1] + Bc[c1] + bf2f((unsigned short)(usv[e] >> 16));
            x0 = x0 > 0.f ? x0 : __expf(x0) - 1.f;
            x1 = x1 > 0.f ? x1 : __expf(x1) - 1.f;
            af[e * 2]     = (short)f2bf(x0);
            af[e * 2 + 1] = (short)f2bf(x1);
        }
        afrag[ki] = af;
    }

    f32x4 acc0 = (f32x4){0.f, 0.f, 0.f, 0.f};   // h1 tile
    f32x4 acc1 = (f32x4){0.f, 0.f, 0.f, 0.f};   // s1 tile
    #pragma unroll
    for (int ki = 0; ki < 4; ki++) {
        acc0 = __builtin_amdgcn_mfma_f32_16x16x32_bf16(afrag[ki], bfrag[0][ki], acc0, 0, 0, 0);
        acc1 = __builtin_amdgcn_mfma_f32_16x16x32_bf16(afrag[ki], bfrag[1][ki], acc1, 0, 0, 0);
    }

    // C layout: col = lane&15 (=j), row = quad*4+r (= node - n0)
    #pragma unroll
    for (int r = 0; r < 4; r++) {
        const int node = n0 + quad * 4 + r;
        h1b[(long)node * 16 + lrow] = f2bf(acc0[r]);
        s1[(long)node * 16 + lrow] = acc1[r];
        float ps = acc0[r] * avec;
        float pd = acc0[r] * dvec;
        ps += __shfl_xor(ps, 1); ps += __shfl_xor(ps, 2);
        ps += __shfl_xor(ps, 4); ps += __shfl_xor(ps, 8);
        pd += __shfl_xor(pd, 1); pd += __shfl_xor(pd, 2);
        pd += __shfl_xor(pd, 4); pd += __shfl_xor(pd, 8);
        if (lrow == 0) { a_src1[node] = ps; a_dst1[node] = pd; }
    }
}

// ---------------------------------------------------------------------------
// K5: layer-1 aggregation + BN1 + skip + ELU -> d_out, two-phase batch-8
// dedup. 8 lanes per dst node, 2 channels per lane; group-local shuffles.
// ---------------------------------------------------------------------------
__global__ __launch_bounds__(256) void k_agg1_final(
    const int* __restrict__ rowbeg, const int* __restrict__ deg,
    const unsigned short* __restrict__ srcidx,
    const unsigned short* __restrict__ h1b, const float* __restrict__ a_src1,
    const float* __restrict__ a_dst1, const float* __restrict__ s1,
    const float* __restrict__ b1, const float* __restrict__ g1,
    const float* __restrict__ bb1, const float* __restrict__ m1,
    const float* __restrict__ v1, float* __restrict__ out)
{
    const int gid = blockIdx.x * 256 + threadIdx.x;
    const int d = gid >> 3;                               // 8 lanes per node
    if (d >= NN) return;
    const int lane = threadIdx.x & 63;
    const int gl = lane & 7;                              // lane within group
    const int gb = lane & ~7;                             // group base lane
    const int c0 = gl * 2, c1 = c0 + 1;
    const int beg = rowbeg[d], end = beg + deg[d];
    const float adst = a_dst1[d];

    float den = 0.f;
    float2 acc = {0.f, 0.f};
    for (int i = beg; i < end; i += 8) {
        // phase 1: one weight per lane (edge i+gl)
        const int idx = i + gl;
        const bool valid = idx < end;
        const int s_l = valid ? (int)srcidx[idx] : 0;
        float a = a_src1[s_l] + adst;
        a = a > 0.f ? a : 0.2f * a;
        float w_l = valid ? __expf(a) : 0.f;
        den += w_l;
        // phase 2: 8 rounds, 4B h1b loads (2 channels)
        #pragma unroll
        for (int j = 0; j < 8; j++) {
            const float wj = __shfl(w_l, gb | j);
            const int sj = __shfl(s_l, gb | j);
            const unsigned int u = *(const unsigned int*)(h1b + (long)sj * 16 + c0);
            acc.x += wj * bf2f((unsigned short)u);
            acc.y += wj * bf2f((unsigned short)(u >> 16));
        }
    }
    den += __shfl_xor(den, 1);
    den += __shfl_xor(den, 2);
    den += __shfl_xor(den, 4);
    const float inv = 1.f / (den + 1e-16f);

    const float A0 = g1[c0] * rsqrtf(v1[c0] + 1e-5f);
    const float B0 = (b1[c0] - m1[c0]) * A0 + bb1[c0];
    const float A1 = g1[c1] * rsqrtf(v1[c1] + 1e-5f);
    const float B1 = (b1[c1] - m1[c1]) * A1 + bb1[c1];
    float2 sv = *(const float2*)(s1 + (long)d * 16 + c0);
    float v0o = acc.x * inv * A0 + B0 + sv.x;
    float v1o = acc.y * inv * A1 + B1 + sv.y;
    v0o = v0o > 0.f ? v0o : __expf(v0o) - 1.f;
    v1o = v1o > 0.f ? v1o : __expf(v1o) - 1.f;
    *(float2*)(out + (long)d * 16 + c0) = make_float2(v0o, v1o);
}

extern "C" void kernel_launch(void* const* d_in, const int* in_sizes, int n_in,
                              void* d_out, int out_size, void* d_ws, size_t ws_size,
                              hipStream_t stream)
{
    (void)in_sizes; (void)n_in; (void)out_size; (void)ws_size;
    const float* x     = (const float*)d_in[0];
    const int*   ei    = (const int*)d_in[1];
    const float* w0    = (const float*)d_in[2];
    const float* asrc0 = (const float*)d_in[3];
    const float* adst0 = (const float*)d_in[4];
    const float* b0    = (const float*)d_in[5];
    const float* skip0 = (const float*)d_in[6];
    const float* bn0g  = (const float*)d_in[7];
    const float* bn0b  = (const float*)d_in[8];
    const float* bn0m  = (const float*)d_in[9];
    const float* bn0v  = (const float*)d_in[10];
    const float* w1    = (const float*)d_in[11];
    const float* asrc1 = (const float*)d_in[12];
    const float* adst1 = (const float*)d_in[13];
    const float* b1    = (const float*)d_in[14];
    const float* skip1 = (const float*)d_in[15];
    const float* bn1g  = (const float*)d_in[16];
    const float* bn1b  = (const float*)d_in[17];
    const float* bn1m  = (const float*)d_in[18];
    const float* bn1v  = (const float*)d_in[19];

    // workspace layout (pairs first for 8B alignment)
    unsigned long long* pairs = (unsigned long long*)d_ws;          // EE
    unsigned short* xb    = (unsigned short*)(pairs + EE);          // NN*128
    unsigned short* wb    = xb + (long)NN * 128;                    // 256*128
    unsigned short* wb1   = wb + 256 * 128;                         // 32*128
    unsigned short* h0b   = wb1 + 32 * 128;                         // NN*128
    unsigned short* s0b   = h0b + (long)NN * 128;                   // NN*128
    unsigned short* out0b = s0b + (long)NN * 128;                   // NN*128
    unsigned short* h1b   = out0b + (long)NN * 128;                 // NN*16
    unsigned short* srcidx= h1b + (long)NN * 16;                    // EE
    float* a_src0 = (float*)(srcidx + EE);                          // NN*8
    float* a_dst0 = a_src0 + (long)NN * 8;                          // NN*8
    float* s1     = a_dst0 + (long)NN * 8;                          // NN*16
    float* a_src1 = s1 + (long)NN * 16;                             // NN
    float* a_dst1 = a_src1 + NN;                                    // NN
    int* ccnt   = (int*)(a_dst1 + NN);                              // COARSE (zeroed)
    int* cbase  = ccnt + COARSE;                                    // COARSE+1
    int* ccur   = cbase + COARSE + 1;                               // COARSE
    int* rowbeg = ccur + COARSE;                                    // NN
    int* deg    = rowbeg + NN;                                      // NN

    hipMemsetAsync(ccnt, 0, (size_t)COARSE * 4, stream);

    // bf16 conversions (x + all weights, one kernel)
    const long NTOT = (long)NN * 128 / 4 + 256 * 128 / 4 + 32 * 128 / 4;
    k_cvt<<<(unsigned)((NTOT + 255) / 256), 256, 0, stream>>>(
        x, w0, skip0, w1, skip1,
        (unsigned int*)xb, (unsigned int*)wb, (unsigned int*)wb1);

    // CSR build: dense-write partition sort (shared by both layers)
    k_chist<<<(EE + 1023) / 1024, 256, 0, stream>>>(ei, ccnt);
    k_cbase<<<1, 256, 0, stream>>>(ccnt, cbase, ccur);
    k_partA<<<(EE + EPB - 1) / EPB, 256, 0, stream>>>(ei, ccur, pairs);
    k_partB<<<COARSE, 256, 0, stream>>>(pairs, cbase, srcidx, rowbeg, deg);

    // layer 0
    k_gemm0<<<(NN + 63) / 64, 256, 0, stream>>>(xb, wb, asrc0, adst0,
                                                h0b, s0b, a_src0, a_dst0);
    k_agg0<<<(NN * 64 + 255) / 256, 256, 0, stream>>>(rowbeg, deg, srcidx, h0b,
                                                      a_src0, a_dst0, (unsigned int*)out0b);
    k_post0<<<(NN / 16 + 3) / 4, 256, 0, stream>>>(out0b, s0b, b0, bn0g, bn0b, bn0m, bn0v,
                                                   wb1, asrc1, adst1, h1b, s1, a_src1, a_dst1);
    // layer 1 + epilogue
    k_agg1_final<<<(NN * 8 + 255) / 256, 256, 0, stream>>>(rowbeg, deg, srcidx, h1b,
                                                           a_src1, a_dst1, s1,
                                                           b1, bn1g, bn1b, bn1m, bn1v,
                                                           (float*)d_out);
}

// Round 10
// 245.783 us; speedup vs baseline: 8.5917x; 1.0242x over previous
//
#include <hip/hip_runtime.h>
#include <hip/hip_bf16.h>

#define NN 50000
#define EE 800000
#define INDIM 128
#define HIDC 16
#define NHEAD 8
#define COARSE 196          // ceil(NN/256)
#define EPB 2048            // edges per block in partition pass A
#define CAPB 8192           // per-coarse-bin capacity in pass B (avg ~4082)

typedef __attribute__((ext_vector_type(8))) short bf16x8;
typedef __attribute__((ext_vector_type(4))) float f32x4;

__device__ __forceinline__ float bf2f(unsigned short u) {
    union { float f; unsigned int i; } v; v.i = ((unsigned int)u) << 16; return v.f;
}
__device__ __forceinline__ unsigned short f2bf(float f) {
    union { float f; unsigned int i; } v; v.f = f;
    unsigned int r = v.i + 0x7FFFu + ((v.i >> 16) & 1u);
    return (unsigned short)(r >> 16);
}

// ---------------------------------------------------------------------------
// K0: fp32->bf16 conversions: x, [w0|skip0] (GEMM0 B), [w1|skip1] (POST0 B).
// ---------------------------------------------------------------------------
__global__ __launch_bounds__(256) void k_cvt(const float* __restrict__ x,
                                             const float* __restrict__ w0,
                                             const float* __restrict__ skip0,
                                             const float* __restrict__ w1,
                                             const float* __restrict__ skip1,
                                             unsigned int* __restrict__ xb2,
                                             unsigned int* __restrict__ wb2,
                                             unsigned int* __restrict__ wb1_2)
{
    const long NX = (long)NN * 128 / 4;      // x float4 blocks
    const long NW = 256 * 128 / 4;           // w0|skip0
    const long NW1 = 32 * 128 / 4;           // w1|skip1
    long i = (long)blockIdx.x * 256 + threadIdx.x;
    if (i < NX) {
        float4 v = ((const float4*)x)[i];
        xb2[i * 2]     = (unsigned int)f2bf(v.x) | ((unsigned int)f2bf(v.y) << 16);
        xb2[i * 2 + 1] = (unsigned int)f2bf(v.z) | ((unsigned int)f2bf(v.w) << 16);
    } else if (i < NX + NW) {
        long j = i - NX;
        const float4* src = (j < 128 * 128 / 4) ? ((const float4*)w0 + j)
                                                : ((const float4*)skip0 + (j - 128 * 128 / 4));
        float4 v = *src;
        wb2[j * 2]     = (unsigned int)f2bf(v.x) | ((unsigned int)f2bf(v.y) << 16);
        wb2[j * 2 + 1] = (unsigned int)f2bf(v.z) | ((unsigned int)f2bf(v.w) << 16);
    } else if (i < NX + NW + NW1) {
        long j = i - NX - NW;
        const float4* src = (j < 16 * 128 / 4) ? ((const float4*)w1 + j)
                                               : ((const float4*)skip1 + (j - 16 * 128 / 4));
        float4 v = *src;
        wb1_2[j * 2]     = (unsigned int)f2bf(v.x) | ((unsigned int)f2bf(v.y) << 16);
        wb1_2[j * 2 + 1] = (unsigned int)f2bf(v.z) | ((unsigned int)f2bf(v.w) << 16);
    }
}

// ---------------------------------------------------------------------------
// CSR build, dense-write partition sort. Pairs packed to 32-bit (d<<16|s,
// both < 65536) -- halves pairs traffic vs 64-bit.
// ---------------------------------------------------------------------------
__global__ __launch_bounds__(256) void k_chist(const int* __restrict__ ei,
                                               int* __restrict__ ccnt)
{
    __shared__ int h[256];
    h[threadIdx.x] = 0;
    __syncthreads();
    int base = blockIdx.x * 1024 + threadIdx.x;
    #pragma unroll
    for (int k = 0; k < 4; k++) {
        int e = base + k * 256;
        if (e < EE) atomicAdd(&h[ei[EE + e] >> 8], 1);
    }
    __syncthreads();
    if (threadIdx.x < COARSE && h[threadIdx.x])
        atomicAdd(&ccnt[threadIdx.x], h[threadIdx.x]);
}

__global__ __launch_bounds__(256) void k_cbase(const int* __restrict__ ccnt,
                                               int* __restrict__ cbase,
                                               int* __restrict__ ccur)
{
    __shared__ int s[256];
    const int t = threadIdx.x;
    int v = (t < COARSE) ? ccnt[t] : 0;
    s[t] = v;
    __syncthreads();
    for (int off = 1; off < 256; off <<= 1) {
        int u = (t >= off) ? s[t - off] : 0;
        __syncthreads();
        s[t] += u;
        __syncthreads();
    }
    if (t < COARSE) { int ex = s[t] - v; cbase[t] = ex; ccur[t] = ex; }
    if (t == 255) cbase[COARSE] = s[255];
}

__global__ __launch_bounds__(256) void k_partA(const int* __restrict__ ei,
                                               int* __restrict__ ccur,
                                               unsigned int* __restrict__ pairs)
{
    __shared__ int bcnt[256];
    __shared__ int lofs[256];
    __shared__ int gofs[256];
    __shared__ unsigned int stage[EPB];
    __shared__ int gpos[EPB];
    const int t = threadIdx.x;
    const int e0 = blockIdx.x * EPB;

    bcnt[t] = 0;
    __syncthreads();

    int mybin[8], myrank[8];
    unsigned int mypair[8];
    #pragma unroll
    for (int k = 0; k < 8; k++) {
        int e = e0 + k * 256 + t;
        mybin[k] = -1;
        if (e < EE) {
            int s = ei[e], d = ei[EE + e];
            int b = d >> 8;
            myrank[k] = atomicAdd(&bcnt[b], 1);
            mybin[k] = b;
            mypair[k] = ((unsigned)d << 16) | (unsigned)s;
        }
    }
    __syncthreads();

    int v = bcnt[t];
    lofs[t] = v;
    __syncthreads();
    for (int off = 1; off < 256; off <<= 1) {
        int u = (t >= off) ? lofs[t - off] : 0;
        __syncthreads();
        lofs[t] += u;
        __syncthreads();
    }
    if (t < COARSE && v > 0) gofs[t] = atomicAdd(&ccur[t], v);
    __syncthreads();

    #pragma unroll
    for (int k = 0; k < 8; k++) {
        int b = mybin[k];
        if (b >= 0) {
            int slot = (lofs[b] - bcnt[b]) + myrank[k];
            stage[slot] = mypair[k];
            gpos[slot]  = gofs[b] + myrank[k];
        }
    }
    __syncthreads();

    const int total = lofs[255];
    for (int i = t; i < total; i += 256)
        pairs[gpos[i]] = stage[i];
}

__global__ __launch_bounds__(256) void k_partB(const unsigned int* __restrict__ pairs,
                                               const int* __restrict__ cbase,
                                               unsigned short* __restrict__ srcidx,
                                               int* __restrict__ rowbeg,
                                               int* __restrict__ deg)
{
    __shared__ int fcnt[256], fofs[256], fcur[256];
    __shared__ unsigned short stage[CAPB];
    const int b = blockIdx.x, t = threadIdx.x;
    const int beg = cbase[b], end = cbase[b + 1];
    const int cnt = end - beg;

    fcnt[t] = 0;
    __syncthreads();
    for (int i = t; i < cnt; i += 256) {
        unsigned int d = pairs[beg + i] >> 16;
        atomicAdd(&fcnt[d & 255], 1);
    }
    __syncthreads();

    int v = fcnt[t];
    fofs[t] = v;
    __syncthreads();
    for (int off = 1; off < 256; off <<= 1) {
        int u = (t >= off) ? fofs[t - off] : 0;
        __syncthreads();
        fofs[t] += u;
        __syncthreads();
    }
    int ex = fofs[t] - v;
    int node = b * 256 + t;
    if (node < NN) { rowbeg[node] = beg + ex; deg[node] = v; }
    fcur[t] = ex;
    __syncthreads();

    const bool ovf = (cnt > CAPB);
    for (int i = t; i < cnt; i += 256) {
        unsigned int p = pairs[beg + i];
        unsigned int d = p >> 16;
        int slot = atomicAdd(&fcur[d & 255], 1);
        unsigned short s = (unsigned short)(p & 0xFFFFu);   // src < 65536
        if (!ovf) stage[slot] = s;
        else      srcidx[beg + slot] = s;                   // fallback
    }
    __syncthreads();
    if (!ovf)
        for (int i = t; i < cnt; i += 256)
            srcidx[beg + i] = stage[i];
}

// ---------------------------------------------------------------------------
// K1: fused GEMM  h0b = bf16(x@w0^T), s0b = bf16(x@skip0^T), + attention
// coefficients a_src0/a_dst0 in the epilogue.
// ---------------------------------------------------------------------------
__global__ __launch_bounds__(256) void k_gemm0(
    const unsigned short* __restrict__ xb, const unsigned short* __restrict__ wb,
    const float* __restrict__ asrc0, const float* __restrict__ adst0,
    unsigned short* __restrict__ h0b, unsigned short* __restrict__ s0b,
    float* __restrict__ a_src0, float* __restrict__ a_dst0)
{
    const int wave = threadIdx.x >> 6;
    const int lane = threadIdx.x & 63;
    const int lrow = lane & 15;
    const int quad = lane >> 4;
    const int rowbase = blockIdx.x * 64;

    bf16x8 bfrag[4][4];
    float asv[4], adv[4];
    #pragma unroll
    for (int t = 0; t < 4; t++) {
        const int jg = wave * 64 + t * 16 + lrow;
        #pragma unroll
        for (int ki = 0; ki < 4; ki++)
            bfrag[t][ki] = *(const bf16x8*)(wb + (long)jg * 128 + ki * 32 + quad * 8);
        if (wave < 2) { asv[t] = asrc0[jg]; adv[t] = adst0[jg]; }
    }

    #pragma unroll
    for (int sub = 0; sub < 4; sub++) {
        const int row0 = rowbase + sub * 16;
        if (row0 >= NN) break;
        const unsigned short* xrow = xb + (long)(row0 + lrow) * 128;
        bf16x8 afrag[4];
        #pragma unroll
        for (int ki = 0; ki < 4; ki++)
            afrag[ki] = *(const bf16x8*)(xrow + ki * 32 + quad * 8);

        f32x4 acc[4];
        #pragma unroll
        for (int t = 0; t < 4; t++) acc[t] = (f32x4){0.f, 0.f, 0.f, 0.f};

        #pragma unroll
        for (int ki = 0; ki < 4; ki++)
            #pragma unroll
            for (int t = 0; t < 4; t++)
                acc[t] = __builtin_amdgcn_mfma_f32_16x16x32_bf16(afrag[ki], bfrag[t][ki], acc[t], 0, 0, 0);

        if (wave < 2) {
            #pragma unroll
            for (int t = 0; t < 4; t++) {
                const int jg = wave * 64 + t * 16 + lrow;
                #pragma unroll
                for (int r = 0; r < 4; r++) {
                    const int n = row0 + quad * 4 + r;
                    float val = acc[t][r];
                    h0b[(long)n * 128 + jg] = f2bf(val);
                    float ps = val * asv[t];
                    float pd = val * adv[t];
                    ps += __shfl_xor(ps, 1); ps += __shfl_xor(ps, 2);
                    ps += __shfl_xor(ps, 4); ps += __shfl_xor(ps, 8);
                    pd += __shfl_xor(pd, 1); pd += __shfl_xor(pd, 2);
                    pd += __shfl_xor(pd, 4); pd += __shfl_xor(pd, 8);
                    if (lrow == 0) {
                        const int h = wave * 4 + t;
                        a_src0[(long)n * 8 + h] = ps;
                        a_dst0[(long)n * 8 + h] = pd;
                    }
                }
            }
        } else {
            #pragma unroll
            for (int t = 0; t < 4; t++) {
                const int jg = wave * 64 + t * 16 + lrow - 128;
                #pragma unroll
                for (int r = 0; r < 4; r++) {
                    const int n = row0 + quad * 4 + r;
                    s0b[(long)n * 128 + jg] = f2bf(acc[t][r]);
                }
            }
        }
    }
}

// ---------------------------------------------------------------------------
// K3: layer-0 aggregation, two-phase dedup + 2x batch interleave (16 edges
// in flight per wave) to hide gather latency. One wave per dst node.
// ---------------------------------------------------------------------------
__global__ __launch_bounds__(256) void k_agg0(
    const int* __restrict__ rowbeg, const int* __restrict__ deg,
    const unsigned short* __restrict__ srcidx,
    const unsigned short* __restrict__ h0b, const float* __restrict__ a_src0,
    const float* __restrict__ a_dst0, unsigned int* __restrict__ out0b2)
{
    const int d = (blockIdx.x * 256 + threadIdx.x) >> 6;  // one wave per node
    if (d >= NN) return;
    const int lane = threadIdx.x & 63;
    const int beg = rowbeg[d], end = beg + deg[d];
    const int eslot = lane >> 3;                          // phase-1 edge slot
    const int hph1 = lane & 7;                            // phase-1 head
    const int c = lane * 2;                               // phase-2 channels
    const int hsel = lane >> 3;                           // head for channels c
    const float adst = a_dst0[(long)d * 8 + hph1];

    float den = 0.f;
    float2 accA = {0.f, 0.f}, accB = {0.f, 0.f};
    for (int i = beg; i < end; i += 16) {
        // ---- phase 1: two independent 8-edge batches ----
        const int idxA = i + eslot;
        const int idxB = i + 8 + eslot;
        const bool vA = idxA < end;
        const bool vB = idxB < end;
        const int sA = vA ? (int)srcidx[idxA] : 0;
        const int sB = vB ? (int)srcidx[idxB] : 0;
        float aA = a_src0[(long)sA * 8 + hph1] + adst;
        float aB = a_src0[(long)sB * 8 + hph1] + adst;
        aA = aA > 0.f ? aA : 0.2f * aA;
        aB = aB > 0.f ? aB : 0.2f * aB;
        const float wA = vA ? __expf(aA) : 0.f;
        const float wB = vB ? __expf(aB) : 0.f;
        den += wA + wB;
        // ---- phase 2: 8 rounds x 2 batches, dense h0b row loads ----
        #pragma unroll
        for (int j = 0; j < 8; j++) {
            const float wjA = __shfl(wA, j * 8 + hsel);
            const int sjA = __shfl(sA, j * 8);
            const float wjB = __shfl(wB, j * 8 + hsel);
            const int sjB = __shfl(sB, j * 8);
            const unsigned int uA = *(const unsigned int*)(h0b + (long)sjA * 128 + c);
            const unsigned int uB = *(const unsigned int*)(h0b + (long)sjB * 128 + c);
            accA.x += wjA * bf2f((unsigned short)uA);
            accA.y += wjA * bf2f((unsigned short)(uA >> 16));
            accB.x += wjB * bf2f((unsigned short)uB);
            accB.y += wjB * bf2f((unsigned short)(uB >> 16));
        }
    }
    float2 acc = {accA.x + accB.x, accA.y + accB.y};
    // reduce den over edge slots (lanes with equal lane&7)
    den += __shfl_xor(den, 8);
    den += __shfl_xor(den, 16);
    den += __shfl_xor(den, 32);
    const float denh = __shfl(den, hsel);
    const float inv = 1.f / (denh + 1e-16f);
    out0b2[(long)d * 64 + lane] =
        (unsigned int)f2bf(acc.x * inv) | ((unsigned int)f2bf(acc.y * inv) << 16);
}

// ---------------------------------------------------------------------------
// K4: MFMA-based post0: h_act = ELU(BN(out0)+s0) in registers, then
// [h1|s1] = h_act @ [w1^T|skip1^T] via two 16x16x32 MFMA tiles per 16 nodes.
// ---------------------------------------------------------------------------
__global__ __launch_bounds__(256) void k_post0(
    const unsigned short* __restrict__ out0b, const unsigned short* __restrict__ s0b,
    const float* __restrict__ b0, const float* __restrict__ g0,
    const float* __restrict__ bb0, const float* __restrict__ m0,
    const float* __restrict__ v0,
    const unsigned short* __restrict__ wb1,     // [32][128] bf16: w1 rows, skip1 rows
    const float* __restrict__ asrc1, const float* __restrict__ adst1,
    unsigned short* __restrict__ h1b, float* __restrict__ s1,
    float* __restrict__ a_src1, float* __restrict__ a_dst1)
{
    __shared__ float Ac[128], Bc[128];
    const int tid = threadIdx.x;
    if (tid < 128) {
        float A = g0[tid] * rsqrtf(v0[tid] + 1e-5f);
        Ac[tid] = A;
        Bc[tid] = (b0[tid] - m0[tid]) * A + bb0[tid];
    }
    __syncthreads();

    const int lane = tid & 63, wave = tid >> 6;
    const int lrow = lane & 15, quad = lane >> 4;

    bf16x8 bfrag[2][4];
    #pragma unroll
    for (int t = 0; t < 2; t++)
        #pragma unroll
        for (int ki = 0; ki < 4; ki++)
            bfrag[t][ki] = *(const bf16x8*)(wb1 + (long)(t * 16 + lrow) * 128 + ki * 32 + quad * 8);
    const float avec = asrc1[lrow];
    const float dvec = adst1[lrow];

    const int tile = blockIdx.x * 4 + wave;           // 16 nodes per tile
    if (tile * 16 >= NN) return;
    const int n0 = tile * 16;
    const long arow = (long)(n0 + lrow) * 128;

    bf16x8 afrag[4];
    #pragma unroll
    for (int ki = 0; ki < 4; ki++) {
        const int ch = ki * 32 + quad * 8;
        uint4 uo = *(const uint4*)(out0b + arow + ch);
        uint4 us = *(const uint4*)(s0b + arow + ch);
        const unsigned int uov[4] = {uo.x, uo.y, uo.z, uo.w};
        const unsigned int usv[4] = {us.x, us.y, us.z, us.w};
        bf16x8 af;
        #pragma unroll
        for (int e = 0; e < 4; e++) {
            const int c0 = ch + e * 2, c1 = c0 + 1;
            float x0 = bf2f((unsigned short)uov[e]) * Ac[c0] + Bc[c0] + bf2f((unsigned short)usv[e]);
            float x1 = bf2f((unsigned short)(uov[e] >> 16)) * Ac[c1] + Bc[c1] + bf2f((unsigned short)(usv[e] >> 16));
            x0 = x0 > 0.f ? x0 : __expf(x0) - 1.f;
            x1 = x1 > 0.f ? x1 : __expf(x1) - 1.f;
            af[e * 2]     = (short)f2bf(x0);
            af[e * 2 + 1] = (short)f2bf(x1);
        }
        afrag[ki] = af;
    }

    f32x4 acc0 = (f32x4){0.f, 0.f, 0.f, 0.f};   // h1 tile
    f32x4 acc1 = (f32x4){0.f, 0.f, 0.f, 0.f};   // s1 tile
    #pragma unroll
    for (int ki = 0; ki < 4; ki++) {
        acc0 = __builtin_amdgcn_mfma_f32_16x16x32_bf16(afrag[ki], bfrag[0][ki], acc0, 0, 0, 0);
        acc1 = __builtin_amdgcn_mfma_f32_16x16x32_bf16(afrag[ki], bfrag[1][ki], acc1, 0, 0, 0);
    }

    // C layout: col = lane&15 (=j), row = quad*4+r (= node - n0)
    #pragma unroll
    for (int r = 0; r < 4; r++) {
        const int node = n0 + quad * 4 + r;
        h1b[(long)node * 16 + lrow] = f2bf(acc0[r]);
        s1[(long)node * 16 + lrow] = acc1[r];
        float ps = acc0[r] * avec;
        float pd = acc0[r] * dvec;
        ps += __shfl_xor(ps, 1); ps += __shfl_xor(ps, 2);
        ps += __shfl_xor(ps, 4); ps += __shfl_xor(ps, 8);
        pd += __shfl_xor(pd, 1); pd += __shfl_xor(pd, 2);
        pd += __shfl_xor(pd, 4); pd += __shfl_xor(pd, 8);
        if (lrow == 0) { a_src1[node] = ps; a_dst1[node] = pd; }
    }
}

// ---------------------------------------------------------------------------
// K5: layer-1 aggregation + BN1 + skip + ELU -> d_out, two-phase dedup + 2x
// batch interleave. 8 lanes per dst node, 2 channels per lane.
// ---------------------------------------------------------------------------
__global__ __launch_bounds__(256) void k_agg1_final(
    const int* __restrict__ rowbeg, const int* __restrict__ deg,
    const unsigned short* __restrict__ srcidx,
    const unsigned short* __restrict__ h1b, const float* __restrict__ a_src1,
    const float* __restrict__ a_dst1, const float* __restrict__ s1,
    const float* __restrict__ b1, const float* __restrict__ g1,
    const float* __restrict__ bb1, const float* __restrict__ m1,
    const float* __restrict__ v1, float* __restrict__ out)
{
    const int gid = blockIdx.x * 256 + threadIdx.x;
    const int d = gid >> 3;                               // 8 lanes per node
    if (d >= NN) return;
    const int lane = threadIdx.x & 63;
    const int gl = lane & 7;                              // lane within group
    const int gb = lane & ~7;                             // group base lane
    const int c0 = gl * 2, c1 = c0 + 1;
    const int beg = rowbeg[d], end = beg + deg[d];
    const float adst = a_dst1[d];

    float den = 0.f;
    float2 accA = {0.f, 0.f}, accB = {0.f, 0.f};
    for (int i = beg; i < end; i += 16) {
        const int idxA = i + gl;
        const int idxB = i + 8 + gl;
        const bool vA = idxA < end;
        const bool vB = idxB < end;
        const int sA = vA ? (int)srcidx[idxA] : 0;
        const int sB = vB ? (int)srcidx[idxB] : 0;
        float aA = a_src1[sA] + adst;
        float aB = a_src1[sB] + adst;
        aA = aA > 0.f ? aA : 0.2f * aA;
        aB = aB > 0.f ? aB : 0.2f * aB;
        const float wA = vA ? __expf(aA) : 0.f;
        const float wB = vB ? __expf(aB) : 0.f;
        den += wA + wB;
        #pragma unroll
        for (int j = 0; j < 8; j++) {
            const float wjA = __shfl(wA, gb | j);
            const int sjA = __shfl(sA, gb | j);
            const float wjB = __shfl(wB, gb | j);
            const int sjB = __shfl(sB, gb | j);
            const unsigned int uA = *(const unsigned int*)(h1b + (long)sjA * 16 + c0);
            const unsigned int uB = *(const unsigned int*)(h1b + (long)sjB * 16 + c0);
            accA.x += wjA * bf2f((unsigned short)uA);
            accA.y += wjA * bf2f((unsigned short)(uA >> 16));
            accB.x += wjB * bf2f((unsigned short)uB);
            accB.y += wjB * bf2f((unsigned short)(uB >> 16));
        }
    }
    float2 acc = {accA.x + accB.x, accA.y + accB.y};
    den += __shfl_xor(den, 1);
    den += __shfl_xor(den, 2);
    den += __shfl_xor(den, 4);
    const float inv = 1.f / (den + 1e-16f);

    const float A0 = g1[c0] * rsqrtf(v1[c0] + 1e-5f);
    const float B0 = (b1[c0] - m1[c0]) * A0 + bb1[c0];
    const float A1 = g1[c1] * rsqrtf(v1[c1] + 1e-5f);
    const float B1 = (b1[c1] - m1[c1]) * A1 + bb1[c1];
    float2 sv = *(const float2*)(s1 + (long)d * 16 + c0);
    float v0o = acc.x * inv * A0 + B0 + sv.x;
    float v1o = acc.y * inv * A1 + B1 + sv.y;
    v0o = v0o > 0.f ? v0o : __expf(v0o) - 1.f;
    v1o = v1o > 0.f ? v1o : __expf(v1o) - 1.f;
    *(float2*)(out + (long)d * 16 + c0) = make_float2(v0o, v1o);
}

extern "C" void kernel_launch(void* const* d_in, const int* in_sizes, int n_in,
                              void* d_out, int out_size, void* d_ws, size_t ws_size,
                              hipStream_t stream)
{
    (void)in_sizes; (void)n_in; (void)out_size; (void)ws_size;
    const float* x     = (const float*)d_in[0];
    const int*   ei    = (const int*)d_in[1];
    const float* w0    = (const float*)d_in[2];
    const float* asrc0 = (const float*)d_in[3];
    const float* adst0 = (const float*)d_in[4];
    const float* b0    = (const float*)d_in[5];
    const float* skip0 = (const float*)d_in[6];
    const float* bn0g  = (const float*)d_in[7];
    const float* bn0b  = (const float*)d_in[8];
    const float* bn0m  = (const float*)d_in[9];
    const float* bn0v  = (const float*)d_in[10];
    const float* w1    = (const float*)d_in[11];
    const float* asrc1 = (const float*)d_in[12];
    const float* adst1 = (const float*)d_in[13];
    const float* b1    = (const float*)d_in[14];
    const float* skip1 = (const float*)d_in[15];
    const float* bn1g  = (const float*)d_in[16];
    const float* bn1b  = (const float*)d_in[17];
    const float* bn1m  = (const float*)d_in[18];
    const float* bn1v  = (const float*)d_in[19];

    // workspace layout
    unsigned int* pairs = (unsigned int*)d_ws;                      // EE (u32 packed)
    unsigned short* xb    = (unsigned short*)(pairs + EE);          // NN*128
    unsigned short* wb    = xb + (long)NN * 128;                    // 256*128
    unsigned short* wb1   = wb + 256 * 128;                         // 32*128
    unsigned short* h0b   = wb1 + 32 * 128;                         // NN*128
    unsigned short* s0b   = h0b + (long)NN * 128;                   // NN*128
    unsigned short* out0b = s0b + (long)NN * 128;                   // NN*128
    unsigned short* h1b   = out0b + (long)NN * 128;                 // NN*16
    unsigned short* srcidx= h1b + (long)NN * 16;                    // EE
    float* a_src0 = (float*)(srcidx + EE);                          // NN*8
    float* a_dst0 = a_src0 + (long)NN * 8;                          // NN*8
    float* s1     = a_dst0 + (long)NN * 8;                          // NN*16
    float* a_src1 = s1 + (long)NN * 16;                             // NN
    float* a_dst1 = a_src1 + NN;                                    // NN
    int* ccnt   = (int*)(a_dst1 + NN);                              // COARSE (zeroed)
    int* cbase  = ccnt + COARSE;                                    // COARSE+1
    int* ccur   = cbase + COARSE + 1;                               // COARSE
    int* rowbeg = ccur + COARSE;                                    // NN
    int* deg    = rowbeg + NN;                                      // NN

    hipMemsetAsync(ccnt, 0, (size_t)COARSE * 4, stream);

    // bf16 conversions (x + all weights, one kernel)
    const long NTOT = (long)NN * 128 / 4 + 256 * 128 / 4 + 32 * 128 / 4;
    k_cvt<<<(unsigned)((NTOT + 255) / 256), 256, 0, stream>>>(
        x, w0, skip0, w1, skip1,
        (unsigned int*)xb, (unsigned int*)wb, (unsigned int*)wb1);

    // CSR build: dense-write partition sort (shared by both layers)
    k_chist<<<(EE + 1023) / 1024, 256, 0, stream>>>(ei, ccnt);
    k_cbase<<<1, 256, 0, stream>>>(ccnt, cbase, ccur);
    k_partA<<<(EE + EPB - 1) / EPB, 256, 0, stream>>>(ei, ccur, pairs);
    k_partB<<<COARSE, 256, 0, stream>>>(pairs, cbase, srcidx, rowbeg, deg);

    // layer 0
    k_gemm0<<<(NN + 63) / 64, 256, 0, stream>>>(xb, wb, asrc0, adst0,
                                                h0b, s0b, a_src0, a_dst0);
    k_agg0<<<(NN * 64 + 255) / 256, 256, 0, stream>>>(rowbeg, deg, srcidx, h0b,
                                                      a_src0, a_dst0, (unsigned int*)out0b);
    k_post0<<<(NN / 16 + 3) / 4, 256, 0, stream>>>(out0b, s0b, b0, bn0g, bn0b, bn0m, bn0v,
                                                   wb1, asrc1, adst1, h1b, s1, a_src1, a_dst1);
    // layer 1 + epilogue
    k_agg1_final<<<(NN * 8 + 255) / 256, 256, 0, stream>>>(rowbeg, deg, srcidx, h1b,
                                                           a_src1, a_dst1, s1,
                                                           b1, bn1g, bn1b, bn1m, bn1v,
                                                           (float*)d_out);
}

// Round 11
// 218.216 us; speedup vs baseline: 9.6771x; 1.1263x over previous
//
#include <hip/hip_runtime.h>
#include <hip/hip_bf16.h>

#define NN 50000
#define EE 800000
#define INDIM 128
#define HIDC 16
#define NHEAD 8
#define COARSE 196          // ceil(NN/256)
#define EPB 2048            // edges per block in partition pass A
#define CAPR 6144           // fixed region stride per coarse bin (avg cnt ~4082, 31-sigma margin)
#define CAPB 8192           // partB LDS stage capacity (>= CAPR)

typedef __attribute__((ext_vector_type(8))) short bf16x8;
typedef __attribute__((ext_vector_type(4))) float f32x4;

__device__ __forceinline__ float bf2f(unsigned short u) {
    union { float f; unsigned int i; } v; v.i = ((unsigned int)u) << 16; return v.f;
}
__device__ __forceinline__ unsigned short f2bf(float f) {
    union { float f; unsigned int i; } v; v.f = f;
    unsigned int r = v.i + 0x7FFFu + ((v.i >> 16) & 1u);
    return (unsigned short)(r >> 16);
}
__device__ __forceinline__ unsigned char f2fp8(float f) {
    // OCP e4m3 via HW cvt (gfx950)
    return (unsigned char)(__builtin_amdgcn_cvt_pk_fp8_f32(f, f, 0, 0) & 0xFF);
}

// ---------------------------------------------------------------------------
// K0: fp32->bf16 conversions (x, [w0|skip0], [w1|skip1]) + ccur region init.
// ---------------------------------------------------------------------------
__global__ __launch_bounds__(256) void k_cvt(const float* __restrict__ x,
                                             const float* __restrict__ w0,
                                             const float* __restrict__ skip0,
                                             const float* __restrict__ w1,
                                             const float* __restrict__ skip1,
                                             unsigned int* __restrict__ xb2,
                                             unsigned int* __restrict__ wb2,
                                             unsigned int* __restrict__ wb1_2,
                                             int* __restrict__ ccur)
{
    if (blockIdx.x == 0 && threadIdx.x < COARSE)
        ccur[threadIdx.x] = threadIdx.x * CAPR;

    const long NX = (long)NN * 128 / 4;      // x float4 blocks
    const long NW = 256 * 128 / 4;           // w0|skip0
    const long NW1 = 32 * 128 / 4;           // w1|skip1
    long i = (long)blockIdx.x * 256 + threadIdx.x;
    if (i < NX) {
        float4 v = ((const float4*)x)[i];
        xb2[i * 2]     = (unsigned int)f2bf(v.x) | ((unsigned int)f2bf(v.y) << 16);
        xb2[i * 2 + 1] = (unsigned int)f2bf(v.z) | ((unsigned int)f2bf(v.w) << 16);
    } else if (i < NX + NW) {
        long j = i - NX;
        const float4* src = (j < 128 * 128 / 4) ? ((const float4*)w0 + j)
                                                : ((const float4*)skip0 + (j - 128 * 128 / 4));
        float4 v = *src;
        wb2[j * 2]     = (unsigned int)f2bf(v.x) | ((unsigned int)f2bf(v.y) << 16);
        wb2[j * 2 + 1] = (unsigned int)f2bf(v.z) | ((unsigned int)f2bf(v.w) << 16);
    } else if (i < NX + NW + NW1) {
        long j = i - NX - NW;
        const float4* src = (j < 16 * 128 / 4) ? ((const float4*)w1 + j)
                                               : ((const float4*)skip1 + (j - 16 * 128 / 4));
        float4 v = *src;
        wb1_2[j * 2]     = (unsigned int)f2bf(v.x) | ((unsigned int)f2bf(v.y) << 16);
        wb1_2[j * 2 + 1] = (unsigned int)f2bf(v.z) | ((unsigned int)f2bf(v.w) << 16);
    }
}

// ---------------------------------------------------------------------------
// Partition pass A: coarse scatter of packed (d<<16|s) into FIXED per-bin
// regions (no global histogram/scan needed). LDS staging -> dense writes.
// ---------------------------------------------------------------------------
__global__ __launch_bounds__(256) void k_partA(const int* __restrict__ ei,
                                               int* __restrict__ ccur,
                                               unsigned int* __restrict__ pairs)
{
    __shared__ int bcnt[256];
    __shared__ int lofs[256];
    __shared__ int gofs[256];
    __shared__ unsigned int stage[EPB];
    __shared__ int gpos[EPB];
    const int t = threadIdx.x;
    const int e0 = blockIdx.x * EPB;

    bcnt[t] = 0;
    __syncthreads();

    int mybin[8], myrank[8];
    unsigned int mypair[8];
    #pragma unroll
    for (int k = 0; k < 8; k++) {
        int e = e0 + k * 256 + t;
        mybin[k] = -1;
        if (e < EE) {
            int s = ei[e], d = ei[EE + e];
            int b = d >> 8;
            myrank[k] = atomicAdd(&bcnt[b], 1);
            mybin[k] = b;
            mypair[k] = ((unsigned)d << 16) | (unsigned)s;
        }
    }
    __syncthreads();

    int v = bcnt[t];
    lofs[t] = v;
    __syncthreads();
    for (int off = 1; off < 256; off <<= 1) {
        int u = (t >= off) ? lofs[t - off] : 0;
        __syncthreads();
        lofs[t] += u;
        __syncthreads();
    }
    if (t < COARSE && v > 0) gofs[t] = atomicAdd(&ccur[t], v);
    __syncthreads();

    #pragma unroll
    for (int k = 0; k < 8; k++) {
        int b = mybin[k];
        if (b >= 0) {
            int slot = (lofs[b] - bcnt[b]) + myrank[k];
            stage[slot] = mypair[k];
            gpos[slot]  = gofs[b] + myrank[k];
        }
    }
    __syncthreads();

    const int total = lofs[255];
    for (int i = t; i < total; i += 256)
        pairs[gpos[i]] = stage[i];
}

// ---------------------------------------------------------------------------
// Partition pass B: one block per coarse bin; LDS counting-sort by exact dst;
// emits rowbeg/deg and contiguous srcidx (u16).
// ---------------------------------------------------------------------------
__global__ __launch_bounds__(256) void k_partB(const unsigned int* __restrict__ pairs,
                                               const int* __restrict__ ccur,
                                               unsigned short* __restrict__ srcidx,
                                               int* __restrict__ rowbeg,
                                               int* __restrict__ deg)
{
    __shared__ int fcnt[256], fofs[256], fcur[256];
    __shared__ unsigned short stage[CAPB];
    const int b = blockIdx.x, t = threadIdx.x;
    const int beg = b * CAPR;
    int cnt = ccur[b] - beg;
    if (cnt > CAPR) cnt = CAPR;   // safety clamp

    fcnt[t] = 0;
    __syncthreads();
    for (int i = t; i < cnt; i += 256) {
        unsigned int d = pairs[beg + i] >> 16;
        atomicAdd(&fcnt[d & 255], 1);
    }
    __syncthreads();

    int v = fcnt[t];
    fofs[t] = v;
    __syncthreads();
    for (int off = 1; off < 256; off <<= 1) {
        int u = (t >= off) ? fofs[t - off] : 0;
        __syncthreads();
        fofs[t] += u;
        __syncthreads();
    }
    int ex = fofs[t] - v;
    int node = b * 256 + t;
    if (node < NN) { rowbeg[node] = beg + ex; deg[node] = v; }
    fcur[t] = ex;
    __syncthreads();

    for (int i = t; i < cnt; i += 256) {
        unsigned int p = pairs[beg + i];
        unsigned int d = p >> 16;
        int slot = atomicAdd(&fcur[d & 255], 1);
        stage[slot] = (unsigned short)(p & 0xFFFFu);
    }
    __syncthreads();
    for (int i = t; i < cnt; i += 256)
        srcidx[beg + i] = stage[i];
}

// ---------------------------------------------------------------------------
// K1: fused GEMM  h0f = fp8(x@w0^T), s0b = bf16(x@skip0^T), + attention
// coefficients a_src0/a_dst0 in the epilogue (from fp32 accumulators).
// ---------------------------------------------------------------------------
__global__ __launch_bounds__(256) void k_gemm0(
    const unsigned short* __restrict__ xb, const unsigned short* __restrict__ wb,
    const float* __restrict__ asrc0, const float* __restrict__ adst0,
    unsigned char* __restrict__ h0f, unsigned short* __restrict__ s0b,
    float* __restrict__ a_src0, float* __restrict__ a_dst0)
{
    const int wave = threadIdx.x >> 6;
    const int lane = threadIdx.x & 63;
    const int lrow = lane & 15;
    const int quad = lane >> 4;
    const int rowbase = blockIdx.x * 64;

    bf16x8 bfrag[4][4];
    float asv[4], adv[4];
    #pragma unroll
    for (int t = 0; t < 4; t++) {
        const int jg = wave * 64 + t * 16 + lrow;
        #pragma unroll
        for (int ki = 0; ki < 4; ki++)
            bfrag[t][ki] = *(const bf16x8*)(wb + (long)jg * 128 + ki * 32 + quad * 8);
        if (wave < 2) { asv[t] = asrc0[jg]; adv[t] = adst0[jg]; }
    }

    #pragma unroll
    for (int sub = 0; sub < 4; sub++) {
        const int row0 = rowbase + sub * 16;
        if (row0 >= NN) break;
        const unsigned short* xrow = xb + (long)(row0 + lrow) * 128;
        bf16x8 afrag[4];
        #pragma unroll
        for (int ki = 0; ki < 4; ki++)
            afrag[ki] = *(const bf16x8*)(xrow + ki * 32 + quad * 8);

        f32x4 acc[4];
        #pragma unroll
        for (int t = 0; t < 4; t++) acc[t] = (f32x4){0.f, 0.f, 0.f, 0.f};

        #pragma unroll
        for (int ki = 0; ki < 4; ki++)
            #pragma unroll
            for (int t = 0; t < 4; t++)
                acc[t] = __builtin_amdgcn_mfma_f32_16x16x32_bf16(afrag[ki], bfrag[t][ki], acc[t], 0, 0, 0);

        if (wave < 2) {
            #pragma unroll
            for (int t = 0; t < 4; t++) {
                const int jg = wave * 64 + t * 16 + lrow;
                #pragma unroll
                for (int r = 0; r < 4; r++) {
                    const int n = row0 + quad * 4 + r;
                    float val = acc[t][r];
                    h0f[(long)n * 128 + jg] = f2fp8(val);
                    float ps = val * asv[t];
                    float pd = val * adv[t];
                    ps += __shfl_xor(ps, 1); ps += __shfl_xor(ps, 2);
                    ps += __shfl_xor(ps, 4); ps += __shfl_xor(ps, 8);
                    pd += __shfl_xor(pd, 1); pd += __shfl_xor(pd, 2);
                    pd += __shfl_xor(pd, 4); pd += __shfl_xor(pd, 8);
                    if (lrow == 0) {
                        const int h = wave * 4 + t;
                        a_src0[(long)n * 8 + h] = ps;
                        a_dst0[(long)n * 8 + h] = pd;
                    }
                }
            }
        } else {
            #pragma unroll
            for (int t = 0; t < 4; t++) {
                const int jg = wave * 64 + t * 16 + lrow - 128;
                #pragma unroll
                for (int r = 0; r < 4; r++) {
                    const int n = row0 + quad * 4 + r;
                    s0b[(long)n * 128 + jg] = f2bf(acc[t][r]);
                }
            }
        }
    }
}

// ---------------------------------------------------------------------------
// K3: layer-0 aggregation, fp8 h0 table (halves replicated L2-miss traffic).
// Two-phase dedup + 2x batch interleave. One wave per dst node; lane owns
// channels {2*lane, 2*lane+1} -> ushort load = 2 fp8.
// ---------------------------------------------------------------------------
__global__ __launch_bounds__(256) void k_agg0(
    const int* __restrict__ rowbeg, const int* __restrict__ deg,
    const unsigned short* __restrict__ srcidx,
    const unsigned char* __restrict__ h0f, const float* __restrict__ a_src0,
    const float* __restrict__ a_dst0, unsigned int* __restrict__ out0b2)
{
    const int d = (blockIdx.x * 256 + threadIdx.x) >> 6;  // one wave per node
    if (d >= NN) return;
    const int lane = threadIdx.x & 63;
    const int beg = rowbeg[d], end = beg + deg[d];
    const int eslot = lane >> 3;                          // phase-1 edge slot
    const int hph1 = lane & 7;                            // phase-1 head
    const int c = lane * 2;                               // phase-2 channels
    const int hsel = lane >> 3;                           // head for channels c
    const float adst = a_dst0[(long)d * 8 + hph1];

    float den = 0.f;
    float2 accA = {0.f, 0.f}, accB = {0.f, 0.f};
    for (int i = beg; i < end; i += 16) {
        const int idxA = i + eslot;
        const int idxB = i + 8 + eslot;
        const bool vA = idxA < end;
        const bool vB = idxB < end;
        const int sA = vA ? (int)srcidx[idxA] : 0;
        const int sB = vB ? (int)srcidx[idxB] : 0;
        float aA = a_src0[(long)sA * 8 + hph1] + adst;
        float aB = a_src0[(long)sB * 8 + hph1] + adst;
        aA = aA > 0.f ? aA : 0.2f * aA;
        aB = aB > 0.f ? aB : 0.2f * aB;
        const float wA = vA ? __expf(aA) : 0.f;
        const float wB = vB ? __expf(aB) : 0.f;
        den += wA + wB;
        #pragma unroll
        for (int j = 0; j < 8; j++) {
            const float wjA = __shfl(wA, j * 8 + hsel);
            const int sjA = __shfl(sA, j * 8);
            const float wjB = __shfl(wB, j * 8 + hsel);
            const int sjB = __shfl(sB, j * 8);
            const unsigned int uA = *(const unsigned short*)(h0f + (long)sjA * 128 + c);
            const unsigned int uB = *(const unsigned short*)(h0f + (long)sjB * 128 + c);
            accA.x += wjA * __builtin_amdgcn_cvt_f32_fp8(uA, 0);
            accA.y += wjA * __builtin_amdgcn_cvt_f32_fp8(uA, 1);
            accB.x += wjB * __builtin_amdgcn_cvt_f32_fp8(uB, 0);
            accB.y += wjB * __builtin_amdgcn_cvt_f32_fp8(uB, 1);
        }
    }
    float2 acc = {accA.x + accB.x, accA.y + accB.y};
    den += __shfl_xor(den, 8);
    den += __shfl_xor(den, 16);
    den += __shfl_xor(den, 32);
    const float denh = __shfl(den, hsel);
    const float inv = 1.f / (denh + 1e-16f);
    out0b2[(long)d * 64 + lane] =
        (unsigned int)f2bf(acc.x * inv) | ((unsigned int)f2bf(acc.y * inv) << 16);
}

// ---------------------------------------------------------------------------
// K4: MFMA-based post0: h_act = ELU(BN(out0)+s0) in registers, then
// [h1|s1] = h_act @ [w1^T|skip1^T] via two 16x16x32 MFMA tiles per 16 nodes.
// ---------------------------------------------------------------------------
__global__ __launch_bounds__(256) void k_post0(
    const unsigned short* __restrict__ out0b, const unsigned short* __restrict__ s0b,
    const float* __restrict__ b0, const float* __restrict__ g0,
    const float* __restrict__ bb0, const float* __restrict__ m0,
    const float* __restrict__ v0,
    const unsigned short* __restrict__ wb1,     // [32][128] bf16: w1 rows, skip1 rows
    const float* __restrict__ asrc1, const float* __restrict__ adst1,
    unsigned short* __restrict__ h1b, float* __restrict__ s1,
    float* __restrict__ a_src1, float* __restrict__ a_dst1)
{
    __shared__ float Ac[128], Bc[128];
    const int tid = threadIdx.x;
    if (tid < 128) {
        float A = g0[tid] * rsqrtf(v0[tid] + 1e-5f);
        Ac[tid] = A;
        Bc[tid] = (b0[tid] - m0[tid]) * A + bb0[tid];
    }
    __syncthreads();

    const int lane = tid & 63, wave = tid >> 6;
    const int lrow = lane & 15, quad = lane >> 4;

    bf16x8 bfrag[2][4];
    #pragma unroll
    for (int t = 0; t < 2; t++)
        #pragma unroll
        for (int ki = 0; ki < 4; ki++)
            bfrag[t][ki] = *(const bf16x8*)(wb1 + (long)(t * 16 + lrow) * 128 + ki * 32 + quad * 8);
    const float avec = asrc1[lrow];
    const float dvec = adst1[lrow];

    const int tile = blockIdx.x * 4 + wave;           // 16 nodes per tile
    if (tile * 16 >= NN) return;
    const int n0 = tile * 16;
    const long arow = (long)(n0 + lrow) * 128;

    bf16x8 afrag[4];
    #pragma unroll
    for (int ki = 0; ki < 4; ki++) {
        const int ch = ki * 32 + quad * 8;
        uint4 uo = *(const uint4*)(out0b + arow + ch);
        uint4 us = *(const uint4*)(s0b + arow + ch);
        const unsigned int uov[4] = {uo.x, uo.y, uo.z, uo.w};
        const unsigned int usv[4] = {us.x, us.y, us.z, us.w};
        bf16x8 af;
        #pragma unroll
        for (int e = 0; e < 4; e++) {
            const int c0 = ch + e * 2, c1 = c0 + 1;
            float x0 = bf2f((unsigned short)uov[e]) * Ac[c0] + Bc[c0] + bf2f((unsigned short)usv[e]);
            float x1 = bf2f((unsigned short)(uov[e] >> 16)) * Ac[c1] + Bc[c1] + bf2f((unsigned short)(usv[e] >> 16));
            x0 = x0 > 0.f ? x0 : __expf(x0) - 1.f;
            x1 = x1 > 0.f ? x1 : __expf(x1) - 1.f;
            af[e * 2]     = (short)f2bf(x0);
            af[e * 2 + 1] = (short)f2bf(x1);
        }
        afrag[ki] = af;
    }

    f32x4 acc0 = (f32x4){0.f, 0.f, 0.f, 0.f};   // h1 tile
    f32x4 acc1 = (f32x4){0.f, 0.f, 0.f, 0.f};   // s1 tile
    #pragma unroll
    for (int ki = 0; ki < 4; ki++) {
        acc0 = __builtin_amdgcn_mfma_f32_16x16x32_bf16(afrag[ki], bfrag[0][ki], acc0, 0, 0, 0);
        acc1 = __builtin_amdgcn_mfma_f32_16x16x32_bf16(afrag[ki], bfrag[1][ki], acc1, 0, 0, 0);
    }

    // C layout: col = lane&15 (=j), row = quad*4+r (= node - n0)
    #pragma unroll
    for (int r = 0; r < 4; r++) {
        const int node = n0 + quad * 4 + r;
        h1b[(long)node * 16 + lrow] = f2bf(acc0[r]);
        s1[(long)node * 16 + lrow] = acc1[r];
        float ps = acc0[r] * avec;
        float pd = acc0[r] * dvec;
        ps += __shfl_xor(ps, 1); ps += __shfl_xor(ps, 2);
        ps += __shfl_xor(ps, 4); ps += __shfl_xor(ps, 8);
        pd += __shfl_xor(pd, 1); pd += __shfl_xor(pd, 2);
        pd += __shfl_xor(pd, 4); pd += __shfl_xor(pd, 8);
        if (lrow == 0) { a_src1[node] = ps; a_dst1[node] = pd; }
    }
}

// ---------------------------------------------------------------------------
// K5: layer-1 aggregation + BN1 + skip + ELU -> d_out, two-phase dedup + 2x
// batch interleave. 8 lanes per dst node, 2 channels per lane.
// ---------------------------------------------------------------------------
__global__ __launch_bounds__(256) void k_agg1_final(
    const int* __restrict__ rowbeg, const int* __restrict__ deg,
    const unsigned short* __restrict__ srcidx,
    const unsigned short* __restrict__ h1b, const float* __restrict__ a_src1,
    const float* __restrict__ a_dst1, const float* __restrict__ s1,
    const float* __restrict__ b1, const float* __restrict__ g1,
    const float* __restrict__ bb1, const float* __restrict__ m1,
    const float* __restrict__ v1, float* __restrict__ out)
{
    const int gid = blockIdx.x * 256 + threadIdx.x;
    const int d = gid >> 3;                               // 8 lanes per node
    if (d >= NN) return;
    const int lane = threadIdx.x & 63;
    const int gl = lane & 7;                              // lane within group
    const int gb = lane & ~7;                             // group base lane
    const int c0 = gl * 2, c1 = c0 + 1;
    const int beg = rowbeg[d], end = beg + deg[d];
    const float adst = a_dst1[d];

    float den = 0.f;
    float2 accA = {0.f, 0.f}, accB = {0.f, 0.f};
    for (int i = beg; i < end; i += 16) {
        const int idxA = i + gl;
        const int idxB = i + 8 + gl;
        const bool vA = idxA < end;
        const bool vB = idxB < end;
        const int sA = vA ? (int)srcidx[idxA] : 0;
        const int sB = vB ? (int)srcidx[idxB] : 0;
        float aA = a_src1[sA] + adst;
        float aB = a_src1[sB] + adst;
        aA = aA > 0.f ? aA : 0.2f * aA;
        aB = aB > 0.f ? aB : 0.2f * aB;
        const float wA = vA ? __expf(aA) : 0.f;
        const float wB = vB ? __expf(aB) : 0.f;
        den += wA + wB;
        #pragma unroll
        for (int j = 0; j < 8; j++) {
            const float wjA = __shfl(wA, gb | j);
            const int sjA = __shfl(sA, gb | j);
            const float wjB = __shfl(wB, gb | j);
            const int sjB = __shfl(sB, gb | j);
            const unsigned int uA = *(const unsigned int*)(h1b + (long)sjA * 16 + c0);
            const unsigned int uB = *(const unsigned int*)(h1b + (long)sjB * 16 + c0);
            accA.x += wjA * bf2f((unsigned short)uA);
            accA.y += wjA * bf2f((unsigned short)(uA >> 16));
            accB.x += wjB * bf2f((unsigned short)uB);
            accB.y += wjB * bf2f((unsigned short)(uB >> 16));
        }
    }
    float2 acc = {accA.x + accB.x, accA.y + accB.y};
    den += __shfl_xor(den, 1);
    den += __shfl_xor(den, 2);
    den += __shfl_xor(den, 4);
    const float inv = 1.f / (den + 1e-16f);

    const float A0 = g1[c0] * rsqrtf(v1[c0] + 1e-5f);
    const float B0 = (b1[c0] - m1[c0]) * A0 + bb1[c0];
    const float A1 = g1[c1] * rsqrtf(v1[c1] + 1e-5f);
    const float B1 = (b1[c1] - m1[c1]) * A1 + bb1[c1];
    float2 sv = *(const float2*)(s1 + (long)d * 16 + c0);
    float v0o = acc.x * inv * A0 + B0 + sv.x;
    float v1o = acc.y * inv * A1 + B1 + sv.y;
    v0o = v0o > 0.f ? v0o : __expf(v0o) - 1.f;
    v1o = v1o > 0.f ? v1o : __expf(v1o) - 1.f;
    *(float2*)(out + (long)d * 16 + c0) = make_float2(v0o, v1o);
}

extern "C" void kernel_launch(void* const* d_in, const int* in_sizes, int n_in,
                              void* d_out, int out_size, void* d_ws, size_t ws_size,
                              hipStream_t stream)
{
    (void)in_sizes; (void)n_in; (void)out_size; (void)ws_size;
    const float* x     = (const float*)d_in[0];
    const int*   ei    = (const int*)d_in[1];
    const float* w0    = (const float*)d_in[2];
    const float* asrc0 = (const float*)d_in[3];
    const float* adst0 = (const float*)d_in[4];
    const float* b0    = (const float*)d_in[5];
    const float* skip0 = (const float*)d_in[6];
    const float* bn0g  = (const float*)d_in[7];
    const float* bn0b  = (const float*)d_in[8];
    const float* bn0m  = (const float*)d_in[9];
    const float* bn0v  = (const float*)d_in[10];
    const float* w1    = (const float*)d_in[11];
    const float* asrc1 = (const float*)d_in[12];
    const float* adst1 = (const float*)d_in[13];
    const float* b1    = (const float*)d_in[14];
    const float* skip1 = (const float*)d_in[15];
    const float* bn1g  = (const float*)d_in[16];
    const float* bn1b  = (const float*)d_in[17];
    const float* bn1m  = (const float*)d_in[18];
    const float* bn1v  = (const float*)d_in[19];

    // workspace layout (16B-aligned large arrays first)
    const long NPAIR = (long)COARSE * CAPR;                         // 1,204,224
    unsigned int* pairs = (unsigned int*)d_ws;                      // NPAIR u32
    unsigned short* xb    = (unsigned short*)(pairs + NPAIR);       // NN*128 bf16
    unsigned short* wb    = xb + (long)NN * 128;                    // 256*128
    unsigned short* wb1   = wb + 256 * 128;                         // 32*128
    unsigned short* s0b   = wb1 + 32 * 128;                         // NN*128
    unsigned short* out0b = s0b + (long)NN * 128;                   // NN*128
    unsigned short* h1b   = out0b + (long)NN * 128;                 // NN*16
    unsigned short* srcidx= h1b + (long)NN * 16;                    // NPAIR u16
    unsigned char*  h0f   = (unsigned char*)(srcidx + NPAIR);       // NN*128 fp8
    float* a_src0 = (float*)(h0f + (long)NN * 128);                 // NN*8
    float* a_dst0 = a_src0 + (long)NN * 8;                          // NN*8
    float* s1     = a_dst0 + (long)NN * 8;                          // NN*16
    float* a_src1 = s1 + (long)NN * 16;                             // NN
    float* a_dst1 = a_src1 + NN;                                    // NN
    int* ccur   = (int*)(a_dst1 + NN);                              // COARSE
    int* rowbeg = ccur + COARSE;                                    // NN
    int* deg    = rowbeg + NN;                                      // NN

    // conversions + ccur region init (one kernel, no memset needed)
    const long NTOT = (long)NN * 128 / 4 + 256 * 128 / 4 + 32 * 128 / 4;
    k_cvt<<<(unsigned)((NTOT + 255) / 256), 256, 0, stream>>>(
        x, w0, skip0, w1, skip1,
        (unsigned int*)xb, (unsigned int*)wb, (unsigned int*)wb1, ccur);

    // CSR build: fixed-region partition sort (shared by both layers)
    k_partA<<<(EE + EPB - 1) / EPB, 256, 0, stream>>>(ei, ccur, pairs);
    k_partB<<<COARSE, 256, 0, stream>>>(pairs, ccur, srcidx, rowbeg, deg);

    // layer 0
    k_gemm0<<<(NN + 63) / 64, 256, 0, stream>>>(xb, wb, asrc0, adst0,
                                                h0f, s0b, a_src0, a_dst0);
    k_agg0<<<(NN * 64 + 255) / 256, 256, 0, stream>>>(rowbeg, deg, srcidx, h0f,
                                                      a_src0, a_dst0, (unsigned int*)out0b);
    k_post0<<<(NN / 16 + 3) / 4, 256, 0, stream>>>(out0b, s0b, b0, bn0g, bn0b, bn0m, bn0v,
                                                   wb1, asrc1, adst1, h1b, s1, a_src1, a_dst1);
    // layer 1 + epilogue
    k_agg1_final<<<(NN * 8 + 255) / 256, 256, 0, stream>>>(rowbeg, deg, srcidx, h1b,
                                                           a_src1, a_dst1, s1,
                                                           b1, bn1g, bn1b, bn1m, bn1v,
                                                           (float*)d_out);
}